// Round 10
// baseline (372.816 us; speedup 1.0000x reference)
//
#include <hip/hip_runtime.h>
#include <hip/hip_bf16.h>
#include <stdint.h>

// ---------------------------------------------------------------------------
// NRI-style MLP encoder. B=32, T=50, N=100, D=4, E=9900, H=256. fp32 I/O.
// R7 formulation (send terms are node GEMMs; only edge GEMM is K=256 t2@Wpz).
// R10 change (phaseB was VALU-bound, 57% busy): R9's K-loop built identical
// t2 A-frags in ALL 4 waves (frag indices don't depend on wave) -> 4x
// redundant VALU. Now t2 built ONCE into LDS (stage0, rows split by wave),
// K-loop reads A via ds_read_b128 (row stride 264 elems = 4-bank shift ->
// 2-way alias, free). z4 tile aliases t2 LDS after barrier; LDS stays 33.8KB.
// Rows >= nrows zero-filled (no garbage into MFMA). launch_bounds(256,3):
// no spill (R8 lesson: (256,4)'s 128-reg unified cap spilled 836 MB).
// ---------------------------------------------------------------------------

typedef __attribute__((ext_vector_type(8))) short short8;
typedef __attribute__((ext_vector_type(4))) float float4v;
typedef __attribute__((ext_vector_type(4))) unsigned short ushort4v;

__device__ inline float bf2f(unsigned short u) {
    union { unsigned int i; float f; } v; v.i = ((unsigned int)u) << 16; return v.f;
}
__device__ inline unsigned short f2bf(float f) {
    union { float f; unsigned int i; } v; v.f = f;
    unsigned int i = v.i;
    return (unsigned short)((i + 0x7FFFu + ((i >> 16) & 1u)) >> 16);
}

// ---------------------------------------------------------------------------
// MEGA-PREP: bx<2272 weight packs | <2528 Wpz=pack(w2b@w4a_e) | <2530 misc
// (Wfp/bfv/b4ap/b2bs) | rest repack x. fp32 in, bf16 packed out.
// ---------------------------------------------------------------------------
__global__ __launch_bounds__(256) void prep_kernel(
        const float* __restrict__ x,
        const float* __restrict__ w1a, const float* __restrict__ w1b,
        const float* __restrict__ w2a, const float* __restrict__ w2b,
        const float* __restrict__ w3a, const float* __restrict__ w3b,
        const float* __restrict__ w4a, const float* __restrict__ b4a,
        const float* __restrict__ w4b, const float* __restrict__ b4b,
        const float* __restrict__ wo,  const float* __restrict__ bo,
        const float* __restrict__ b2b,
        unsigned short* __restrict__ Wp1a, unsigned short* __restrict__ Wp1b,
        unsigned short* __restrict__ Wp2r, unsigned short* __restrict__ Wp2s,
        unsigned short* __restrict__ Wp2b, unsigned short* __restrict__ Wp3a,
        unsigned short* __restrict__ Wp3b, unsigned short* __restrict__ Wp4r,
        unsigned short* __restrict__ Wp4s, unsigned short* __restrict__ Wpz,
        unsigned short* __restrict__ Wfp, float* __restrict__ bfv,
        float* __restrict__ b4ap, float* __restrict__ b2bs,
        unsigned short* __restrict__ hin) {
    int bx = blockIdx.x;
    int tid = threadIdx.x;
    if (bx < 2272) {
        const float* W; unsigned short* Wp; int Kin; int b0;
        if      (bx <  224) { W = w1a;             Wp = Wp1a; Kin = 200; b0 = 0;    }
        else if (bx <  480) { W = w1b;             Wp = Wp1b; Kin = 256; b0 = 224;  }
        else if (bx <  736) { W = w2a;             Wp = Wp2r; Kin = 256; b0 = 480;  }
        else if (bx <  992) { W = w2a + 256 * 256; Wp = Wp2s; Kin = 256; b0 = 736;  }
        else if (bx < 1248) { W = w2b;             Wp = Wp2b; Kin = 256; b0 = 992;  }
        else if (bx < 1504) { W = w3a;             Wp = Wp3a; Kin = 256; b0 = 1248; }
        else if (bx < 1760) { W = w3b;             Wp = Wp3b; Kin = 256; b0 = 1504; }
        else if (bx < 2016) { W = w4a;             Wp = Wp4r; Kin = 256; b0 = 1760; }
        else                { W = w4a + 256 * 256; Wp = Wp4s; Kin = 256; b0 = 2016; }
        int idx = (bx - b0) * 256 + tid;
        int k = idx >> 8, n = idx & 255;
        unsigned short v = (k < Kin) ? f2bf(W[k * 256 + n]) : (unsigned short)0;
        Wp[((size_t)(k >> 5) * 256 + n) * 32 + (k & 31)] = v;
    } else if (bx < 2528) {
        int k = bx - 2272, c = tid;
        float s = 0.f;
        for (int t = 0; t < 256; ++t)
            s += w2b[k * 256 + t] * w4a[(size_t)(512 + t) * 256 + c];
        Wpz[((size_t)(k >> 5) * 256 + c) * 32 + (k & 31)] = f2bf(s);
    } else if (bx < 2530) {
        int k = tid;
        if (bx == 2528) {
            float a[4] = {0.f, 0.f, 0.f, 0.f};
            for (int c = 0; c < 256; ++c) {
                float wv = w4b[k * 256 + c];
                #pragma unroll
                for (int o = 0; o < 4; ++o) a[o] += wv * wo[c * 4 + o];
            }
            #pragma unroll
            for (int n = 0; n < 16; ++n)
                Wfp[(size_t)(k >> 5) * 512 + n * 32 + (k & 31)] =
                    (n < 4) ? f2bf(a[n]) : (unsigned short)0;
            if (k < 4) {
                float s = bo[k];
                for (int c = 0; c < 256; ++c) s += b4b[c] * wo[c * 4 + k];
                bfv[k] = s;
            }
        } else {
            float s = b4a[k];
            for (int t = 0; t < 256; ++t)
                s += b2b[t] * w4a[(size_t)(512 + t) * 256 + k];
            b4ap[k] = s;
            b2bs[k] = 0.99f * b2b[k];
        }
    } else {
        int idx = (bx - 2530) * 256 + tid;
        if (idx < 3200 * 224) {
            int row = idx / 224;
            int c = idx - row * 224;
            int b = row / 100, n = row - b * 100;
            unsigned short v = 0;
            if (c < 200) {
                int t = c >> 2, d = c & 3;
                v = f2bf(x[(((size_t)(b * 50 + t)) * 100 + n) * 4 + d]);
            }
            hin[(size_t)row * 224 + c] = v;
        }
    }
}

// ---------------------------------------------------------------------------
// Node GEMM: C = act(A@Wp + bias). Grid (100,4), block 128.
// ---------------------------------------------------------------------------
template <bool RELU>
__global__ __launch_bounds__(128) void node_gemm_kernel(
        const unsigned short* __restrict__ A,
        const unsigned short* __restrict__ Bp,
        const float* __restrict__ bias,
        unsigned short* __restrict__ C, int K) {
    const int tid  = threadIdx.x;
    const int wave = tid >> 6;
    const int lane = tid & 63;
    const int l15  = lane & 15;
    const int quad = lane >> 4;
    const int m0   = blockIdx.x * 32 + wave * 16;
    const int n0   = blockIdx.y * 64;
    const int koff = quad * 8;

    float4v acc[4];
    #pragma unroll
    for (int ni = 0; ni < 4; ++ni) acc[ni] = (float4v)(0.0f);

    const int KB = K >> 5;
    for (int kb = 0; kb < KB; ++kb) {
        short8 af = *(const short8*)(A + (size_t)(m0 + l15) * K + kb * 32 + koff);
        short8 bf[4];
        #pragma unroll
        for (int ni = 0; ni < 4; ++ni)
            bf[ni] = *(const short8*)(Bp + ((size_t)kb * 256 + n0 + ni * 16 + l15) * 32 + koff);
        #pragma unroll
        for (int ni = 0; ni < 4; ++ni)
            acc[ni] = __builtin_amdgcn_mfma_f32_16x16x32_bf16(af, bf[ni], acc[ni], 0, 0, 0);
    }

    #pragma unroll
    for (int ni = 0; ni < 4; ++ni) {
        int col = n0 + ni * 16 + l15;
        float bv = bias[col];
        #pragma unroll
        for (int r = 0; r < 4; ++r) {
            float v = acc[ni][r] + bv;
            if (RELU) v = v > 0.f ? v : 0.f;
            C[(size_t)(m0 + quad * 4 + r) * 256 + col] = f2bf(v);
        }
    }
}

// ---- dual node GEMM (shared A, K=256): y<4 -> C0=A@Bp0+bias0; y>=4 -> C1=A@Bp1 ----
__global__ __launch_bounds__(128) void node_gemm_dual_kernel(
        const unsigned short* __restrict__ A,
        const unsigned short* __restrict__ Bp0, const float* __restrict__ bias0,
        unsigned short* __restrict__ C0,
        const unsigned short* __restrict__ Bp1, unsigned short* __restrict__ C1) {
    const int tid  = threadIdx.x;
    const int wave = tid >> 6;
    const int lane = tid & 63;
    const int l15  = lane & 15;
    const int quad = lane >> 4;
    const int m0   = blockIdx.x * 32 + wave * 16;
    const int sel  = blockIdx.y >> 2;
    const int n0   = (blockIdx.y & 3) * 64;
    const int koff = quad * 8;
    const unsigned short* Bp = sel ? Bp1 : Bp0;
    unsigned short* C = sel ? C1 : C0;

    float4v acc[4];
    #pragma unroll
    for (int ni = 0; ni < 4; ++ni) acc[ni] = (float4v)(0.0f);

    for (int kb = 0; kb < 8; ++kb) {
        short8 af = *(const short8*)(A + (size_t)(m0 + l15) * 256 + kb * 32 + koff);
        short8 bf[4];
        #pragma unroll
        for (int ni = 0; ni < 4; ++ni)
            bf[ni] = *(const short8*)(Bp + ((size_t)kb * 256 + n0 + ni * 16 + l15) * 32 + koff);
        #pragma unroll
        for (int ni = 0; ni < 4; ++ni)
            acc[ni] = __builtin_amdgcn_mfma_f32_16x16x32_bf16(af, bf[ni], acc[ni], 0, 0, 0);
    }

    #pragma unroll
    for (int ni = 0; ni < 4; ++ni) {
        int col = n0 + ni * 16 + l15;
        float bv = sel ? 0.f : bias0[col];
        #pragma unroll
        for (int r = 0; r < 4; ++r)
            C[(size_t)(m0 + quad * 4 + r) * 256 + col] = f2bf(acc[ni][r] + bv);
    }
}

// ---------------------------------------------------------------------------
// colsum: Ssc[g,c] = 0.01*( sum_j relu(U[g,c]+Hs[b,j,c]) - relu(U[g,c]+Hs[b,i,c]) )
// ---------------------------------------------------------------------------
__global__ __launch_bounds__(256) void colsum_kernel(
        const unsigned short* __restrict__ U, const unsigned short* __restrict__ Hs,
        unsigned short* __restrict__ Ssc) {
    const int g = blockIdx.x;
    const int b = g / 100, i = g - b * 100;
    const int c = threadIdx.x;
    const float u = bf2f(U[(size_t)g * 256 + c]);
    const unsigned short* base = Hs + (size_t)b * 100 * 256 + c;
    float s = 0.f;
    #pragma unroll 4
    for (int j = 0; j < 100; ++j) {
        float v = u + bf2f(base[(size_t)j * 256]);
        s += (v > 0.f ? v : 0.f);
    }
    float vi = u + bf2f(base[(size_t)i * 256]);
    s -= (vi > 0.f ? vi : 0.f);
    Ssc[(size_t)g * 256 + c] = f2bf(s * 0.01f);
}

// ---------------------------------------------------------------------------
// Phase B: grid (3200,2), block 256 (4 waves x 64 cols), M=64 (<=50 real).
// stage0: t2 = relu(U_i + Hs_j) -> LDS ONCE (rows split by wave; rows>=nrows
//         zeroed). R9 built this 4x redundantly in-register (VALU 57%).
// K-loop: A-frags via ds_read_b128 from t2s; B = Wpz (L2); 16 MFMA/kb.
// z4 = relu(C4_i + Vs_j + acc) -> LDS (aliases t2s after barrier);
// projection: 8 MFMA vs Wfp (w4b@wo, 16-col padded); lanes l15<4 store fp32.
// LDS 64x264x2 = 33792 B. launch_bounds(256,3): 170-reg cap, no spill.
// ---------------------------------------------------------------------------
__global__ __launch_bounds__(256, 3) void edge_phaseB_kernel(
        const unsigned short* __restrict__ Hs, const unsigned short* __restrict__ Vs,
        const unsigned short* __restrict__ U, const unsigned short* __restrict__ C4,
        const unsigned short* __restrict__ Wpz, const unsigned short* __restrict__ Wfp,
        const float* __restrict__ bfv,
        float* __restrict__ out) {
    __shared__ __align__(16) unsigned short t2s[64 * 264]; // 33792 B (z4 aliases later)
    const int g = blockIdx.x, hb = blockIdx.y;
    const int b = g / 100, nr = g - b * 100;
    const int nrows = hb ? 49 : 50;
    const int k0 = hb * 50;
    const int tid  = threadIdx.x;
    const int wave = tid >> 6;
    const int lane = tid & 63;
    const int l15  = lane & 15;
    const int quad = lane >> 4;
    const int n0   = wave * 64;
    const int koff = quad * 8;

    // ---- stage 0: build t2 tile ONCE (coalesced 8B/lane; pad rows zeroed) ----
    {
        const int c = lane * 4;
        ushort4v uv = *(const ushort4v*)(U + (size_t)g * 256 + c);
        float u0 = bf2f(uv[0]), u1 = bf2f(uv[1]), u2 = bf2f(uv[2]), u3 = bf2f(uv[3]);
        for (int r = wave; r < 64; r += 4) {
            ushort4v tv = (ushort4v)(unsigned short)0;
            if (r < nrows) {
                int k = k0 + r;
                int j = k + (k >= nr ? 1 : 0);
                ushort4v hv = *(const ushort4v*)(Hs + (size_t)(b * 100 + j) * 256 + c);
                float t0 = u0 + bf2f(hv[0]); tv[0] = f2bf(t0 > 0.f ? t0 : 0.f);
                float t1 = u1 + bf2f(hv[1]); tv[1] = f2bf(t1 > 0.f ? t1 : 0.f);
                float t2 = u2 + bf2f(hv[2]); tv[2] = f2bf(t2 > 0.f ? t2 : 0.f);
                float t3 = u3 + bf2f(hv[3]); tv[3] = f2bf(t3 > 0.f ? t3 : 0.f);
            }
            *(ushort4v*)(&t2s[r * 264 + c]) = tv;
        }
    }
    __syncthreads();

    // ---- K-loop: z4 GEMM (K=256), A from LDS, B from L2 ----
    float4v acc[4][4];
    #pragma unroll
    for (int mi = 0; mi < 4; ++mi)
        #pragma unroll
        for (int ni = 0; ni < 4; ++ni) acc[mi][ni] = (float4v)(0.0f);

    #pragma unroll
    for (int kb = 0; kb < 8; ++kb) {
        short8 af[4], bf[4];
        #pragma unroll
        for (int mi = 0; mi < 4; ++mi)
            af[mi] = *(const short8*)(&t2s[(mi * 16 + l15) * 264 + kb * 32 + koff]);
        #pragma unroll
        for (int ni = 0; ni < 4; ++ni)
            bf[ni] = *(const short8*)(Wpz + ((size_t)kb * 256 + n0 + ni * 16 + l15) * 32 + koff);
        #pragma unroll
        for (int mi = 0; mi < 4; ++mi)
            #pragma unroll
            for (int ni = 0; ni < 4; ++ni)
                acc[mi][ni] = __builtin_amdgcn_mfma_f32_16x16x32_bf16(af[mi], bf[ni], acc[mi][ni], 0, 0, 0);
    }
    __syncthreads();            // all t2s A-reads done; z4 aliases t2s below

    // ---- z4 = relu(C4_i + Vs_j + acc) -> LDS (C-layout) ----
    float c4v[4];
    #pragma unroll
    for (int ni = 0; ni < 4; ++ni)
        c4v[ni] = bf2f(C4[(size_t)g * 256 + n0 + ni * 16 + l15]);
    #pragma unroll
    for (int mi = 0; mi < 4; ++mi) {
        #pragma unroll
        for (int r = 0; r < 4; ++r) {
            int row = mi * 16 + quad * 4 + r;          // local edge idx (C-layout)
            int k = k0 + row;
            int j = (row < nrows) ? (k + (k >= nr ? 1 : 0)) : 0;
            const unsigned short* vsr = Vs + (size_t)(b * 100 + j) * 256;
            #pragma unroll
            for (int ni = 0; ni < 4; ++ni) {
                int col = n0 + ni * 16 + l15;
                float zv = c4v[ni] + bf2f(vsr[col]) + acc[mi][ni][r];
                zv = zv > 0.f ? zv : 0.f;
                t2s[row * 264 + col] = f2bf(zv);
            }
        }
    }
    __syncthreads();

    // ---- projection: wave handles rows wave*16..+15; 8 MFMA vs Wfp ----
    float4v pacc = (float4v)(0.0f);
    #pragma unroll
    for (int kb = 0; kb < 8; ++kb) {
        short8 za = *(const short8*)(&t2s[(wave * 16 + l15) * 264 + kb * 32 + koff]);
        short8 wb = *(const short8*)(Wfp + (size_t)kb * 512 + l15 * 32 + koff);
        pacc = __builtin_amdgcn_mfma_f32_16x16x32_bf16(za, wb, pacc, 0, 0, 0);
    }

    if (l15 < 4) {
        float bv = bfv[l15];
        #pragma unroll
        for (int r = 0; r < 4; ++r) {
            int row = wave * 16 + quad * 4 + r;
            if (row < nrows)
                out[((size_t)b * 9900 + nr * 99 + k0 + row) * 4 + l15] = pacc[r] + bv;
        }
    }
}

extern "C" void kernel_launch(void* const* d_in, const int* in_sizes, int n_in,
                              void* d_out, int out_size, void* d_ws, size_t ws_size,
                              hipStream_t stream) {
    const float* x   = (const float*)d_in[0];
    const float* w1a = (const float*)d_in[3];
    const float* b1a = (const float*)d_in[4];
    const float* w1b = (const float*)d_in[5];
    const float* b1b = (const float*)d_in[6];
    const float* w2a = (const float*)d_in[7];
    const float* b2a = (const float*)d_in[8];
    const float* w2b = (const float*)d_in[9];
    const float* b2b = (const float*)d_in[10];
    const float* w3a = (const float*)d_in[11];
    const float* b3a = (const float*)d_in[12];
    const float* w3b = (const float*)d_in[13];
    const float* b3b = (const float*)d_in[14];
    const float* w4a = (const float*)d_in[15];
    const float* b4a = (const float*)d_in[16];
    const float* w4b = (const float*)d_in[17];
    const float* b4b = (const float*)d_in[18];
    const float* wo  = (const float*)d_in[19];
    const float* bo  = (const float*)d_in[20];
    float* out = (float*)d_out;
    (void)in_sizes; (void)n_in; (void)out_size; (void)ws_size;

    char* ws = (char*)d_ws;
    size_t off = 0;
    auto alloc = [&](size_t bytes) {
        size_t o = off;
        off = (off + bytes + 255) & ~(size_t)255;
        return o;
    };
    const size_t SLOT_BF = (size_t)3200 * 256 * 2;   // 1.64 MB
    unsigned short* S_h  = (unsigned short*)(ws + alloc(SLOT_BF)); // h
    unsigned short* S_U  = (unsigned short*)(ws + alloc(SLOT_BF)); // U
    unsigned short* S_Hs = (unsigned short*)(ws + alloc(SLOT_BF)); // Hs
    unsigned short* S_Vs = (unsigned short*)(ws + alloc(SLOT_BF)); // Vs
    unsigned short* S_3  = (unsigned short*)(ws + alloc(SLOT_BF)); // t1 -> vin -> v2
    unsigned short* S_4  = (unsigned short*)(ws + alloc(SLOT_BF)); // hin -> Ssc -> t3 -> C4
    unsigned short* Wp1a = (unsigned short*)(ws + alloc(224 * 256 * 2));
    unsigned short* Wp1b = (unsigned short*)(ws + alloc(256 * 256 * 2));
    unsigned short* Wp2r = (unsigned short*)(ws + alloc(256 * 256 * 2));
    unsigned short* Wp2s = (unsigned short*)(ws + alloc(256 * 256 * 2));
    unsigned short* Wp2b = (unsigned short*)(ws + alloc(256 * 256 * 2));
    unsigned short* Wp3a = (unsigned short*)(ws + alloc(256 * 256 * 2));
    unsigned short* Wp3b = (unsigned short*)(ws + alloc(256 * 256 * 2));
    unsigned short* Wp4r = (unsigned short*)(ws + alloc(256 * 256 * 2));
    unsigned short* Wp4s = (unsigned short*)(ws + alloc(256 * 256 * 2));
    unsigned short* Wpz  = (unsigned short*)(ws + alloc(256 * 256 * 2));
    unsigned short* Wfp  = (unsigned short*)(ws + alloc(8 * 16 * 32 * 2));
    float*          bfv  = (float*)(ws + alloc(4 * 4));
    float*          b4ap = (float*)(ws + alloc(256 * 4));
    float*          b2bs = (float*)(ws + alloc(256 * 4));
    // total ~11.13 MB (<= 11.2 proven safe)

    unsigned short* hin = S_4;   // [prep, g1]
    unsigned short* Ssc = S_4;   // [colsum, g4]
    unsigned short* t3  = S_4;   // [g5, g6]
    unsigned short* C4  = S_4;   // [g7d, phaseB]
    unsigned short* t1  = S_3;   // [g1, g2]
    unsigned short* vin = S_3;   // [g4, g5]
    unsigned short* v2  = S_3;   // [g6, g7d]

    // ---- prep (1 launch: packs + fusions + repack) ----
    hipLaunchKernelGGL(prep_kernel, dim3(5330), dim3(256), 0, stream,
                       x, w1a, w1b, w2a, w2b, w3a, w3b, w4a, b4a, w4b, b4b, wo, bo, b2b,
                       Wp1a, Wp1b, Wp2r, Wp2s, Wp2b, Wp3a, Wp3b, Wp4r, Wp4s, Wpz,
                       Wfp, bfv, b4ap, b2bs, hin);

    // ---- node MLP1, then U & Hs (dual) ----
    hipLaunchKernelGGL((node_gemm_kernel<true >), dim3(100, 4), dim3(128), 0, stream, hin, Wp1a, b1a, t1,  224); // g1
    hipLaunchKernelGGL((node_gemm_kernel<false>), dim3(100, 4), dim3(128), 0, stream, t1,  Wp1b, b1b, S_h, 256); // g2
    hipLaunchKernelGGL(node_gemm_dual_kernel, dim3(100, 8), dim3(128), 0, stream,
                       S_h, Wp2r, b2a, S_U, Wp2s, S_Hs);                                                          // g3d
    // ---- colsum (edge aggregation without GEMM) ----
    hipLaunchKernelGGL(colsum_kernel, dim3(3200), dim3(256), 0, stream, S_U, S_Hs, Ssc);
    // ---- vin + node MLP3, then C4 & Vs (dual) ----
    hipLaunchKernelGGL((node_gemm_kernel<false>), dim3(100, 4), dim3(128), 0, stream, Ssc, Wp2b, b2bs, vin, 256); // g4
    hipLaunchKernelGGL((node_gemm_kernel<true >), dim3(100, 4), dim3(128), 0, stream, vin, Wp3a, b3a,  t3,  256); // g5
    hipLaunchKernelGGL((node_gemm_kernel<false>), dim3(100, 4), dim3(128), 0, stream, t3,  Wp3b, b3b,  v2,  256); // g6
    hipLaunchKernelGGL(node_gemm_dual_kernel, dim3(100, 8), dim3(128), 0, stream,
                       v2, Wp4r, b4ap, C4, Wp4s, S_Vs);                                                           // g7d
    // ---- phase B (LDS t2 once, K=256 GEMM, MFMA projection) ----
    hipLaunchKernelGGL(edge_phaseB_kernel, dim3(3200, 2), dim3(256), 0, stream,
                       S_Hs, S_Vs, S_U, C4, Wpz, Wfp, bfv, out);
}

// Round 11
// 299.442 us; speedup vs baseline: 1.2450x; 1.2450x over previous
//
#include <hip/hip_runtime.h>
#include <hip/hip_bf16.h>
#include <stdint.h>

// ---------------------------------------------------------------------------
// NRI-style MLP encoder. B=32, T=50, N=100, D=4, E=9900, H=256. fp32 I/O.
// R7 formulation (send terms are node GEMMs; only edge GEMM is K=256 t2@Wpz).
// R11 = R10 + spill fix: R10's fully-unrolled K-loop (32 hoisted ds_read_b128
// + 64-AGPR acc) overflowed the (256,3) 170-reg cap -> 167 B/thread scratch
// (WRITE 274 MB, FETCH 101 MB). K-loop now `#pragma unroll 2` to cap the live
// window. VALU dedup from R10 is kept (t2 built once in LDS; VALUBusy already
// dropped 57->27% in R10).
// ---------------------------------------------------------------------------

typedef __attribute__((ext_vector_type(8))) short short8;
typedef __attribute__((ext_vector_type(4))) float float4v;
typedef __attribute__((ext_vector_type(4))) unsigned short ushort4v;

__device__ inline float bf2f(unsigned short u) {
    union { unsigned int i; float f; } v; v.i = ((unsigned int)u) << 16; return v.f;
}
__device__ inline unsigned short f2bf(float f) {
    union { float f; unsigned int i; } v; v.f = f;
    unsigned int i = v.i;
    return (unsigned short)((i + 0x7FFFu + ((i >> 16) & 1u)) >> 16);
}

// ---------------------------------------------------------------------------
// MEGA-PREP: bx<2272 weight packs | <2528 Wpz=pack(w2b@w4a_e) | <2530 misc
// (Wfp/bfv/b4ap/b2bs) | rest repack x. fp32 in, bf16 packed out.
// ---------------------------------------------------------------------------
__global__ __launch_bounds__(256) void prep_kernel(
        const float* __restrict__ x,
        const float* __restrict__ w1a, const float* __restrict__ w1b,
        const float* __restrict__ w2a, const float* __restrict__ w2b,
        const float* __restrict__ w3a, const float* __restrict__ w3b,
        const float* __restrict__ w4a, const float* __restrict__ b4a,
        const float* __restrict__ w4b, const float* __restrict__ b4b,
        const float* __restrict__ wo,  const float* __restrict__ bo,
        const float* __restrict__ b2b,
        unsigned short* __restrict__ Wp1a, unsigned short* __restrict__ Wp1b,
        unsigned short* __restrict__ Wp2r, unsigned short* __restrict__ Wp2s,
        unsigned short* __restrict__ Wp2b, unsigned short* __restrict__ Wp3a,
        unsigned short* __restrict__ Wp3b, unsigned short* __restrict__ Wp4r,
        unsigned short* __restrict__ Wp4s, unsigned short* __restrict__ Wpz,
        unsigned short* __restrict__ Wfp, float* __restrict__ bfv,
        float* __restrict__ b4ap, float* __restrict__ b2bs,
        unsigned short* __restrict__ hin) {
    int bx = blockIdx.x;
    int tid = threadIdx.x;
    if (bx < 2272) {
        const float* W; unsigned short* Wp; int Kin; int b0;
        if      (bx <  224) { W = w1a;             Wp = Wp1a; Kin = 200; b0 = 0;    }
        else if (bx <  480) { W = w1b;             Wp = Wp1b; Kin = 256; b0 = 224;  }
        else if (bx <  736) { W = w2a;             Wp = Wp2r; Kin = 256; b0 = 480;  }
        else if (bx <  992) { W = w2a + 256 * 256; Wp = Wp2s; Kin = 256; b0 = 736;  }
        else if (bx < 1248) { W = w2b;             Wp = Wp2b; Kin = 256; b0 = 992;  }
        else if (bx < 1504) { W = w3a;             Wp = Wp3a; Kin = 256; b0 = 1248; }
        else if (bx < 1760) { W = w3b;             Wp = Wp3b; Kin = 256; b0 = 1504; }
        else if (bx < 2016) { W = w4a;             Wp = Wp4r; Kin = 256; b0 = 1760; }
        else                { W = w4a + 256 * 256; Wp = Wp4s; Kin = 256; b0 = 2016; }
        int idx = (bx - b0) * 256 + tid;
        int k = idx >> 8, n = idx & 255;
        unsigned short v = (k < Kin) ? f2bf(W[k * 256 + n]) : (unsigned short)0;
        Wp[((size_t)(k >> 5) * 256 + n) * 32 + (k & 31)] = v;
    } else if (bx < 2528) {
        int k = bx - 2272, c = tid;
        float s = 0.f;
        for (int t = 0; t < 256; ++t)
            s += w2b[k * 256 + t] * w4a[(size_t)(512 + t) * 256 + c];
        Wpz[((size_t)(k >> 5) * 256 + c) * 32 + (k & 31)] = f2bf(s);
    } else if (bx < 2530) {
        int k = tid;
        if (bx == 2528) {
            float a[4] = {0.f, 0.f, 0.f, 0.f};
            for (int c = 0; c < 256; ++c) {
                float wv = w4b[k * 256 + c];
                #pragma unroll
                for (int o = 0; o < 4; ++o) a[o] += wv * wo[c * 4 + o];
            }
            #pragma unroll
            for (int n = 0; n < 16; ++n)
                Wfp[(size_t)(k >> 5) * 512 + n * 32 + (k & 31)] =
                    (n < 4) ? f2bf(a[n]) : (unsigned short)0;
            if (k < 4) {
                float s = bo[k];
                for (int c = 0; c < 256; ++c) s += b4b[c] * wo[c * 4 + k];
                bfv[k] = s;
            }
        } else {
            float s = b4a[k];
            for (int t = 0; t < 256; ++t)
                s += b2b[t] * w4a[(size_t)(512 + t) * 256 + k];
            b4ap[k] = s;
            b2bs[k] = 0.99f * b2b[k];
        }
    } else {
        int idx = (bx - 2530) * 256 + tid;
        if (idx < 3200 * 224) {
            int row = idx / 224;
            int c = idx - row * 224;
            int b = row / 100, n = row - b * 100;
            unsigned short v = 0;
            if (c < 200) {
                int t = c >> 2, d = c & 3;
                v = f2bf(x[(((size_t)(b * 50 + t)) * 100 + n) * 4 + d]);
            }
            hin[(size_t)row * 224 + c] = v;
        }
    }
}

// ---------------------------------------------------------------------------
// Node GEMM: C = act(A@Wp + bias). Grid (100,4), block 128.
// ---------------------------------------------------------------------------
template <bool RELU>
__global__ __launch_bounds__(128) void node_gemm_kernel(
        const unsigned short* __restrict__ A,
        const unsigned short* __restrict__ Bp,
        const float* __restrict__ bias,
        unsigned short* __restrict__ C, int K) {
    const int tid  = threadIdx.x;
    const int wave = tid >> 6;
    const int lane = tid & 63;
    const int l15  = lane & 15;
    const int quad = lane >> 4;
    const int m0   = blockIdx.x * 32 + wave * 16;
    const int n0   = blockIdx.y * 64;
    const int koff = quad * 8;

    float4v acc[4];
    #pragma unroll
    for (int ni = 0; ni < 4; ++ni) acc[ni] = (float4v)(0.0f);

    const int KB = K >> 5;
    for (int kb = 0; kb < KB; ++kb) {
        short8 af = *(const short8*)(A + (size_t)(m0 + l15) * K + kb * 32 + koff);
        short8 bf[4];
        #pragma unroll
        for (int ni = 0; ni < 4; ++ni)
            bf[ni] = *(const short8*)(Bp + ((size_t)kb * 256 + n0 + ni * 16 + l15) * 32 + koff);
        #pragma unroll
        for (int ni = 0; ni < 4; ++ni)
            acc[ni] = __builtin_amdgcn_mfma_f32_16x16x32_bf16(af, bf[ni], acc[ni], 0, 0, 0);
    }

    #pragma unroll
    for (int ni = 0; ni < 4; ++ni) {
        int col = n0 + ni * 16 + l15;
        float bv = bias[col];
        #pragma unroll
        for (int r = 0; r < 4; ++r) {
            float v = acc[ni][r] + bv;
            if (RELU) v = v > 0.f ? v : 0.f;
            C[(size_t)(m0 + quad * 4 + r) * 256 + col] = f2bf(v);
        }
    }
}

// ---- dual node GEMM (shared A, K=256): y<4 -> C0=A@Bp0+bias0; y>=4 -> C1=A@Bp1 ----
__global__ __launch_bounds__(128) void node_gemm_dual_kernel(
        const unsigned short* __restrict__ A,
        const unsigned short* __restrict__ Bp0, const float* __restrict__ bias0,
        unsigned short* __restrict__ C0,
        const unsigned short* __restrict__ Bp1, unsigned short* __restrict__ C1) {
    const int tid  = threadIdx.x;
    const int wave = tid >> 6;
    const int lane = tid & 63;
    const int l15  = lane & 15;
    const int quad = lane >> 4;
    const int m0   = blockIdx.x * 32 + wave * 16;
    const int sel  = blockIdx.y >> 2;
    const int n0   = (blockIdx.y & 3) * 64;
    const int koff = quad * 8;
    const unsigned short* Bp = sel ? Bp1 : Bp0;
    unsigned short* C = sel ? C1 : C0;

    float4v acc[4];
    #pragma unroll
    for (int ni = 0; ni < 4; ++ni) acc[ni] = (float4v)(0.0f);

    for (int kb = 0; kb < 8; ++kb) {
        short8 af = *(const short8*)(A + (size_t)(m0 + l15) * 256 + kb * 32 + koff);
        short8 bf[4];
        #pragma unroll
        for (int ni = 0; ni < 4; ++ni)
            bf[ni] = *(const short8*)(Bp + ((size_t)kb * 256 + n0 + ni * 16 + l15) * 32 + koff);
        #pragma unroll
        for (int ni = 0; ni < 4; ++ni)
            acc[ni] = __builtin_amdgcn_mfma_f32_16x16x32_bf16(af, bf[ni], acc[ni], 0, 0, 0);
    }

    #pragma unroll
    for (int ni = 0; ni < 4; ++ni) {
        int col = n0 + ni * 16 + l15;
        float bv = sel ? 0.f : bias0[col];
        #pragma unroll
        for (int r = 0; r < 4; ++r)
            C[(size_t)(m0 + quad * 4 + r) * 256 + col] = f2bf(acc[ni][r] + bv);
    }
}

// ---------------------------------------------------------------------------
// colsum: Ssc[g,c] = 0.01*( sum_j relu(U[g,c]+Hs[b,j,c]) - relu(U[g,c]+Hs[b,i,c]) )
// ---------------------------------------------------------------------------
__global__ __launch_bounds__(256) void colsum_kernel(
        const unsigned short* __restrict__ U, const unsigned short* __restrict__ Hs,
        unsigned short* __restrict__ Ssc) {
    const int g = blockIdx.x;
    const int b = g / 100, i = g - b * 100;
    const int c = threadIdx.x;
    const float u = bf2f(U[(size_t)g * 256 + c]);
    const unsigned short* base = Hs + (size_t)b * 100 * 256 + c;
    float s = 0.f;
    #pragma unroll 4
    for (int j = 0; j < 100; ++j) {
        float v = u + bf2f(base[(size_t)j * 256]);
        s += (v > 0.f ? v : 0.f);
    }
    float vi = u + bf2f(base[(size_t)i * 256]);
    s -= (vi > 0.f ? vi : 0.f);
    Ssc[(size_t)g * 256 + c] = f2bf(s * 0.01f);
}

// ---------------------------------------------------------------------------
// Phase B: grid (3200,2), block 256 (4 waves x 64 cols), M=64 (<=50 real).
// stage0: t2 = relu(U_i + Hs_j) -> LDS ONCE (rows split by wave; pad rows 0).
// K-loop (#pragma unroll 2 -- spill guard): A via ds_read_b128, B = Wpz (L2).
// z4 = relu(C4_i + Vs_j + acc) -> LDS (aliases t2s after barrier);
// projection: 8 MFMA vs Wfp (w4b@wo, 16-col padded); lanes l15<4 store fp32.
// LDS 64x264x2 = 33792 B. launch_bounds(256,3): 170-reg cap.
// ---------------------------------------------------------------------------
__global__ __launch_bounds__(256, 3) void edge_phaseB_kernel(
        const unsigned short* __restrict__ Hs, const unsigned short* __restrict__ Vs,
        const unsigned short* __restrict__ U, const unsigned short* __restrict__ C4,
        const unsigned short* __restrict__ Wpz, const unsigned short* __restrict__ Wfp,
        const float* __restrict__ bfv,
        float* __restrict__ out) {
    __shared__ __align__(16) unsigned short t2s[64 * 264]; // 33792 B (z4 aliases later)
    const int g = blockIdx.x, hb = blockIdx.y;
    const int b = g / 100, nr = g - b * 100;
    const int nrows = hb ? 49 : 50;
    const int k0 = hb * 50;
    const int tid  = threadIdx.x;
    const int wave = tid >> 6;
    const int lane = tid & 63;
    const int l15  = lane & 15;
    const int quad = lane >> 4;
    const int n0   = wave * 64;
    const int koff = quad * 8;

    // ---- stage 0: build t2 tile ONCE (coalesced 8B/lane; pad rows zeroed) ----
    {
        const int c = lane * 4;
        ushort4v uv = *(const ushort4v*)(U + (size_t)g * 256 + c);
        float u0 = bf2f(uv[0]), u1 = bf2f(uv[1]), u2 = bf2f(uv[2]), u3 = bf2f(uv[3]);
        for (int r = wave; r < 64; r += 4) {
            ushort4v tv = (ushort4v)(unsigned short)0;
            if (r < nrows) {
                int k = k0 + r;
                int j = k + (k >= nr ? 1 : 0);
                ushort4v hv = *(const ushort4v*)(Hs + (size_t)(b * 100 + j) * 256 + c);
                float t0 = u0 + bf2f(hv[0]); tv[0] = f2bf(t0 > 0.f ? t0 : 0.f);
                float t1 = u1 + bf2f(hv[1]); tv[1] = f2bf(t1 > 0.f ? t1 : 0.f);
                float t2 = u2 + bf2f(hv[2]); tv[2] = f2bf(t2 > 0.f ? t2 : 0.f);
                float t3 = u3 + bf2f(hv[3]); tv[3] = f2bf(t3 > 0.f ? t3 : 0.f);
            }
            *(ushort4v*)(&t2s[r * 264 + c]) = tv;
        }
    }
    __syncthreads();

    // ---- K-loop: z4 GEMM (K=256), A from LDS, B from L2 ----
    float4v acc[4][4];
    #pragma unroll
    for (int mi = 0; mi < 4; ++mi)
        #pragma unroll
        for (int ni = 0; ni < 4; ++ni) acc[mi][ni] = (float4v)(0.0f);

    #pragma unroll 2              // spill guard: full unroll overflowed 170-reg cap (R10)
    for (int kb = 0; kb < 8; ++kb) {
        short8 af[4], bf[4];
        #pragma unroll
        for (int mi = 0; mi < 4; ++mi)
            af[mi] = *(const short8*)(&t2s[(mi * 16 + l15) * 264 + kb * 32 + koff]);
        #pragma unroll
        for (int ni = 0; ni < 4; ++ni)
            bf[ni] = *(const short8*)(Wpz + ((size_t)kb * 256 + n0 + ni * 16 + l15) * 32 + koff);
        #pragma unroll
        for (int mi = 0; mi < 4; ++mi)
            #pragma unroll
            for (int ni = 0; ni < 4; ++ni)
                acc[mi][ni] = __builtin_amdgcn_mfma_f32_16x16x32_bf16(af[mi], bf[ni], acc[mi][ni], 0, 0, 0);
    }
    __syncthreads();            // all t2s A-reads done; z4 aliases t2s below

    // ---- z4 = relu(C4_i + Vs_j + acc) -> LDS (C-layout) ----
    float c4v[4];
    #pragma unroll
    for (int ni = 0; ni < 4; ++ni)
        c4v[ni] = bf2f(C4[(size_t)g * 256 + n0 + ni * 16 + l15]);
    #pragma unroll
    for (int mi = 0; mi < 4; ++mi) {
        #pragma unroll
        for (int r = 0; r < 4; ++r) {
            int row = mi * 16 + quad * 4 + r;          // local edge idx (C-layout)
            int k = k0 + row;
            int j = (row < nrows) ? (k + (k >= nr ? 1 : 0)) : 0;
            const unsigned short* vsr = Vs + (size_t)(b * 100 + j) * 256;
            #pragma unroll
            for (int ni = 0; ni < 4; ++ni) {
                int col = n0 + ni * 16 + l15;
                float zv = c4v[ni] + bf2f(vsr[col]) + acc[mi][ni][r];
                zv = zv > 0.f ? zv : 0.f;
                t2s[row * 264 + col] = f2bf(zv);
            }
        }
    }
    __syncthreads();

    // ---- projection: wave handles rows wave*16..+15; 8 MFMA vs Wfp ----
    float4v pacc = (float4v)(0.0f);
    #pragma unroll
    for (int kb = 0; kb < 8; ++kb) {
        short8 za = *(const short8*)(&t2s[(wave * 16 + l15) * 264 + kb * 32 + koff]);
        short8 wb = *(const short8*)(Wfp + (size_t)kb * 512 + l15 * 32 + koff);
        pacc = __builtin_amdgcn_mfma_f32_16x16x32_bf16(za, wb, pacc, 0, 0, 0);
    }

    if (l15 < 4) {
        float bv = bfv[l15];
        #pragma unroll
        for (int r = 0; r < 4; ++r) {
            int row = wave * 16 + quad * 4 + r;
            if (row < nrows)
                out[((size_t)b * 9900 + nr * 99 + k0 + row) * 4 + l15] = pacc[r] + bv;
        }
    }
}

extern "C" void kernel_launch(void* const* d_in, const int* in_sizes, int n_in,
                              void* d_out, int out_size, void* d_ws, size_t ws_size,
                              hipStream_t stream) {
    const float* x   = (const float*)d_in[0];
    const float* w1a = (const float*)d_in[3];
    const float* b1a = (const float*)d_in[4];
    const float* w1b = (const float*)d_in[5];
    const float* b1b = (const float*)d_in[6];
    const float* w2a = (const float*)d_in[7];
    const float* b2a = (const float*)d_in[8];
    const float* w2b = (const float*)d_in[9];
    const float* b2b = (const float*)d_in[10];
    const float* w3a = (const float*)d_in[11];
    const float* b3a = (const float*)d_in[12];
    const float* w3b = (const float*)d_in[13];
    const float* b3b = (const float*)d_in[14];
    const float* w4a = (const float*)d_in[15];
    const float* b4a = (const float*)d_in[16];
    const float* w4b = (const float*)d_in[17];
    const float* b4b = (const float*)d_in[18];
    const float* wo  = (const float*)d_in[19];
    const float* bo  = (const float*)d_in[20];
    float* out = (float*)d_out;
    (void)in_sizes; (void)n_in; (void)out_size; (void)ws_size;

    char* ws = (char*)d_ws;
    size_t off = 0;
    auto alloc = [&](size_t bytes) {
        size_t o = off;
        off = (off + bytes + 255) & ~(size_t)255;
        return o;
    };
    const size_t SLOT_BF = (size_t)3200 * 256 * 2;   // 1.64 MB
    unsigned short* S_h  = (unsigned short*)(ws + alloc(SLOT_BF)); // h
    unsigned short* S_U  = (unsigned short*)(ws + alloc(SLOT_BF)); // U
    unsigned short* S_Hs = (unsigned short*)(ws + alloc(SLOT_BF)); // Hs
    unsigned short* S_Vs = (unsigned short*)(ws + alloc(SLOT_BF)); // Vs
    unsigned short* S_3  = (unsigned short*)(ws + alloc(SLOT_BF)); // t1 -> vin -> v2
    unsigned short* S_4  = (unsigned short*)(ws + alloc(SLOT_BF)); // hin -> Ssc -> t3 -> C4
    unsigned short* Wp1a = (unsigned short*)(ws + alloc(224 * 256 * 2));
    unsigned short* Wp1b = (unsigned short*)(ws + alloc(256 * 256 * 2));
    unsigned short* Wp2r = (unsigned short*)(ws + alloc(256 * 256 * 2));
    unsigned short* Wp2s = (unsigned short*)(ws + alloc(256 * 256 * 2));
    unsigned short* Wp2b = (unsigned short*)(ws + alloc(256 * 256 * 2));
    unsigned short* Wp3a = (unsigned short*)(ws + alloc(256 * 256 * 2));
    unsigned short* Wp3b = (unsigned short*)(ws + alloc(256 * 256 * 2));
    unsigned short* Wp4r = (unsigned short*)(ws + alloc(256 * 256 * 2));
    unsigned short* Wp4s = (unsigned short*)(ws + alloc(256 * 256 * 2));
    unsigned short* Wpz  = (unsigned short*)(ws + alloc(256 * 256 * 2));
    unsigned short* Wfp  = (unsigned short*)(ws + alloc(8 * 16 * 32 * 2));
    float*          bfv  = (float*)(ws + alloc(4 * 4));
    float*          b4ap = (float*)(ws + alloc(256 * 4));
    float*          b2bs = (float*)(ws + alloc(256 * 4));
    // total ~11.13 MB (<= 11.2 proven safe)

    unsigned short* hin = S_4;   // [prep, g1]
    unsigned short* Ssc = S_4;   // [colsum, g4]
    unsigned short* t3  = S_4;   // [g5, g6]
    unsigned short* C4  = S_4;   // [g7d, phaseB]
    unsigned short* t1  = S_3;   // [g1, g2]
    unsigned short* vin = S_3;   // [g4, g5]
    unsigned short* v2  = S_3;   // [g6, g7d]

    // ---- prep (1 launch: packs + fusions + repack) ----
    hipLaunchKernelGGL(prep_kernel, dim3(5330), dim3(256), 0, stream,
                       x, w1a, w1b, w2a, w2b, w3a, w3b, w4a, b4a, w4b, b4b, wo, bo, b2b,
                       Wp1a, Wp1b, Wp2r, Wp2s, Wp2b, Wp3a, Wp3b, Wp4r, Wp4s, Wpz,
                       Wfp, bfv, b4ap, b2bs, hin);

    // ---- node MLP1, then U & Hs (dual) ----
    hipLaunchKernelGGL((node_gemm_kernel<true >), dim3(100, 4), dim3(128), 0, stream, hin, Wp1a, b1a, t1,  224); // g1
    hipLaunchKernelGGL((node_gemm_kernel<false>), dim3(100, 4), dim3(128), 0, stream, t1,  Wp1b, b1b, S_h, 256); // g2
    hipLaunchKernelGGL(node_gemm_dual_kernel, dim3(100, 8), dim3(128), 0, stream,
                       S_h, Wp2r, b2a, S_U, Wp2s, S_Hs);                                                          // g3d
    // ---- colsum (edge aggregation without GEMM) ----
    hipLaunchKernelGGL(colsum_kernel, dim3(3200), dim3(256), 0, stream, S_U, S_Hs, Ssc);
    // ---- vin + node MLP3, then C4 & Vs (dual) ----
    hipLaunchKernelGGL((node_gemm_kernel<false>), dim3(100, 4), dim3(128), 0, stream, Ssc, Wp2b, b2bs, vin, 256); // g4
    hipLaunchKernelGGL((node_gemm_kernel<true >), dim3(100, 4), dim3(128), 0, stream, vin, Wp3a, b3a,  t3,  256); // g5
    hipLaunchKernelGGL((node_gemm_kernel<false>), dim3(100, 4), dim3(128), 0, stream, t3,  Wp3b, b3b,  v2,  256); // g6
    hipLaunchKernelGGL(node_gemm_dual_kernel, dim3(100, 8), dim3(128), 0, stream,
                       v2, Wp4r, b4ap, C4, Wp4s, S_Vs);                                                           // g7d
    // ---- phase B (LDS t2 once, K=256 GEMM, MFMA projection) ----
    hipLaunchKernelGGL(edge_phaseB_kernel, dim3(3200, 2), dim3(256), 0, stream,
                       S_Hs, S_Vs, S_U, C4, Wpz, Wfp, bfv, out);
}

// Round 12
// 275.813 us; speedup vs baseline: 1.3517x; 1.0857x over previous
//
#include <hip/hip_runtime.h>
#include <hip/hip_bf16.h>
#include <stdint.h>

// ---------------------------------------------------------------------------
// NRI-style MLP encoder. B=32, T=50, N=100, D=4, E=9900, H=256. fp32 I/O.
// R7 formulation (send terms are node GEMMs; only edge GEMM is K=256 t2@Wpz).
// R12: node-level pipeline FUSED into 2 kernels (was 8 launches ~144us of
// launch/latency-bound 0.4-GFLOP GEMMs):
//   nodeA: t1 -> h -> (U, Hs dual)   [t1, h LDS-only; h global slot deleted]
//   nodeC: vin -> t3 -> v2 -> (C4, Vs dual)   [all intermediates LDS-only]
// Grid 200 x 256thr, 16 rows/block, wave = 16 rows x 64 cols.
// 5 dispatches total: prep, nodeA, colsum, nodeC, phaseB.
// phaseB byte-identical to R11 (137.8us: no spill, unroll-2 guard).
// S_4 slot: hin [prep,nodeA] -> Ssc [colsum,nodeC] -> C4 [nodeC,phaseB]
// (nodeC reads its own Ssc rows before writing C4 to the same rows).
// ---------------------------------------------------------------------------

typedef __attribute__((ext_vector_type(8))) short short8;
typedef __attribute__((ext_vector_type(4))) float float4v;
typedef __attribute__((ext_vector_type(4))) unsigned short ushort4v;

__device__ inline float bf2f(unsigned short u) {
    union { unsigned int i; float f; } v; v.i = ((unsigned int)u) << 16; return v.f;
}
__device__ inline unsigned short f2bf(float f) {
    union { float f; unsigned int i; } v; v.f = f;
    unsigned int i = v.i;
    return (unsigned short)((i + 0x7FFFu + ((i >> 16) & 1u)) >> 16);
}

// ---------------------------------------------------------------------------
// MEGA-PREP: bx<2272 weight packs | <2528 Wpz=pack(w2b@w4a_e) | <2530 misc
// (Wfp/bfv/b4ap/b2bs) | rest repack x. fp32 in, bf16 packed out.
// ---------------------------------------------------------------------------
__global__ __launch_bounds__(256) void prep_kernel(
        const float* __restrict__ x,
        const float* __restrict__ w1a, const float* __restrict__ w1b,
        const float* __restrict__ w2a, const float* __restrict__ w2b,
        const float* __restrict__ w3a, const float* __restrict__ w3b,
        const float* __restrict__ w4a, const float* __restrict__ b4a,
        const float* __restrict__ w4b, const float* __restrict__ b4b,
        const float* __restrict__ wo,  const float* __restrict__ bo,
        const float* __restrict__ b2b,
        unsigned short* __restrict__ Wp1a, unsigned short* __restrict__ Wp1b,
        unsigned short* __restrict__ Wp2r, unsigned short* __restrict__ Wp2s,
        unsigned short* __restrict__ Wp2b, unsigned short* __restrict__ Wp3a,
        unsigned short* __restrict__ Wp3b, unsigned short* __restrict__ Wp4r,
        unsigned short* __restrict__ Wp4s, unsigned short* __restrict__ Wpz,
        unsigned short* __restrict__ Wfp, float* __restrict__ bfv,
        float* __restrict__ b4ap, float* __restrict__ b2bs,
        unsigned short* __restrict__ hin) {
    int bx = blockIdx.x;
    int tid = threadIdx.x;
    if (bx < 2272) {
        const float* W; unsigned short* Wp; int Kin; int b0;
        if      (bx <  224) { W = w1a;             Wp = Wp1a; Kin = 200; b0 = 0;    }
        else if (bx <  480) { W = w1b;             Wp = Wp1b; Kin = 256; b0 = 224;  }
        else if (bx <  736) { W = w2a;             Wp = Wp2r; Kin = 256; b0 = 480;  }
        else if (bx <  992) { W = w2a + 256 * 256; Wp = Wp2s; Kin = 256; b0 = 736;  }
        else if (bx < 1248) { W = w2b;             Wp = Wp2b; Kin = 256; b0 = 992;  }
        else if (bx < 1504) { W = w3a;             Wp = Wp3a; Kin = 256; b0 = 1248; }
        else if (bx < 1760) { W = w3b;             Wp = Wp3b; Kin = 256; b0 = 1504; }
        else if (bx < 2016) { W = w4a;             Wp = Wp4r; Kin = 256; b0 = 1760; }
        else                { W = w4a + 256 * 256; Wp = Wp4s; Kin = 256; b0 = 2016; }
        int idx = (bx - b0) * 256 + tid;
        int k = idx >> 8, n = idx & 255;
        unsigned short v = (k < Kin) ? f2bf(W[k * 256 + n]) : (unsigned short)0;
        Wp[((size_t)(k >> 5) * 256 + n) * 32 + (k & 31)] = v;
    } else if (bx < 2528) {
        int k = bx - 2272, c = tid;
        float s = 0.f;
        for (int t = 0; t < 256; ++t)
            s += w2b[k * 256 + t] * w4a[(size_t)(512 + t) * 256 + c];
        Wpz[((size_t)(k >> 5) * 256 + c) * 32 + (k & 31)] = f2bf(s);
    } else if (bx < 2530) {
        int k = tid;
        if (bx == 2528) {
            float a[4] = {0.f, 0.f, 0.f, 0.f};
            for (int c = 0; c < 256; ++c) {
                float wv = w4b[k * 256 + c];
                #pragma unroll
                for (int o = 0; o < 4; ++o) a[o] += wv * wo[c * 4 + o];
            }
            #pragma unroll
            for (int n = 0; n < 16; ++n)
                Wfp[(size_t)(k >> 5) * 512 + n * 32 + (k & 31)] =
                    (n < 4) ? f2bf(a[n]) : (unsigned short)0;
            if (k < 4) {
                float s = bo[k];
                for (int c = 0; c < 256; ++c) s += b4b[c] * wo[c * 4 + k];
                bfv[k] = s;
            }
        } else {
            float s = b4a[k];
            for (int t = 0; t < 256; ++t)
                s += b2b[t] * w4a[(size_t)(512 + t) * 256 + k];
            b4ap[k] = s;
            b2bs[k] = 0.99f * b2b[k];
        }
    } else {
        int idx = (bx - 2530) * 256 + tid;
        if (idx < 3200 * 224) {
            int row = idx / 224;
            int c = idx - row * 224;
            int b = row / 100, n = row - b * 100;
            unsigned short v = 0;
            if (c < 200) {
                int t = c >> 2, d = c & 3;
                v = f2bf(x[(((size_t)(b * 50 + t)) * 100 + n) * 4 + d]);
            }
            hin[(size_t)row * 224 + c] = v;
        }
    }
}

// ---------------------------------------------------------------------------
// nodeA (fused): rows m0=bx*16. t1=relu(hin@W1a+b1a) [LDS] ->
// h=t1@W1b+b1b [LDS] -> U=h@W2r+b2a, Hs=h@W2s (dual, global).
// Wave: 16 rows x 64 cols (4 frags); dual stage: 8 frags.
// ---------------------------------------------------------------------------
__global__ __launch_bounds__(256) void node_fusedA_kernel(
        const unsigned short* __restrict__ hin,
        const unsigned short* __restrict__ Wp1a, const float* __restrict__ b1a,
        const unsigned short* __restrict__ Wp1b, const float* __restrict__ b1b,
        const unsigned short* __restrict__ Wp2r, const float* __restrict__ b2a,
        const unsigned short* __restrict__ Wp2s,
        unsigned short* __restrict__ U, unsigned short* __restrict__ Hs) {
    __shared__ __align__(16) unsigned short t1s[16 * 264];
    __shared__ __align__(16) unsigned short hs2[16 * 264];
    const int m0 = blockIdx.x * 16;
    const int tid  = threadIdx.x;
    const int wave = tid >> 6;
    const int lane = tid & 63;
    const int l15  = lane & 15;
    const int quad = lane >> 4;
    const int n0   = wave * 64;
    const int koff = quad * 8;

    // ---- S1: t1 = relu(hin@W1a + b1a), K=224 ----
    {
        float4v acc[4];
        #pragma unroll
        for (int ni = 0; ni < 4; ++ni) acc[ni] = (float4v)(0.0f);
        for (int kb = 0; kb < 7; ++kb) {
            short8 af = *(const short8*)(hin + (size_t)(m0 + l15) * 224 + kb * 32 + koff);
            short8 bf[4];
            #pragma unroll
            for (int ni = 0; ni < 4; ++ni)
                bf[ni] = *(const short8*)(Wp1a + ((size_t)kb * 256 + n0 + ni * 16 + l15) * 32 + koff);
            #pragma unroll
            for (int ni = 0; ni < 4; ++ni)
                acc[ni] = __builtin_amdgcn_mfma_f32_16x16x32_bf16(af, bf[ni], acc[ni], 0, 0, 0);
        }
        #pragma unroll
        for (int ni = 0; ni < 4; ++ni) {
            int col = n0 + ni * 16 + l15;
            float bv = b1a[col];
            #pragma unroll
            for (int r = 0; r < 4; ++r) {
                float v = acc[ni][r] + bv;
                v = v > 0.f ? v : 0.f;
                t1s[(quad * 4 + r) * 264 + col] = f2bf(v);
            }
        }
    }
    __syncthreads();

    // ---- S2: h = t1@W1b + b1b ----
    {
        float4v acc[4];
        #pragma unroll
        for (int ni = 0; ni < 4; ++ni) acc[ni] = (float4v)(0.0f);
        for (int kb = 0; kb < 8; ++kb) {
            short8 af = *(const short8*)(&t1s[l15 * 264 + kb * 32 + koff]);
            short8 bf[4];
            #pragma unroll
            for (int ni = 0; ni < 4; ++ni)
                bf[ni] = *(const short8*)(Wp1b + ((size_t)kb * 256 + n0 + ni * 16 + l15) * 32 + koff);
            #pragma unroll
            for (int ni = 0; ni < 4; ++ni)
                acc[ni] = __builtin_amdgcn_mfma_f32_16x16x32_bf16(af, bf[ni], acc[ni], 0, 0, 0);
        }
        #pragma unroll
        for (int ni = 0; ni < 4; ++ni) {
            int col = n0 + ni * 16 + l15;
            float bv = b1b[col];
            #pragma unroll
            for (int r = 0; r < 4; ++r)
                hs2[(quad * 4 + r) * 264 + col] = f2bf(acc[ni][r] + bv);
        }
    }
    __syncthreads();

    // ---- S3 (dual): U = h@W2r + b2a ; Hs = h@W2s ----
    {
        float4v aU[4], aH[4];
        #pragma unroll
        for (int ni = 0; ni < 4; ++ni) { aU[ni] = (float4v)(0.0f); aH[ni] = (float4v)(0.0f); }
        for (int kb = 0; kb < 8; ++kb) {
            short8 af = *(const short8*)(&hs2[l15 * 264 + kb * 32 + koff]);
            #pragma unroll
            for (int ni = 0; ni < 4; ++ni) {
                short8 bu = *(const short8*)(Wp2r + ((size_t)kb * 256 + n0 + ni * 16 + l15) * 32 + koff);
                short8 bh = *(const short8*)(Wp2s + ((size_t)kb * 256 + n0 + ni * 16 + l15) * 32 + koff);
                aU[ni] = __builtin_amdgcn_mfma_f32_16x16x32_bf16(af, bu, aU[ni], 0, 0, 0);
                aH[ni] = __builtin_amdgcn_mfma_f32_16x16x32_bf16(af, bh, aH[ni], 0, 0, 0);
            }
        }
        #pragma unroll
        for (int ni = 0; ni < 4; ++ni) {
            int col = n0 + ni * 16 + l15;
            float bv = b2a[col];
            #pragma unroll
            for (int r = 0; r < 4; ++r) {
                size_t o = (size_t)(m0 + quad * 4 + r) * 256 + col;
                U[o]  = f2bf(aU[ni][r] + bv);
                Hs[o] = f2bf(aH[ni][r]);
            }
        }
    }
}

// ---------------------------------------------------------------------------
// nodeC (fused): rows m0=bx*16. vin=Ssc@W2b+b2bs [LDS] -> t3=relu(vin@W3a+b3a)
// [LDS] -> v2=t3@W3b+b3b [LDS] -> C4=v2@W4r+b4ap, Vs=v2@W4s (dual, global).
// ---------------------------------------------------------------------------
__global__ __launch_bounds__(256) void node_fusedC_kernel(
        const unsigned short* __restrict__ Ssc,
        const unsigned short* __restrict__ Wp2b, const float* __restrict__ b2bs,
        const unsigned short* __restrict__ Wp3a, const float* __restrict__ b3a,
        const unsigned short* __restrict__ Wp3b, const float* __restrict__ b3b,
        const unsigned short* __restrict__ Wp4r, const float* __restrict__ b4ap,
        const unsigned short* __restrict__ Wp4s,
        unsigned short* __restrict__ C4, unsigned short* __restrict__ Vs) {
    __shared__ __align__(16) unsigned short buf0[16 * 264];
    __shared__ __align__(16) unsigned short buf1[16 * 264];
    const int m0 = blockIdx.x * 16;
    const int tid  = threadIdx.x;
    const int wave = tid >> 6;
    const int lane = tid & 63;
    const int l15  = lane & 15;
    const int quad = lane >> 4;
    const int n0   = wave * 64;
    const int koff = quad * 8;

    // ---- S1: vin = Ssc@W2b + b2bs -> buf0 ----
    {
        float4v acc[4];
        #pragma unroll
        for (int ni = 0; ni < 4; ++ni) acc[ni] = (float4v)(0.0f);
        for (int kb = 0; kb < 8; ++kb) {
            short8 af = *(const short8*)(Ssc + (size_t)(m0 + l15) * 256 + kb * 32 + koff);
            short8 bf[4];
            #pragma unroll
            for (int ni = 0; ni < 4; ++ni)
                bf[ni] = *(const short8*)(Wp2b + ((size_t)kb * 256 + n0 + ni * 16 + l15) * 32 + koff);
            #pragma unroll
            for (int ni = 0; ni < 4; ++ni)
                acc[ni] = __builtin_amdgcn_mfma_f32_16x16x32_bf16(af, bf[ni], acc[ni], 0, 0, 0);
        }
        #pragma unroll
        for (int ni = 0; ni < 4; ++ni) {
            int col = n0 + ni * 16 + l15;
            float bv = b2bs[col];
            #pragma unroll
            for (int r = 0; r < 4; ++r)
                buf0[(quad * 4 + r) * 264 + col] = f2bf(acc[ni][r] + bv);
        }
    }
    __syncthreads();

    // ---- S2: t3 = relu(vin@W3a + b3a) -> buf1 ----
    {
        float4v acc[4];
        #pragma unroll
        for (int ni = 0; ni < 4; ++ni) acc[ni] = (float4v)(0.0f);
        for (int kb = 0; kb < 8; ++kb) {
            short8 af = *(const short8*)(&buf0[l15 * 264 + kb * 32 + koff]);
            short8 bf[4];
            #pragma unroll
            for (int ni = 0; ni < 4; ++ni)
                bf[ni] = *(const short8*)(Wp3a + ((size_t)kb * 256 + n0 + ni * 16 + l15) * 32 + koff);
            #pragma unroll
            for (int ni = 0; ni < 4; ++ni)
                acc[ni] = __builtin_amdgcn_mfma_f32_16x16x32_bf16(af, bf[ni], acc[ni], 0, 0, 0);
        }
        #pragma unroll
        for (int ni = 0; ni < 4; ++ni) {
            int col = n0 + ni * 16 + l15;
            float bv = b3a[col];
            #pragma unroll
            for (int r = 0; r < 4; ++r) {
                float v = acc[ni][r] + bv;
                v = v > 0.f ? v : 0.f;
                buf1[(quad * 4 + r) * 264 + col] = f2bf(v);
            }
        }
    }
    __syncthreads();

    // ---- S3: v2 = t3@W3b + b3b -> buf0 ----
    {
        float4v acc[4];
        #pragma unroll
        for (int ni = 0; ni < 4; ++ni) acc[ni] = (float4v)(0.0f);
        for (int kb = 0; kb < 8; ++kb) {
            short8 af = *(const short8*)(&buf1[l15 * 264 + kb * 32 + koff]);
            short8 bf[4];
            #pragma unroll
            for (int ni = 0; ni < 4; ++ni)
                bf[ni] = *(const short8*)(Wp3b + ((size_t)kb * 256 + n0 + ni * 16 + l15) * 32 + koff);
            #pragma unroll
            for (int ni = 0; ni < 4; ++ni)
                acc[ni] = __builtin_amdgcn_mfma_f32_16x16x32_bf16(af, bf[ni], acc[ni], 0, 0, 0);
        }
        __syncthreads();   // buf0's S1 readers done long ago (S2 barrier); safe rewrite
        #pragma unroll
        for (int ni = 0; ni < 4; ++ni) {
            int col = n0 + ni * 16 + l15;
            float bv = b3b[col];
            #pragma unroll
            for (int r = 0; r < 4; ++r)
                buf0[(quad * 4 + r) * 264 + col] = f2bf(acc[ni][r] + bv);
        }
    }
    __syncthreads();

    // ---- S4 (dual): C4 = v2@W4r + b4ap ; Vs = v2@W4s ----
    {
        float4v aC[4], aV[4];
        #pragma unroll
        for (int ni = 0; ni < 4; ++ni) { aC[ni] = (float4v)(0.0f); aV[ni] = (float4v)(0.0f); }
        for (int kb = 0; kb < 8; ++kb) {
            short8 af = *(const short8*)(&buf0[l15 * 264 + kb * 32 + koff]);
            #pragma unroll
            for (int ni = 0; ni < 4; ++ni) {
                short8 bc = *(const short8*)(Wp4r + ((size_t)kb * 256 + n0 + ni * 16 + l15) * 32 + koff);
                short8 bv = *(const short8*)(Wp4s + ((size_t)kb * 256 + n0 + ni * 16 + l15) * 32 + koff);
                aC[ni] = __builtin_amdgcn_mfma_f32_16x16x32_bf16(af, bc, aC[ni], 0, 0, 0);
                aV[ni] = __builtin_amdgcn_mfma_f32_16x16x32_bf16(af, bv, aV[ni], 0, 0, 0);
            }
        }
        #pragma unroll
        for (int ni = 0; ni < 4; ++ni) {
            int col = n0 + ni * 16 + l15;
            float bv = b4ap[col];
            #pragma unroll
            for (int r = 0; r < 4; ++r) {
                size_t o = (size_t)(m0 + quad * 4 + r) * 256 + col;
                C4[o] = f2bf(aC[ni][r] + bv);
                Vs[o] = f2bf(aV[ni][r]);
            }
        }
    }
}

// ---------------------------------------------------------------------------
// colsum: Ssc[g,c] = 0.01*( sum_j relu(U[g,c]+Hs[b,j,c]) - relu(U[g,c]+Hs[b,i,c]) )
// ---------------------------------------------------------------------------
__global__ __launch_bounds__(256) void colsum_kernel(
        const unsigned short* __restrict__ U, const unsigned short* __restrict__ Hs,
        unsigned short* __restrict__ Ssc) {
    const int g = blockIdx.x;
    const int b = g / 100, i = g - b * 100;
    const int c = threadIdx.x;
    const float u = bf2f(U[(size_t)g * 256 + c]);
    const unsigned short* base = Hs + (size_t)b * 100 * 256 + c;
    float s = 0.f;
    #pragma unroll 4
    for (int j = 0; j < 100; ++j) {
        float v = u + bf2f(base[(size_t)j * 256]);
        s += (v > 0.f ? v : 0.f);
    }
    float vi = u + bf2f(base[(size_t)i * 256]);
    s -= (vi > 0.f ? vi : 0.f);
    Ssc[(size_t)g * 256 + c] = f2bf(s * 0.01f);
}

// ---------------------------------------------------------------------------
// Phase B (identical to R11): grid (3200,2), block 256, M=64 (<=50 real).
// stage0: t2 = relu(U_i + Hs_j) -> LDS ONCE. K-loop (unroll 2 spill guard):
// A via ds_read_b128, B = Wpz (L2). z4 -> LDS (aliases t2s); projection
// 8 MFMA vs Wfp; lanes l15<4 store fp32. LDS 33792 B; (256,3) 170-reg cap.
// ---------------------------------------------------------------------------
__global__ __launch_bounds__(256, 3) void edge_phaseB_kernel(
        const unsigned short* __restrict__ Hs, const unsigned short* __restrict__ Vs,
        const unsigned short* __restrict__ U, const unsigned short* __restrict__ C4,
        const unsigned short* __restrict__ Wpz, const unsigned short* __restrict__ Wfp,
        const float* __restrict__ bfv,
        float* __restrict__ out) {
    __shared__ __align__(16) unsigned short t2s[64 * 264]; // 33792 B (z4 aliases later)
    const int g = blockIdx.x, hb = blockIdx.y;
    const int b = g / 100, nr = g - b * 100;
    const int nrows = hb ? 49 : 50;
    const int k0 = hb * 50;
    const int tid  = threadIdx.x;
    const int wave = tid >> 6;
    const int lane = tid & 63;
    const int l15  = lane & 15;
    const int quad = lane >> 4;
    const int n0   = wave * 64;
    const int koff = quad * 8;

    // ---- stage 0: build t2 tile ONCE (coalesced 8B/lane; pad rows zeroed) ----
    {
        const int c = lane * 4;
        ushort4v uv = *(const ushort4v*)(U + (size_t)g * 256 + c);
        float u0 = bf2f(uv[0]), u1 = bf2f(uv[1]), u2 = bf2f(uv[2]), u3 = bf2f(uv[3]);
        for (int r = wave; r < 64; r += 4) {
            ushort4v tv = (ushort4v)(unsigned short)0;
            if (r < nrows) {
                int k = k0 + r;
                int j = k + (k >= nr ? 1 : 0);
                ushort4v hv = *(const ushort4v*)(Hs + (size_t)(b * 100 + j) * 256 + c);
                float t0 = u0 + bf2f(hv[0]); tv[0] = f2bf(t0 > 0.f ? t0 : 0.f);
                float t1 = u1 + bf2f(hv[1]); tv[1] = f2bf(t1 > 0.f ? t1 : 0.f);
                float t2 = u2 + bf2f(hv[2]); tv[2] = f2bf(t2 > 0.f ? t2 : 0.f);
                float t3 = u3 + bf2f(hv[3]); tv[3] = f2bf(t3 > 0.f ? t3 : 0.f);
            }
            *(ushort4v*)(&t2s[r * 264 + c]) = tv;
        }
    }
    __syncthreads();

    // ---- K-loop: z4 GEMM (K=256), A from LDS, B from L2 ----
    float4v acc[4][4];
    #pragma unroll
    for (int mi = 0; mi < 4; ++mi)
        #pragma unroll
        for (int ni = 0; ni < 4; ++ni) acc[mi][ni] = (float4v)(0.0f);

    #pragma unroll 2              // spill guard: full unroll overflowed 170-reg cap (R10)
    for (int kb = 0; kb < 8; ++kb) {
        short8 af[4], bf[4];
        #pragma unroll
        for (int mi = 0; mi < 4; ++mi)
            af[mi] = *(const short8*)(&t2s[(mi * 16 + l15) * 264 + kb * 32 + koff]);
        #pragma unroll
        for (int ni = 0; ni < 4; ++ni)
            bf[ni] = *(const short8*)(Wpz + ((size_t)kb * 256 + n0 + ni * 16 + l15) * 32 + koff);
        #pragma unroll
        for (int mi = 0; mi < 4; ++mi)
            #pragma unroll
            for (int ni = 0; ni < 4; ++ni)
                acc[mi][ni] = __builtin_amdgcn_mfma_f32_16x16x32_bf16(af[mi], bf[ni], acc[mi][ni], 0, 0, 0);
    }
    __syncthreads();            // all t2s A-reads done; z4 aliases t2s below

    // ---- z4 = relu(C4_i + Vs_j + acc) -> LDS (C-layout) ----
    float c4v[4];
    #pragma unroll
    for (int ni = 0; ni < 4; ++ni)
        c4v[ni] = bf2f(C4[(size_t)g * 256 + n0 + ni * 16 + l15]);
    #pragma unroll
    for (int mi = 0; mi < 4; ++mi) {
        #pragma unroll
        for (int r = 0; r < 4; ++r) {
            int row = mi * 16 + quad * 4 + r;          // local edge idx (C-layout)
            int k = k0 + row;
            int j = (row < nrows) ? (k + (k >= nr ? 1 : 0)) : 0;
            const unsigned short* vsr = Vs + (size_t)(b * 100 + j) * 256;
            #pragma unroll
            for (int ni = 0; ni < 4; ++ni) {
                int col = n0 + ni * 16 + l15;
                float zv = c4v[ni] + bf2f(vsr[col]) + acc[mi][ni][r];
                zv = zv > 0.f ? zv : 0.f;
                t2s[row * 264 + col] = f2bf(zv);
            }
        }
    }
    __syncthreads();

    // ---- projection: wave handles rows wave*16..+15; 8 MFMA vs Wfp ----
    float4v pacc = (float4v)(0.0f);
    #pragma unroll
    for (int kb = 0; kb < 8; ++kb) {
        short8 za = *(const short8*)(&t2s[(wave * 16 + l15) * 264 + kb * 32 + koff]);
        short8 wb = *(const short8*)(Wfp + (size_t)kb * 512 + l15 * 32 + koff);
        pacc = __builtin_amdgcn_mfma_f32_16x16x32_bf16(za, wb, pacc, 0, 0, 0);
    }

    if (l15 < 4) {
        float bv = bfv[l15];
        #pragma unroll
        for (int r = 0; r < 4; ++r) {
            int row = wave * 16 + quad * 4 + r;
            if (row < nrows)
                out[((size_t)b * 9900 + nr * 99 + k0 + row) * 4 + l15] = pacc[r] + bv;
        }
    }
}

extern "C" void kernel_launch(void* const* d_in, const int* in_sizes, int n_in,
                              void* d_out, int out_size, void* d_ws, size_t ws_size,
                              hipStream_t stream) {
    const float* x   = (const float*)d_in[0];
    const float* w1a = (const float*)d_in[3];
    const float* b1a = (const float*)d_in[4];
    const float* w1b = (const float*)d_in[5];
    const float* b1b = (const float*)d_in[6];
    const float* w2a = (const float*)d_in[7];
    const float* b2a = (const float*)d_in[8];
    const float* w2b = (const float*)d_in[9];
    const float* b2b = (const float*)d_in[10];
    const float* w3a = (const float*)d_in[11];
    const float* b3a = (const float*)d_in[12];
    const float* w3b = (const float*)d_in[13];
    const float* b3b = (const float*)d_in[14];
    const float* w4a = (const float*)d_in[15];
    const float* b4a = (const float*)d_in[16];
    const float* w4b = (const float*)d_in[17];
    const float* b4b = (const float*)d_in[18];
    const float* wo  = (const float*)d_in[19];
    const float* bo  = (const float*)d_in[20];
    float* out = (float*)d_out;
    (void)in_sizes; (void)n_in; (void)out_size; (void)ws_size;

    char* ws = (char*)d_ws;
    size_t off = 0;
    auto alloc = [&](size_t bytes) {
        size_t o = off;
        off = (off + bytes + 255) & ~(size_t)255;
        return o;
    };
    const size_t SLOT_BF = (size_t)3200 * 256 * 2;   // 1.64 MB
    unsigned short* S_U  = (unsigned short*)(ws + alloc(SLOT_BF)); // U
    unsigned short* S_Hs = (unsigned short*)(ws + alloc(SLOT_BF)); // Hs
    unsigned short* S_Vs = (unsigned short*)(ws + alloc(SLOT_BF)); // Vs
    unsigned short* S_4  = (unsigned short*)(ws + alloc(SLOT_BF)); // hin -> Ssc -> C4
    unsigned short* Wp1a = (unsigned short*)(ws + alloc(224 * 256 * 2));
    unsigned short* Wp1b = (unsigned short*)(ws + alloc(256 * 256 * 2));
    unsigned short* Wp2r = (unsigned short*)(ws + alloc(256 * 256 * 2));
    unsigned short* Wp2s = (unsigned short*)(ws + alloc(256 * 256 * 2));
    unsigned short* Wp2b = (unsigned short*)(ws + alloc(256 * 256 * 2));
    unsigned short* Wp3a = (unsigned short*)(ws + alloc(256 * 256 * 2));
    unsigned short* Wp3b = (unsigned short*)(ws + alloc(256 * 256 * 2));
    unsigned short* Wp4r = (unsigned short*)(ws + alloc(256 * 256 * 2));
    unsigned short* Wp4s = (unsigned short*)(ws + alloc(256 * 256 * 2));
    unsigned short* Wpz  = (unsigned short*)(ws + alloc(256 * 256 * 2));
    unsigned short* Wfp  = (unsigned short*)(ws + alloc(8 * 16 * 32 * 2));
    float*          bfv  = (float*)(ws + alloc(4 * 4));
    float*          b4ap = (float*)(ws + alloc(256 * 4));
    float*          b2bs = (float*)(ws + alloc(256 * 4));
    // total ~8 MB (<= 11.2 proven safe)

    unsigned short* hin = S_4;   // [prep, nodeA]
    unsigned short* Ssc = S_4;   // [colsum, nodeC]
    unsigned short* C4  = S_4;   // [nodeC, phaseB] (block-local read-before-write)

    // ---- 5 dispatches ----
    hipLaunchKernelGGL(prep_kernel, dim3(5330), dim3(256), 0, stream,
                       x, w1a, w1b, w2a, w2b, w3a, w3b, w4a, b4a, w4b, b4b, wo, bo, b2b,
                       Wp1a, Wp1b, Wp2r, Wp2s, Wp2b, Wp3a, Wp3b, Wp4r, Wp4s, Wpz,
                       Wfp, bfv, b4ap, b2bs, hin);
    hipLaunchKernelGGL(node_fusedA_kernel, dim3(200), dim3(256), 0, stream,
                       hin, Wp1a, b1a, Wp1b, b1b, Wp2r, b2a, Wp2s, S_U, S_Hs);
    hipLaunchKernelGGL(colsum_kernel, dim3(3200), dim3(256), 0, stream, S_U, S_Hs, Ssc);
    hipLaunchKernelGGL(node_fusedC_kernel, dim3(200), dim3(256), 0, stream,
                       Ssc, Wp2b, b2bs, Wp3a, b3a, Wp3b, b3b, Wp4r, b4ap, Wp4s, C4, S_Vs);
    hipLaunchKernelGGL(edge_phaseB_kernel, dim3(3200, 2), dim3(256), 0, stream,
                       S_Hs, S_Vs, S_U, C4, Wpz, Wfp, bfv, out);
}

// Round 13
// 267.894 us; speedup vs baseline: 1.3917x; 1.0296x over previous
//
#include <hip/hip_runtime.h>
#include <hip/hip_bf16.h>
#include <stdint.h>

// ---------------------------------------------------------------------------
// NRI-style MLP encoder. B=32, T=50, N=100, D=4, E=9900, H=256. fp32 I/O.
// R7 formulation (send terms are node GEMMs; only edge GEMM is K=256 t2@Wpz).
// R13 changes (phaseB latency-bound: Occ 31% = 512/(68 arch + 64 acc) regs):
//  - phaseB __launch_bounds__(256,4) + K-loop unroll 1: arch live-set < 64
//    -> 4 waves/SIMD. Spill guard: R8 spilled at this cap with 64 arch regs
//    of forced live state; unroll-1 keeps af/bf window at 32.
//  - f2bf uses HW v_cvt_pk_bf16_f32 (gfx950, RNE — identical numerics) with
//    software fallback; stage0 packs pairs (1 inst / 2 values vs ~8).
// Pipeline (5 dispatches): prep, nodeA, colsum, nodeC, phaseB.
// ---------------------------------------------------------------------------

typedef __attribute__((ext_vector_type(8))) short short8;
typedef __attribute__((ext_vector_type(4))) float float4v;
typedef __attribute__((ext_vector_type(4))) unsigned short ushort4v;

__device__ inline float bf2f(unsigned short u) {
    union { unsigned int i; float f; } v; v.i = ((unsigned int)u) << 16; return v.f;
}

#if __has_builtin(__builtin_amdgcn_cvt_pk_bf16_f32)
typedef __attribute__((ext_vector_type(2))) __bf16 bf16x2;
__device__ inline unsigned int f2bf_pk(float a, float b) {   // [15:0]=a [31:16]=b
    union { bf16x2 v; unsigned int u; } c;
    c.v = __builtin_amdgcn_cvt_pk_bf16_f32(a, b);
    return c.u;
}
__device__ inline unsigned short f2bf(float f) {
    return (unsigned short)(f2bf_pk(f, f) & 0xFFFFu);
}
#else
__device__ inline unsigned short f2bf(float f) {
    union { float f; unsigned int i; } v; v.f = f;
    unsigned int i = v.i;
    return (unsigned short)((i + 0x7FFFu + ((i >> 16) & 1u)) >> 16);
}
__device__ inline unsigned int f2bf_pk(float a, float b) {
    return (unsigned int)f2bf(a) | ((unsigned int)f2bf(b) << 16);
}
#endif

// ---------------------------------------------------------------------------
// MEGA-PREP: bx<2272 weight packs | <2528 Wpz=pack(w2b@w4a_e) | <2530 misc
// (Wfp/bfv/b4ap/b2bs) | rest repack x. fp32 in, bf16 packed out.
// ---------------------------------------------------------------------------
__global__ __launch_bounds__(256) void prep_kernel(
        const float* __restrict__ x,
        const float* __restrict__ w1a, const float* __restrict__ w1b,
        const float* __restrict__ w2a, const float* __restrict__ w2b,
        const float* __restrict__ w3a, const float* __restrict__ w3b,
        const float* __restrict__ w4a, const float* __restrict__ b4a,
        const float* __restrict__ w4b, const float* __restrict__ b4b,
        const float* __restrict__ wo,  const float* __restrict__ bo,
        const float* __restrict__ b2b,
        unsigned short* __restrict__ Wp1a, unsigned short* __restrict__ Wp1b,
        unsigned short* __restrict__ Wp2r, unsigned short* __restrict__ Wp2s,
        unsigned short* __restrict__ Wp2b, unsigned short* __restrict__ Wp3a,
        unsigned short* __restrict__ Wp3b, unsigned short* __restrict__ Wp4r,
        unsigned short* __restrict__ Wp4s, unsigned short* __restrict__ Wpz,
        unsigned short* __restrict__ Wfp, float* __restrict__ bfv,
        float* __restrict__ b4ap, float* __restrict__ b2bs,
        unsigned short* __restrict__ hin) {
    int bx = blockIdx.x;
    int tid = threadIdx.x;
    if (bx < 2272) {
        const float* W; unsigned short* Wp; int Kin; int b0;
        if      (bx <  224) { W = w1a;             Wp = Wp1a; Kin = 200; b0 = 0;    }
        else if (bx <  480) { W = w1b;             Wp = Wp1b; Kin = 256; b0 = 224;  }
        else if (bx <  736) { W = w2a;             Wp = Wp2r; Kin = 256; b0 = 480;  }
        else if (bx <  992) { W = w2a + 256 * 256; Wp = Wp2s; Kin = 256; b0 = 736;  }
        else if (bx < 1248) { W = w2b;             Wp = Wp2b; Kin = 256; b0 = 992;  }
        else if (bx < 1504) { W = w3a;             Wp = Wp3a; Kin = 256; b0 = 1248; }
        else if (bx < 1760) { W = w3b;             Wp = Wp3b; Kin = 256; b0 = 1504; }
        else if (bx < 2016) { W = w4a;             Wp = Wp4r; Kin = 256; b0 = 1760; }
        else                { W = w4a + 256 * 256; Wp = Wp4s; Kin = 256; b0 = 2016; }
        int idx = (bx - b0) * 256 + tid;
        int k = idx >> 8, n = idx & 255;
        unsigned short v = (k < Kin) ? f2bf(W[k * 256 + n]) : (unsigned short)0;
        Wp[((size_t)(k >> 5) * 256 + n) * 32 + (k & 31)] = v;
    } else if (bx < 2528) {
        int k = bx - 2272, c = tid;
        float s = 0.f;
        for (int t = 0; t < 256; ++t)
            s += w2b[k * 256 + t] * w4a[(size_t)(512 + t) * 256 + c];
        Wpz[((size_t)(k >> 5) * 256 + c) * 32 + (k & 31)] = f2bf(s);
    } else if (bx < 2530) {
        int k = tid;
        if (bx == 2528) {
            float a[4] = {0.f, 0.f, 0.f, 0.f};
            for (int c = 0; c < 256; ++c) {
                float wv = w4b[k * 256 + c];
                #pragma unroll
                for (int o = 0; o < 4; ++o) a[o] += wv * wo[c * 4 + o];
            }
            #pragma unroll
            for (int n = 0; n < 16; ++n)
                Wfp[(size_t)(k >> 5) * 512 + n * 32 + (k & 31)] =
                    (n < 4) ? f2bf(a[n]) : (unsigned short)0;
            if (k < 4) {
                float s = bo[k];
                for (int c = 0; c < 256; ++c) s += b4b[c] * wo[c * 4 + k];
                bfv[k] = s;
            }
        } else {
            float s = b4a[k];
            for (int t = 0; t < 256; ++t)
                s += b2b[t] * w4a[(size_t)(512 + t) * 256 + k];
            b4ap[k] = s;
            b2bs[k] = 0.99f * b2b[k];
        }
    } else {
        int idx = (bx - 2530) * 256 + tid;
        if (idx < 3200 * 224) {
            int row = idx / 224;
            int c = idx - row * 224;
            int b = row / 100, n = row - b * 100;
            unsigned short v = 0;
            if (c < 200) {
                int t = c >> 2, d = c & 3;
                v = f2bf(x[(((size_t)(b * 50 + t)) * 100 + n) * 4 + d]);
            }
            hin[(size_t)row * 224 + c] = v;
        }
    }
}

// ---------------------------------------------------------------------------
// nodeA (fused): rows m0=bx*16. t1=relu(hin@W1a+b1a) [LDS] ->
// h=t1@W1b+b1b [LDS] -> U=h@W2r+b2a, Hs=h@W2s (dual, global).
// ---------------------------------------------------------------------------
__global__ __launch_bounds__(256) void node_fusedA_kernel(
        const unsigned short* __restrict__ hin,
        const unsigned short* __restrict__ Wp1a, const float* __restrict__ b1a,
        const unsigned short* __restrict__ Wp1b, const float* __restrict__ b1b,
        const unsigned short* __restrict__ Wp2r, const float* __restrict__ b2a,
        const unsigned short* __restrict__ Wp2s,
        unsigned short* __restrict__ U, unsigned short* __restrict__ Hs) {
    __shared__ __align__(16) unsigned short t1s[16 * 264];
    __shared__ __align__(16) unsigned short hs2[16 * 264];
    const int m0 = blockIdx.x * 16;
    const int tid  = threadIdx.x;
    const int wave = tid >> 6;
    const int lane = tid & 63;
    const int l15  = lane & 15;
    const int quad = lane >> 4;
    const int n0   = wave * 64;
    const int koff = quad * 8;

    // ---- S1: t1 = relu(hin@W1a + b1a), K=224 ----
    {
        float4v acc[4];
        #pragma unroll
        for (int ni = 0; ni < 4; ++ni) acc[ni] = (float4v)(0.0f);
        for (int kb = 0; kb < 7; ++kb) {
            short8 af = *(const short8*)(hin + (size_t)(m0 + l15) * 224 + kb * 32 + koff);
            short8 bf[4];
            #pragma unroll
            for (int ni = 0; ni < 4; ++ni)
                bf[ni] = *(const short8*)(Wp1a + ((size_t)kb * 256 + n0 + ni * 16 + l15) * 32 + koff);
            #pragma unroll
            for (int ni = 0; ni < 4; ++ni)
                acc[ni] = __builtin_amdgcn_mfma_f32_16x16x32_bf16(af, bf[ni], acc[ni], 0, 0, 0);
        }
        #pragma unroll
        for (int ni = 0; ni < 4; ++ni) {
            int col = n0 + ni * 16 + l15;
            float bv = b1a[col];
            #pragma unroll
            for (int r = 0; r < 4; ++r) {
                float v = acc[ni][r] + bv;
                v = v > 0.f ? v : 0.f;
                t1s[(quad * 4 + r) * 264 + col] = f2bf(v);
            }
        }
    }
    __syncthreads();

    // ---- S2: h = t1@W1b + b1b ----
    {
        float4v acc[4];
        #pragma unroll
        for (int ni = 0; ni < 4; ++ni) acc[ni] = (float4v)(0.0f);
        for (int kb = 0; kb < 8; ++kb) {
            short8 af = *(const short8*)(&t1s[l15 * 264 + kb * 32 + koff]);
            short8 bf[4];
            #pragma unroll
            for (int ni = 0; ni < 4; ++ni)
                bf[ni] = *(const short8*)(Wp1b + ((size_t)kb * 256 + n0 + ni * 16 + l15) * 32 + koff);
            #pragma unroll
            for (int ni = 0; ni < 4; ++ni)
                acc[ni] = __builtin_amdgcn_mfma_f32_16x16x32_bf16(af, bf[ni], acc[ni], 0, 0, 0);
        }
        #pragma unroll
        for (int ni = 0; ni < 4; ++ni) {
            int col = n0 + ni * 16 + l15;
            float bv = b1b[col];
            #pragma unroll
            for (int r = 0; r < 4; ++r)
                hs2[(quad * 4 + r) * 264 + col] = f2bf(acc[ni][r] + bv);
        }
    }
    __syncthreads();

    // ---- S3 (dual): U = h@W2r + b2a ; Hs = h@W2s ----
    {
        float4v aU[4], aH[4];
        #pragma unroll
        for (int ni = 0; ni < 4; ++ni) { aU[ni] = (float4v)(0.0f); aH[ni] = (float4v)(0.0f); }
        for (int kb = 0; kb < 8; ++kb) {
            short8 af = *(const short8*)(&hs2[l15 * 264 + kb * 32 + koff]);
            #pragma unroll
            for (int ni = 0; ni < 4; ++ni) {
                short8 bu = *(const short8*)(Wp2r + ((size_t)kb * 256 + n0 + ni * 16 + l15) * 32 + koff);
                short8 bh = *(const short8*)(Wp2s + ((size_t)kb * 256 + n0 + ni * 16 + l15) * 32 + koff);
                aU[ni] = __builtin_amdgcn_mfma_f32_16x16x32_bf16(af, bu, aU[ni], 0, 0, 0);
                aH[ni] = __builtin_amdgcn_mfma_f32_16x16x32_bf16(af, bh, aH[ni], 0, 0, 0);
            }
        }
        #pragma unroll
        for (int ni = 0; ni < 4; ++ni) {
            int col = n0 + ni * 16 + l15;
            float bv = b2a[col];
            #pragma unroll
            for (int r = 0; r < 4; ++r) {
                size_t o = (size_t)(m0 + quad * 4 + r) * 256 + col;
                U[o]  = f2bf(aU[ni][r] + bv);
                Hs[o] = f2bf(aH[ni][r]);
            }
        }
    }
}

// ---------------------------------------------------------------------------
// nodeC (fused): rows m0=bx*16. vin=Ssc@W2b+b2bs [LDS] -> t3=relu(vin@W3a+b3a)
// [LDS] -> v2=t3@W3b+b3b [LDS] -> C4=v2@W4r+b4ap, Vs=v2@W4s (dual, global).
// ---------------------------------------------------------------------------
__global__ __launch_bounds__(256) void node_fusedC_kernel(
        const unsigned short* __restrict__ Ssc,
        const unsigned short* __restrict__ Wp2b, const float* __restrict__ b2bs,
        const unsigned short* __restrict__ Wp3a, const float* __restrict__ b3a,
        const unsigned short* __restrict__ Wp3b, const float* __restrict__ b3b,
        const unsigned short* __restrict__ Wp4r, const float* __restrict__ b4ap,
        const unsigned short* __restrict__ Wp4s,
        unsigned short* __restrict__ C4, unsigned short* __restrict__ Vs) {
    __shared__ __align__(16) unsigned short buf0[16 * 264];
    __shared__ __align__(16) unsigned short buf1[16 * 264];
    const int m0 = blockIdx.x * 16;
    const int tid  = threadIdx.x;
    const int wave = tid >> 6;
    const int lane = tid & 63;
    const int l15  = lane & 15;
    const int quad = lane >> 4;
    const int n0   = wave * 64;
    const int koff = quad * 8;

    // ---- S1: vin = Ssc@W2b + b2bs -> buf0 ----
    {
        float4v acc[4];
        #pragma unroll
        for (int ni = 0; ni < 4; ++ni) acc[ni] = (float4v)(0.0f);
        for (int kb = 0; kb < 8; ++kb) {
            short8 af = *(const short8*)(Ssc + (size_t)(m0 + l15) * 256 + kb * 32 + koff);
            short8 bf[4];
            #pragma unroll
            for (int ni = 0; ni < 4; ++ni)
                bf[ni] = *(const short8*)(Wp2b + ((size_t)kb * 256 + n0 + ni * 16 + l15) * 32 + koff);
            #pragma unroll
            for (int ni = 0; ni < 4; ++ni)
                acc[ni] = __builtin_amdgcn_mfma_f32_16x16x32_bf16(af, bf[ni], acc[ni], 0, 0, 0);
        }
        #pragma unroll
        for (int ni = 0; ni < 4; ++ni) {
            int col = n0 + ni * 16 + l15;
            float bv = b2bs[col];
            #pragma unroll
            for (int r = 0; r < 4; ++r)
                buf0[(quad * 4 + r) * 264 + col] = f2bf(acc[ni][r] + bv);
        }
    }
    __syncthreads();

    // ---- S2: t3 = relu(vin@W3a + b3a) -> buf1 ----
    {
        float4v acc[4];
        #pragma unroll
        for (int ni = 0; ni < 4; ++ni) acc[ni] = (float4v)(0.0f);
        for (int kb = 0; kb < 8; ++kb) {
            short8 af = *(const short8*)(&buf0[l15 * 264 + kb * 32 + koff]);
            short8 bf[4];
            #pragma unroll
            for (int ni = 0; ni < 4; ++ni)
                bf[ni] = *(const short8*)(Wp3a + ((size_t)kb * 256 + n0 + ni * 16 + l15) * 32 + koff);
            #pragma unroll
            for (int ni = 0; ni < 4; ++ni)
                acc[ni] = __builtin_amdgcn_mfma_f32_16x16x32_bf16(af, bf[ni], acc[ni], 0, 0, 0);
        }
        #pragma unroll
        for (int ni = 0; ni < 4; ++ni) {
            int col = n0 + ni * 16 + l15;
            float bv = b3a[col];
            #pragma unroll
            for (int r = 0; r < 4; ++r) {
                float v = acc[ni][r] + bv;
                v = v > 0.f ? v : 0.f;
                buf1[(quad * 4 + r) * 264 + col] = f2bf(v);
            }
        }
    }
    __syncthreads();

    // ---- S3: v2 = t3@W3b + b3b -> buf0 ----
    {
        float4v acc[4];
        #pragma unroll
        for (int ni = 0; ni < 4; ++ni) acc[ni] = (float4v)(0.0f);
        for (int kb = 0; kb < 8; ++kb) {
            short8 af = *(const short8*)(&buf1[l15 * 264 + kb * 32 + koff]);
            short8 bf[4];
            #pragma unroll
            for (int ni = 0; ni < 4; ++ni)
                bf[ni] = *(const short8*)(Wp3b + ((size_t)kb * 256 + n0 + ni * 16 + l15) * 32 + koff);
            #pragma unroll
            for (int ni = 0; ni < 4; ++ni)
                acc[ni] = __builtin_amdgcn_mfma_f32_16x16x32_bf16(af, bf[ni], acc[ni], 0, 0, 0);
        }
        __syncthreads();   // buf0's S1 readers done (S2 barrier); safe rewrite
        #pragma unroll
        for (int ni = 0; ni < 4; ++ni) {
            int col = n0 + ni * 16 + l15;
            float bv = b3b[col];
            #pragma unroll
            for (int r = 0; r < 4; ++r)
                buf0[(quad * 4 + r) * 264 + col] = f2bf(acc[ni][r] + bv);
        }
    }
    __syncthreads();

    // ---- S4 (dual): C4 = v2@W4r + b4ap ; Vs = v2@W4s ----
    {
        float4v aC[4], aV[4];
        #pragma unroll
        for (int ni = 0; ni < 4; ++ni) { aC[ni] = (float4v)(0.0f); aV[ni] = (float4v)(0.0f); }
        for (int kb = 0; kb < 8; ++kb) {
            short8 af = *(const short8*)(&buf0[l15 * 264 + kb * 32 + koff]);
            #pragma unroll
            for (int ni = 0; ni < 4; ++ni) {
                short8 bc = *(const short8*)(Wp4r + ((size_t)kb * 256 + n0 + ni * 16 + l15) * 32 + koff);
                short8 bv = *(const short8*)(Wp4s + ((size_t)kb * 256 + n0 + ni * 16 + l15) * 32 + koff);
                aC[ni] = __builtin_amdgcn_mfma_f32_16x16x32_bf16(af, bc, aC[ni], 0, 0, 0);
                aV[ni] = __builtin_amdgcn_mfma_f32_16x16x32_bf16(af, bv, aV[ni], 0, 0, 0);
            }
        }
        #pragma unroll
        for (int ni = 0; ni < 4; ++ni) {
            int col = n0 + ni * 16 + l15;
            float bv = b4ap[col];
            #pragma unroll
            for (int r = 0; r < 4; ++r) {
                size_t o = (size_t)(m0 + quad * 4 + r) * 256 + col;
                C4[o] = f2bf(aC[ni][r] + bv);
                Vs[o] = f2bf(aV[ni][r]);
            }
        }
    }
}

// ---------------------------------------------------------------------------
// colsum: Ssc[g,c] = 0.01*( sum_j relu(U[g,c]+Hs[b,j,c]) - relu(U[g,c]+Hs[b,i,c]) )
// ---------------------------------------------------------------------------
__global__ __launch_bounds__(256) void colsum_kernel(
        const unsigned short* __restrict__ U, const unsigned short* __restrict__ Hs,
        unsigned short* __restrict__ Ssc) {
    const int g = blockIdx.x;
    const int b = g / 100, i = g - b * 100;
    const int c = threadIdx.x;
    const float u = bf2f(U[(size_t)g * 256 + c]);
    const unsigned short* base = Hs + (size_t)b * 100 * 256 + c;
    float s = 0.f;
    #pragma unroll 4
    for (int j = 0; j < 100; ++j) {
        float v = u + bf2f(base[(size_t)j * 256]);
        s += (v > 0.f ? v : 0.f);
    }
    float vi = u + bf2f(base[(size_t)i * 256]);
    s -= (vi > 0.f ? vi : 0.f);
    Ssc[(size_t)g * 256 + c] = f2bf(s * 0.01f);
}

// ---------------------------------------------------------------------------
// Phase B: grid (3200,2), block 256, M=64 (<=50 real).
// stage0: t2 = relu(U_i + Hs_j) -> LDS ONCE (pk-packed pairs).
// K-loop (unroll 1: live-set < 64 arch regs so (256,4) doesn't spill):
// A via ds_read_b128, B = Wpz (L2). z4 -> LDS (aliases t2s); projection
// 8 MFMA vs Wfp; lanes l15<4 store fp32. LDS 33792 B -> 4 blk/CU.
// ---------------------------------------------------------------------------
__global__ __launch_bounds__(256, 4) void edge_phaseB_kernel(
        const unsigned short* __restrict__ Hs, const unsigned short* __restrict__ Vs,
        const unsigned short* __restrict__ U, const unsigned short* __restrict__ C4,
        const unsigned short* __restrict__ Wpz, const unsigned short* __restrict__ Wfp,
        const float* __restrict__ bfv,
        float* __restrict__ out) {
    __shared__ __align__(16) unsigned short t2s[64 * 264]; // 33792 B (z4 aliases later)
    const int g = blockIdx.x, hb = blockIdx.y;
    const int b = g / 100, nr = g - b * 100;
    const int nrows = hb ? 49 : 50;
    const int k0 = hb * 50;
    const int tid  = threadIdx.x;
    const int wave = tid >> 6;
    const int lane = tid & 63;
    const int l15  = lane & 15;
    const int quad = lane >> 4;
    const int n0   = wave * 64;
    const int koff = quad * 8;

    // ---- stage 0: build t2 tile ONCE (8B/lane; pk-pack; pad rows zeroed) ----
    {
        const int c = lane * 4;
        ushort4v uv = *(const ushort4v*)(U + (size_t)g * 256 + c);
        float u0 = bf2f(uv[0]), u1 = bf2f(uv[1]), u2 = bf2f(uv[2]), u3 = bf2f(uv[3]);
        for (int r = wave; r < 64; r += 4) {
            unsigned int p01 = 0, p23 = 0;
            if (r < nrows) {
                int k = k0 + r;
                int j = k + (k >= nr ? 1 : 0);
                ushort4v hv = *(const ushort4v*)(Hs + (size_t)(b * 100 + j) * 256 + c);
                float t0 = u0 + bf2f(hv[0]); t0 = t0 > 0.f ? t0 : 0.f;
                float t1 = u1 + bf2f(hv[1]); t1 = t1 > 0.f ? t1 : 0.f;
                float t2 = u2 + bf2f(hv[2]); t2 = t2 > 0.f ? t2 : 0.f;
                float t3 = u3 + bf2f(hv[3]); t3 = t3 > 0.f ? t3 : 0.f;
                p01 = f2bf_pk(t0, t1);
                p23 = f2bf_pk(t2, t3);
            }
            unsigned int* dst = (unsigned int*)(&t2s[r * 264 + c]);
            dst[0] = p01;
            dst[1] = p23;
        }
    }
    __syncthreads();

    // ---- K-loop: z4 GEMM (K=256), A from LDS, B from L2 ----
    float4v acc[4][4];
    #pragma unroll
    for (int mi = 0; mi < 4; ++mi)
        #pragma unroll
        for (int ni = 0; ni < 4; ++ni) acc[mi][ni] = (float4v)(0.0f);

    #pragma unroll 1              // keep live-set small: (256,4) reg cap = 128 total
    for (int kb = 0; kb < 8; ++kb) {
        short8 af[4], bf[4];
        #pragma unroll
        for (int mi = 0; mi < 4; ++mi)
            af[mi] = *(const short8*)(&t2s[(mi * 16 + l15) * 264 + kb * 32 + koff]);
        #pragma unroll
        for (int ni = 0; ni < 4; ++ni)
            bf[ni] = *(const short8*)(Wpz + ((size_t)kb * 256 + n0 + ni * 16 + l15) * 32 + koff);
        #pragma unroll
        for (int mi = 0; mi < 4; ++mi)
            #pragma unroll
            for (int ni = 0; ni < 4; ++ni)
                acc[mi][ni] = __builtin_amdgcn_mfma_f32_16x16x32_bf16(af[mi], bf[ni], acc[mi][ni], 0, 0, 0);
    }
    __syncthreads();            // all t2s A-reads done; z4 aliases t2s below

    // ---- z4 = relu(C4_i + Vs_j + acc) -> LDS (C-layout) ----
    float c4v[4];
    #pragma unroll
    for (int ni = 0; ni < 4; ++ni)
        c4v[ni] = bf2f(C4[(size_t)g * 256 + n0 + ni * 16 + l15]);
    #pragma unroll
    for (int mi = 0; mi < 4; ++mi) {
        #pragma unroll
        for (int r = 0; r < 4; ++r) {
            int row = mi * 16 + quad * 4 + r;          // local edge idx (C-layout)
            int k = k0 + row;
            int j = (row < nrows) ? (k + (k >= nr ? 1 : 0)) : 0;
            const unsigned short* vsr = Vs + (size_t)(b * 100 + j) * 256;
            #pragma unroll
            for (int ni = 0; ni < 4; ++ni) {
                int col = n0 + ni * 16 + l15;
                float zv = c4v[ni] + bf2f(vsr[col]) + acc[mi][ni][r];
                zv = zv > 0.f ? zv : 0.f;
                t2s[row * 264 + col] = f2bf(zv);
            }
        }
    }
    __syncthreads();

    // ---- projection: wave handles rows wave*16..+15; 8 MFMA vs Wfp ----
    float4v pacc = (float4v)(0.0f);
    #pragma unroll
    for (int kb = 0; kb < 8; ++kb) {
        short8 za = *(const short8*)(&t2s[(wave * 16 + l15) * 264 + kb * 32 + koff]);
        short8 wb = *(const short8*)(Wfp + (size_t)kb * 512 + l15 * 32 + koff);
        pacc = __builtin_amdgcn_mfma_f32_16x16x32_bf16(za, wb, pacc, 0, 0, 0);
    }

    if (l15 < 4) {
        float bv = bfv[l15];
        #pragma unroll
        for (int r = 0; r < 4; ++r) {
            int row = wave * 16 + quad * 4 + r;
            if (row < nrows)
                out[((size_t)b * 9900 + nr * 99 + k0 + row) * 4 + l15] = pacc[r] + bv;
        }
    }
}

extern "C" void kernel_launch(void* const* d_in, const int* in_sizes, int n_in,
                              void* d_out, int out_size, void* d_ws, size_t ws_size,
                              hipStream_t stream) {
    const float* x   = (const float*)d_in[0];
    const float* w1a = (const float*)d_in[3];
    const float* b1a = (const float*)d_in[4];
    const float* w1b = (const float*)d_in[5];
    const float* b1b = (const float*)d_in[6];
    const float* w2a = (const float*)d_in[7];
    const float* b2a = (const float*)d_in[8];
    const float* w2b = (const float*)d_in[9];
    const float* b2b = (const float*)d_in[10];
    const float* w3a = (const float*)d_in[11];
    const float* b3a = (const float*)d_in[12];
    const float* w3b = (const float*)d_in[13];
    const float* b3b = (const float*)d_in[14];
    const float* w4a = (const float*)d_in[15];
    const float* b4a = (const float*)d_in[16];
    const float* w4b = (const float*)d_in[17];
    const float* b4b = (const float*)d_in[18];
    const float* wo  = (const float*)d_in[19];
    const float* bo  = (const float*)d_in[20];
    float* out = (float*)d_out;
    (void)in_sizes; (void)n_in; (void)out_size; (void)ws_size;

    char* ws = (char*)d_ws;
    size_t off = 0;
    auto alloc = [&](size_t bytes) {
        size_t o = off;
        off = (off + bytes + 255) & ~(size_t)255;
        return o;
    };
    const size_t SLOT_BF = (size_t)3200 * 256 * 2;   // 1.64 MB
    unsigned short* S_U  = (unsigned short*)(ws + alloc(SLOT_BF)); // U
    unsigned short* S_Hs = (unsigned short*)(ws + alloc(SLOT_BF)); // Hs
    unsigned short* S_Vs = (unsigned short*)(ws + alloc(SLOT_BF)); // Vs
    unsigned short* S_4  = (unsigned short*)(ws + alloc(SLOT_BF)); // hin -> Ssc -> C4
    unsigned short* Wp1a = (unsigned short*)(ws + alloc(224 * 256 * 2));
    unsigned short* Wp1b = (unsigned short*)(ws + alloc(256 * 256 * 2));
    unsigned short* Wp2r = (unsigned short*)(ws + alloc(256 * 256 * 2));
    unsigned short* Wp2s = (unsigned short*)(ws + alloc(256 * 256 * 2));
    unsigned short* Wp2b = (unsigned short*)(ws + alloc(256 * 256 * 2));
    unsigned short* Wp3a = (unsigned short*)(ws + alloc(256 * 256 * 2));
    unsigned short* Wp3b = (unsigned short*)(ws + alloc(256 * 256 * 2));
    unsigned short* Wp4r = (unsigned short*)(ws + alloc(256 * 256 * 2));
    unsigned short* Wp4s = (unsigned short*)(ws + alloc(256 * 256 * 2));
    unsigned short* Wpz  = (unsigned short*)(ws + alloc(256 * 256 * 2));
    unsigned short* Wfp  = (unsigned short*)(ws + alloc(8 * 16 * 32 * 2));
    float*          bfv  = (float*)(ws + alloc(4 * 4));
    float*          b4ap = (float*)(ws + alloc(256 * 4));
    float*          b2bs = (float*)(ws + alloc(256 * 4));
    // total ~8 MB (<= 11.2 proven safe)

    unsigned short* hin = S_4;   // [prep, nodeA]
    unsigned short* Ssc = S_4;   // [colsum, nodeC]
    unsigned short* C4  = S_4;   // [nodeC, phaseB] (block-local read-before-write)

    // ---- 5 dispatches ----
    hipLaunchKernelGGL(prep_kernel, dim3(5330), dim3(256), 0, stream,
                       x, w1a, w1b, w2a, w2b, w3a, w3b, w4a, b4a, w4b, b4b, wo, bo, b2b,
                       Wp1a, Wp1b, Wp2r, Wp2s, Wp2b, Wp3a, Wp3b, Wp4r, Wp4s, Wpz,
                       Wfp, bfv, b4ap, b2bs, hin);
    hipLaunchKernelGGL(node_fusedA_kernel, dim3(200), dim3(256), 0, stream,
                       hin, Wp1a, b1a, Wp1b, b1b, Wp2r, b2a, Wp2s, S_U, S_Hs);
    hipLaunchKernelGGL(colsum_kernel, dim3(3200), dim3(256), 0, stream, S_U, S_Hs, Ssc);
    hipLaunchKernelGGL(node_fusedC_kernel, dim3(200), dim3(256), 0, stream,
                       Ssc, Wp2b, b2bs, Wp3a, b3a, Wp3b, b3b, Wp4r, b4ap, Wp4s, C4, S_Vs);
    hipLaunchKernelGGL(edge_phaseB_kernel, dim3(3200, 2), dim3(256), 0, stream,
                       S_Hs, S_Vs, S_U, C4, Wpz, Wfp, bfv, out);
}

// Round 14
// 259.635 us; speedup vs baseline: 1.4359x; 1.0318x over previous
//
#include <hip/hip_runtime.h>
#include <hip/hip_bf16.h>
#include <stdint.h>

// ---------------------------------------------------------------------------
// NRI-style MLP encoder. B=32, T=50, N=100, D=4, E=9900, H=256. fp32 I/O.
// R7 formulation (send terms are node GEMMs; only edge GEMM is K=256 t2@Wpz).
// R14 change (phaseB register-capped: 64 acc AGPR + 64 arch = 128 cap @ 4
// waves/SIMD): wave tile 64x64 -> 64x32 (acc[4][2]=32 regs), block 512 thr
// (8 waves cover 256 cols), __launch_bounds__(512,6) -> 24 waves/CU (was 16).
// K-loop: af loaded per-mi inside loop (live ~60 regs < 84 cap). z4-formation
// halves per-thread (32 elems / 32 Vs loads). Projection: waves 0-3 only.
// Spill guard: WRITE_SIZE must stay ~10MB (R8 spill signature = 100s of MB).
// Pipeline (5 dispatches): prep, nodeA, colsum, nodeC, phaseB.
// ---------------------------------------------------------------------------

typedef __attribute__((ext_vector_type(8))) short short8;
typedef __attribute__((ext_vector_type(4))) float float4v;
typedef __attribute__((ext_vector_type(4))) unsigned short ushort4v;

__device__ inline float bf2f(unsigned short u) {
    union { unsigned int i; float f; } v; v.i = ((unsigned int)u) << 16; return v.f;
}

#if __has_builtin(__builtin_amdgcn_cvt_pk_bf16_f32)
typedef __attribute__((ext_vector_type(2))) __bf16 bf16x2;
__device__ inline unsigned int f2bf_pk(float a, float b) {   // [15:0]=a [31:16]=b
    union { bf16x2 v; unsigned int u; } c;
    c.v = __builtin_amdgcn_cvt_pk_bf16_f32(a, b);
    return c.u;
}
__device__ inline unsigned short f2bf(float f) {
    return (unsigned short)(f2bf_pk(f, f) & 0xFFFFu);
}
#else
__device__ inline unsigned short f2bf(float f) {
    union { float f; unsigned int i; } v; v.f = f;
    unsigned int i = v.i;
    return (unsigned short)((i + 0x7FFFu + ((i >> 16) & 1u)) >> 16);
}
__device__ inline unsigned int f2bf_pk(float a, float b) {
    return (unsigned int)f2bf(a) | ((unsigned int)f2bf(b) << 16);
}
#endif

// ---------------------------------------------------------------------------
// MEGA-PREP: bx<2272 weight packs | <2528 Wpz=pack(w2b@w4a_e) | <2530 misc
// (Wfp/bfv/b4ap/b2bs) | rest repack x. fp32 in, bf16 packed out.
// ---------------------------------------------------------------------------
__global__ __launch_bounds__(256) void prep_kernel(
        const float* __restrict__ x,
        const float* __restrict__ w1a, const float* __restrict__ w1b,
        const float* __restrict__ w2a, const float* __restrict__ w2b,
        const float* __restrict__ w3a, const float* __restrict__ w3b,
        const float* __restrict__ w4a, const float* __restrict__ b4a,
        const float* __restrict__ w4b, const float* __restrict__ b4b,
        const float* __restrict__ wo,  const float* __restrict__ bo,
        const float* __restrict__ b2b,
        unsigned short* __restrict__ Wp1a, unsigned short* __restrict__ Wp1b,
        unsigned short* __restrict__ Wp2r, unsigned short* __restrict__ Wp2s,
        unsigned short* __restrict__ Wp2b, unsigned short* __restrict__ Wp3a,
        unsigned short* __restrict__ Wp3b, unsigned short* __restrict__ Wp4r,
        unsigned short* __restrict__ Wp4s, unsigned short* __restrict__ Wpz,
        unsigned short* __restrict__ Wfp, float* __restrict__ bfv,
        float* __restrict__ b4ap, float* __restrict__ b2bs,
        unsigned short* __restrict__ hin) {
    int bx = blockIdx.x;
    int tid = threadIdx.x;
    if (bx < 2272) {
        const float* W; unsigned short* Wp; int Kin; int b0;
        if      (bx <  224) { W = w1a;             Wp = Wp1a; Kin = 200; b0 = 0;    }
        else if (bx <  480) { W = w1b;             Wp = Wp1b; Kin = 256; b0 = 224;  }
        else if (bx <  736) { W = w2a;             Wp = Wp2r; Kin = 256; b0 = 480;  }
        else if (bx <  992) { W = w2a + 256 * 256; Wp = Wp2s; Kin = 256; b0 = 736;  }
        else if (bx < 1248) { W = w2b;             Wp = Wp2b; Kin = 256; b0 = 992;  }
        else if (bx < 1504) { W = w3a;             Wp = Wp3a; Kin = 256; b0 = 1248; }
        else if (bx < 1760) { W = w3b;             Wp = Wp3b; Kin = 256; b0 = 1504; }
        else if (bx < 2016) { W = w4a;             Wp = Wp4r; Kin = 256; b0 = 1760; }
        else                { W = w4a + 256 * 256; Wp = Wp4s; Kin = 256; b0 = 2016; }
        int idx = (bx - b0) * 256 + tid;
        int k = idx >> 8, n = idx & 255;
        unsigned short v = (k < Kin) ? f2bf(W[k * 256 + n]) : (unsigned short)0;
        Wp[((size_t)(k >> 5) * 256 + n) * 32 + (k & 31)] = v;
    } else if (bx < 2528) {
        int k = bx - 2272, c = tid;
        float s = 0.f;
        for (int t = 0; t < 256; ++t)
            s += w2b[k * 256 + t] * w4a[(size_t)(512 + t) * 256 + c];
        Wpz[((size_t)(k >> 5) * 256 + c) * 32 + (k & 31)] = f2bf(s);
    } else if (bx < 2530) {
        int k = tid;
        if (bx == 2528) {
            float a[4] = {0.f, 0.f, 0.f, 0.f};
            for (int c = 0; c < 256; ++c) {
                float wv = w4b[k * 256 + c];
                #pragma unroll
                for (int o = 0; o < 4; ++o) a[o] += wv * wo[c * 4 + o];
            }
            #pragma unroll
            for (int n = 0; n < 16; ++n)
                Wfp[(size_t)(k >> 5) * 512 + n * 32 + (k & 31)] =
                    (n < 4) ? f2bf(a[n]) : (unsigned short)0;
            if (k < 4) {
                float s = bo[k];
                for (int c = 0; c < 256; ++c) s += b4b[c] * wo[c * 4 + k];
                bfv[k] = s;
            }
        } else {
            float s = b4a[k];
            for (int t = 0; t < 256; ++t)
                s += b2b[t] * w4a[(size_t)(512 + t) * 256 + k];
            b4ap[k] = s;
            b2bs[k] = 0.99f * b2b[k];
        }
    } else {
        int idx = (bx - 2530) * 256 + tid;
        if (idx < 3200 * 224) {
            int row = idx / 224;
            int c = idx - row * 224;
            int b = row / 100, n = row - b * 100;
            unsigned short v = 0;
            if (c < 200) {
                int t = c >> 2, d = c & 3;
                v = f2bf(x[(((size_t)(b * 50 + t)) * 100 + n) * 4 + d]);
            }
            hin[(size_t)row * 224 + c] = v;
        }
    }
}

// ---------------------------------------------------------------------------
// nodeA (fused): rows m0=bx*16. t1=relu(hin@W1a+b1a) [LDS] ->
// h=t1@W1b+b1b [LDS] -> U=h@W2r+b2a, Hs=h@W2s (dual, global).
// ---------------------------------------------------------------------------
__global__ __launch_bounds__(256) void node_fusedA_kernel(
        const unsigned short* __restrict__ hin,
        const unsigned short* __restrict__ Wp1a, const float* __restrict__ b1a,
        const unsigned short* __restrict__ Wp1b, const float* __restrict__ b1b,
        const unsigned short* __restrict__ Wp2r, const float* __restrict__ b2a,
        const unsigned short* __restrict__ Wp2s,
        unsigned short* __restrict__ U, unsigned short* __restrict__ Hs) {
    __shared__ __align__(16) unsigned short t1s[16 * 264];
    __shared__ __align__(16) unsigned short hs2[16 * 264];
    const int m0 = blockIdx.x * 16;
    const int tid  = threadIdx.x;
    const int wave = tid >> 6;
    const int lane = tid & 63;
    const int l15  = lane & 15;
    const int quad = lane >> 4;
    const int n0   = wave * 64;
    const int koff = quad * 8;

    // ---- S1: t1 = relu(hin@W1a + b1a), K=224 ----
    {
        float4v acc[4];
        #pragma unroll
        for (int ni = 0; ni < 4; ++ni) acc[ni] = (float4v)(0.0f);
        for (int kb = 0; kb < 7; ++kb) {
            short8 af = *(const short8*)(hin + (size_t)(m0 + l15) * 224 + kb * 32 + koff);
            short8 bf[4];
            #pragma unroll
            for (int ni = 0; ni < 4; ++ni)
                bf[ni] = *(const short8*)(Wp1a + ((size_t)kb * 256 + n0 + ni * 16 + l15) * 32 + koff);
            #pragma unroll
            for (int ni = 0; ni < 4; ++ni)
                acc[ni] = __builtin_amdgcn_mfma_f32_16x16x32_bf16(af, bf[ni], acc[ni], 0, 0, 0);
        }
        #pragma unroll
        for (int ni = 0; ni < 4; ++ni) {
            int col = n0 + ni * 16 + l15;
            float bv = b1a[col];
            #pragma unroll
            for (int r = 0; r < 4; ++r) {
                float v = acc[ni][r] + bv;
                v = v > 0.f ? v : 0.f;
                t1s[(quad * 4 + r) * 264 + col] = f2bf(v);
            }
        }
    }
    __syncthreads();

    // ---- S2: h = t1@W1b + b1b ----
    {
        float4v acc[4];
        #pragma unroll
        for (int ni = 0; ni < 4; ++ni) acc[ni] = (float4v)(0.0f);
        for (int kb = 0; kb < 8; ++kb) {
            short8 af = *(const short8*)(&t1s[l15 * 264 + kb * 32 + koff]);
            short8 bf[4];
            #pragma unroll
            for (int ni = 0; ni < 4; ++ni)
                bf[ni] = *(const short8*)(Wp1b + ((size_t)kb * 256 + n0 + ni * 16 + l15) * 32 + koff);
            #pragma unroll
            for (int ni = 0; ni < 4; ++ni)
                acc[ni] = __builtin_amdgcn_mfma_f32_16x16x32_bf16(af, bf[ni], acc[ni], 0, 0, 0);
        }
        #pragma unroll
        for (int ni = 0; ni < 4; ++ni) {
            int col = n0 + ni * 16 + l15;
            float bv = b1b[col];
            #pragma unroll
            for (int r = 0; r < 4; ++r)
                hs2[(quad * 4 + r) * 264 + col] = f2bf(acc[ni][r] + bv);
        }
    }
    __syncthreads();

    // ---- S3 (dual): U = h@W2r + b2a ; Hs = h@W2s ----
    {
        float4v aU[4], aH[4];
        #pragma unroll
        for (int ni = 0; ni < 4; ++ni) { aU[ni] = (float4v)(0.0f); aH[ni] = (float4v)(0.0f); }
        for (int kb = 0; kb < 8; ++kb) {
            short8 af = *(const short8*)(&hs2[l15 * 264 + kb * 32 + koff]);
            #pragma unroll
            for (int ni = 0; ni < 4; ++ni) {
                short8 bu = *(const short8*)(Wp2r + ((size_t)kb * 256 + n0 + ni * 16 + l15) * 32 + koff);
                short8 bh = *(const short8*)(Wp2s + ((size_t)kb * 256 + n0 + ni * 16 + l15) * 32 + koff);
                aU[ni] = __builtin_amdgcn_mfma_f32_16x16x32_bf16(af, bu, aU[ni], 0, 0, 0);
                aH[ni] = __builtin_amdgcn_mfma_f32_16x16x32_bf16(af, bh, aH[ni], 0, 0, 0);
            }
        }
        #pragma unroll
        for (int ni = 0; ni < 4; ++ni) {
            int col = n0 + ni * 16 + l15;
            float bv = b2a[col];
            #pragma unroll
            for (int r = 0; r < 4; ++r) {
                size_t o = (size_t)(m0 + quad * 4 + r) * 256 + col;
                U[o]  = f2bf(aU[ni][r] + bv);
                Hs[o] = f2bf(aH[ni][r]);
            }
        }
    }
}

// ---------------------------------------------------------------------------
// nodeC (fused): rows m0=bx*16. vin=Ssc@W2b+b2bs [LDS] -> t3=relu(vin@W3a+b3a)
// [LDS] -> v2=t3@W3b+b3b [LDS] -> C4=v2@W4r+b4ap, Vs=v2@W4s (dual, global).
// ---------------------------------------------------------------------------
__global__ __launch_bounds__(256) void node_fusedC_kernel(
        const unsigned short* __restrict__ Ssc,
        const unsigned short* __restrict__ Wp2b, const float* __restrict__ b2bs,
        const unsigned short* __restrict__ Wp3a, const float* __restrict__ b3a,
        const unsigned short* __restrict__ Wp3b, const float* __restrict__ b3b,
        const unsigned short* __restrict__ Wp4r, const float* __restrict__ b4ap,
        const unsigned short* __restrict__ Wp4s,
        unsigned short* __restrict__ C4, unsigned short* __restrict__ Vs) {
    __shared__ __align__(16) unsigned short buf0[16 * 264];
    __shared__ __align__(16) unsigned short buf1[16 * 264];
    const int m0 = blockIdx.x * 16;
    const int tid  = threadIdx.x;
    const int wave = tid >> 6;
    const int lane = tid & 63;
    const int l15  = lane & 15;
    const int quad = lane >> 4;
    const int n0   = wave * 64;
    const int koff = quad * 8;

    // ---- S1: vin = Ssc@W2b + b2bs -> buf0 ----
    {
        float4v acc[4];
        #pragma unroll
        for (int ni = 0; ni < 4; ++ni) acc[ni] = (float4v)(0.0f);
        for (int kb = 0; kb < 8; ++kb) {
            short8 af = *(const short8*)(Ssc + (size_t)(m0 + l15) * 256 + kb * 32 + koff);
            short8 bf[4];
            #pragma unroll
            for (int ni = 0; ni < 4; ++ni)
                bf[ni] = *(const short8*)(Wp2b + ((size_t)kb * 256 + n0 + ni * 16 + l15) * 32 + koff);
            #pragma unroll
            for (int ni = 0; ni < 4; ++ni)
                acc[ni] = __builtin_amdgcn_mfma_f32_16x16x32_bf16(af, bf[ni], acc[ni], 0, 0, 0);
        }
        #pragma unroll
        for (int ni = 0; ni < 4; ++ni) {
            int col = n0 + ni * 16 + l15;
            float bv = b2bs[col];
            #pragma unroll
            for (int r = 0; r < 4; ++r)
                buf0[(quad * 4 + r) * 264 + col] = f2bf(acc[ni][r] + bv);
        }
    }
    __syncthreads();

    // ---- S2: t3 = relu(vin@W3a + b3a) -> buf1 ----
    {
        float4v acc[4];
        #pragma unroll
        for (int ni = 0; ni < 4; ++ni) acc[ni] = (float4v)(0.0f);
        for (int kb = 0; kb < 8; ++kb) {
            short8 af = *(const short8*)(&buf0[l15 * 264 + kb * 32 + koff]);
            short8 bf[4];
            #pragma unroll
            for (int ni = 0; ni < 4; ++ni)
                bf[ni] = *(const short8*)(Wp3a + ((size_t)kb * 256 + n0 + ni * 16 + l15) * 32 + koff);
            #pragma unroll
            for (int ni = 0; ni < 4; ++ni)
                acc[ni] = __builtin_amdgcn_mfma_f32_16x16x32_bf16(af, bf[ni], acc[ni], 0, 0, 0);
        }
        #pragma unroll
        for (int ni = 0; ni < 4; ++ni) {
            int col = n0 + ni * 16 + l15;
            float bv = b3a[col];
            #pragma unroll
            for (int r = 0; r < 4; ++r) {
                float v = acc[ni][r] + bv;
                v = v > 0.f ? v : 0.f;
                buf1[(quad * 4 + r) * 264 + col] = f2bf(v);
            }
        }
    }
    __syncthreads();

    // ---- S3: v2 = t3@W3b + b3b -> buf0 ----
    {
        float4v acc[4];
        #pragma unroll
        for (int ni = 0; ni < 4; ++ni) acc[ni] = (float4v)(0.0f);
        for (int kb = 0; kb < 8; ++kb) {
            short8 af = *(const short8*)(&buf1[l15 * 264 + kb * 32 + koff]);
            short8 bf[4];
            #pragma unroll
            for (int ni = 0; ni < 4; ++ni)
                bf[ni] = *(const short8*)(Wp3b + ((size_t)kb * 256 + n0 + ni * 16 + l15) * 32 + koff);
            #pragma unroll
            for (int ni = 0; ni < 4; ++ni)
                acc[ni] = __builtin_amdgcn_mfma_f32_16x16x32_bf16(af, bf[ni], acc[ni], 0, 0, 0);
        }
        __syncthreads();   // buf0's S1 readers done (S2 barrier); safe rewrite
        #pragma unroll
        for (int ni = 0; ni < 4; ++ni) {
            int col = n0 + ni * 16 + l15;
            float bv = b3b[col];
            #pragma unroll
            for (int r = 0; r < 4; ++r)
                buf0[(quad * 4 + r) * 264 + col] = f2bf(acc[ni][r] + bv);
        }
    }
    __syncthreads();

    // ---- S4 (dual): C4 = v2@W4r + b4ap ; Vs = v2@W4s ----
    {
        float4v aC[4], aV[4];
        #pragma unroll
        for (int ni = 0; ni < 4; ++ni) { aC[ni] = (float4v)(0.0f); aV[ni] = (float4v)(0.0f); }
        for (int kb = 0; kb < 8; ++kb) {
            short8 af = *(const short8*)(&buf0[l15 * 264 + kb * 32 + koff]);
            #pragma unroll
            for (int ni = 0; ni < 4; ++ni) {
                short8 bc = *(const short8*)(Wp4r + ((size_t)kb * 256 + n0 + ni * 16 + l15) * 32 + koff);
                short8 bv = *(const short8*)(Wp4s + ((size_t)kb * 256 + n0 + ni * 16 + l15) * 32 + koff);
                aC[ni] = __builtin_amdgcn_mfma_f32_16x16x32_bf16(af, bc, aC[ni], 0, 0, 0);
                aV[ni] = __builtin_amdgcn_mfma_f32_16x16x32_bf16(af, bv, aV[ni], 0, 0, 0);
            }
        }
        #pragma unroll
        for (int ni = 0; ni < 4; ++ni) {
            int col = n0 + ni * 16 + l15;
            float bv = b4ap[col];
            #pragma unroll
            for (int r = 0; r < 4; ++r) {
                size_t o = (size_t)(m0 + quad * 4 + r) * 256 + col;
                C4[o] = f2bf(aC[ni][r] + bv);
                Vs[o] = f2bf(aV[ni][r]);
            }
        }
    }
}

// ---------------------------------------------------------------------------
// colsum: Ssc[g,c] = 0.01*( sum_j relu(U[g,c]+Hs[b,j,c]) - relu(U[g,c]+Hs[b,i,c]) )
// ---------------------------------------------------------------------------
__global__ __launch_bounds__(256) void colsum_kernel(
        const unsigned short* __restrict__ U, const unsigned short* __restrict__ Hs,
        unsigned short* __restrict__ Ssc) {
    const int g = blockIdx.x;
    const int b = g / 100, i = g - b * 100;
    const int c = threadIdx.x;
    const float u = bf2f(U[(size_t)g * 256 + c]);
    const unsigned short* base = Hs + (size_t)b * 100 * 256 + c;
    float s = 0.f;
    #pragma unroll 4
    for (int j = 0; j < 100; ++j) {
        float v = u + bf2f(base[(size_t)j * 256]);
        s += (v > 0.f ? v : 0.f);
    }
    float vi = u + bf2f(base[(size_t)i * 256]);
    s -= (vi > 0.f ? vi : 0.f);
    Ssc[(size_t)g * 256 + c] = f2bf(s * 0.01f);
}

// ---------------------------------------------------------------------------
// Phase B: grid (3200,2), block 512 (8 waves x 32 cols), M=64 (<=50 real).
// stage0: t2 = relu(U_i + Hs_j) -> LDS ONCE (8 rows/wave, pk-packed).
// K-loop: acc[4][2] (32 regs); af loaded per-mi (live ~60 < 84 cap).
// z4 = relu(C4_i + Vs_j + acc) -> LDS (aliases t2s); 32 elems/thread.
// projection: waves 0-3, 8 MFMA vs Wfp; lanes l15<4 store fp32.
// LDS 33792 B. __launch_bounds__(512,6): 24 waves/CU (3 blocks x 8 waves).
// ---------------------------------------------------------------------------
__global__ __launch_bounds__(512, 6) void edge_phaseB_kernel(
        const unsigned short* __restrict__ Hs, const unsigned short* __restrict__ Vs,
        const unsigned short* __restrict__ U, const unsigned short* __restrict__ C4,
        const unsigned short* __restrict__ Wpz, const unsigned short* __restrict__ Wfp,
        const float* __restrict__ bfv,
        float* __restrict__ out) {
    __shared__ __align__(16) unsigned short t2s[64 * 264]; // 33792 B (z4 aliases later)
    const int g = blockIdx.x, hb = blockIdx.y;
    const int b = g / 100, nr = g - b * 100;
    const int nrows = hb ? 49 : 50;
    const int k0 = hb * 50;
    const int tid  = threadIdx.x;
    const int wave = tid >> 6;          // 0..7
    const int lane = tid & 63;
    const int l15  = lane & 15;
    const int quad = lane >> 4;
    const int n0   = wave * 32;         // 32-col slice per wave
    const int koff = quad * 8;

    // ---- stage 0: build t2 tile ONCE (8 rows/wave; pk-pack; pad rows 0) ----
    {
        const int c = lane * 4;
        ushort4v uv = *(const ushort4v*)(U + (size_t)g * 256 + c);
        float u0 = bf2f(uv[0]), u1 = bf2f(uv[1]), u2 = bf2f(uv[2]), u3 = bf2f(uv[3]);
        for (int r = wave; r < 64; r += 8) {
            unsigned int p01 = 0, p23 = 0;
            if (r < nrows) {
                int k = k0 + r;
                int j = k + (k >= nr ? 1 : 0);
                ushort4v hv = *(const ushort4v*)(Hs + (size_t)(b * 100 + j) * 256 + c);
                float t0 = u0 + bf2f(hv[0]); t0 = t0 > 0.f ? t0 : 0.f;
                float t1 = u1 + bf2f(hv[1]); t1 = t1 > 0.f ? t1 : 0.f;
                float t2 = u2 + bf2f(hv[2]); t2 = t2 > 0.f ? t2 : 0.f;
                float t3 = u3 + bf2f(hv[3]); t3 = t3 > 0.f ? t3 : 0.f;
                p01 = f2bf_pk(t0, t1);
                p23 = f2bf_pk(t2, t3);
            }
            unsigned int* dst = (unsigned int*)(&t2s[r * 264 + c]);
            dst[0] = p01;
            dst[1] = p23;
        }
    }
    __syncthreads();

    // ---- K-loop: z4 GEMM (K=256), A from LDS, B from L2; acc[4][2] ----
    float4v acc[4][2];
    #pragma unroll
    for (int mi = 0; mi < 4; ++mi) {
        acc[mi][0] = (float4v)(0.0f);
        acc[mi][1] = (float4v)(0.0f);
    }

    #pragma unroll 1              // spill guard (R10 lesson); live-set kept < 84-reg cap
    for (int kb = 0; kb < 8; ++kb) {
        short8 bf0 = *(const short8*)(Wpz + ((size_t)kb * 256 + n0 + l15) * 32 + koff);
        short8 bf1 = *(const short8*)(Wpz + ((size_t)kb * 256 + n0 + 16 + l15) * 32 + koff);
        #pragma unroll
        for (int mi = 0; mi < 4; ++mi) {
            short8 af = *(const short8*)(&t2s[(mi * 16 + l15) * 264 + kb * 32 + koff]);
            acc[mi][0] = __builtin_amdgcn_mfma_f32_16x16x32_bf16(af, bf0, acc[mi][0], 0, 0, 0);
            acc[mi][1] = __builtin_amdgcn_mfma_f32_16x16x32_bf16(af, bf1, acc[mi][1], 0, 0, 0);
        }
    }
    __syncthreads();            // all t2s A-reads done; z4 aliases t2s below

    // ---- z4 = relu(C4_i + Vs_j + acc) -> LDS (C-layout), 32 elems/thread ----
    {
        float c4v0 = bf2f(C4[(size_t)g * 256 + n0 + l15]);
        float c4v1 = bf2f(C4[(size_t)g * 256 + n0 + 16 + l15]);
        #pragma unroll
        for (int mi = 0; mi < 4; ++mi) {
            #pragma unroll
            for (int r = 0; r < 4; ++r) {
                int row = mi * 16 + quad * 4 + r;      // local edge idx (C-layout)
                int k = k0 + row;
                int j = (row < nrows) ? (k + (k >= nr ? 1 : 0)) : 0;
                const unsigned short* vsr = Vs + (size_t)(b * 100 + j) * 256;
                float z0 = c4v0 + bf2f(vsr[n0 + l15]) + acc[mi][0][r];
                float z1 = c4v1 + bf2f(vsr[n0 + 16 + l15]) + acc[mi][1][r];
                z0 = z0 > 0.f ? z0 : 0.f;
                z1 = z1 > 0.f ? z1 : 0.f;
                t2s[row * 264 + n0 + l15]      = f2bf(z0);
                t2s[row * 264 + n0 + 16 + l15] = f2bf(z1);
            }
        }
    }
    __syncthreads();

    // ---- projection: waves 0-3, rows wave*16..+15; 8 MFMA vs Wfp ----
    if (wave < 4) {
        float4v pacc = (float4v)(0.0f);
        #pragma unroll
        for (int kb = 0; kb < 8; ++kb) {
            short8 za = *(const short8*)(&t2s[(wave * 16 + l15) * 264 + kb * 32 + koff]);
            short8 wb = *(const short8*)(Wfp + (size_t)kb * 512 + l15 * 32 + koff);
            pacc = __builtin_amdgcn_mfma_f32_16x16x32_bf16(za, wb, pacc, 0, 0, 0);
        }
        if (l15 < 4) {
            float bv = bfv[l15];
            #pragma unroll
            for (int r = 0; r < 4; ++r) {
                int row = wave * 16 + quad * 4 + r;
                if (row < nrows)
                    out[((size_t)b * 9900 + nr * 99 + k0 + row) * 4 + l15] = pacc[r] + bv;
            }
        }
    }
}

extern "C" void kernel_launch(void* const* d_in, const int* in_sizes, int n_in,
                              void* d_out, int out_size, void* d_ws, size_t ws_size,
                              hipStream_t stream) {
    const float* x   = (const float*)d_in[0];
    const float* w1a = (const float*)d_in[3];
    const float* b1a = (const float*)d_in[4];
    const float* w1b = (const float*)d_in[5];
    const float* b1b = (const float*)d_in[6];
    const float* w2a = (const float*)d_in[7];
    const float* b2a = (const float*)d_in[8];
    const float* w2b = (const float*)d_in[9];
    const float* b2b = (const float*)d_in[10];
    const float* w3a = (const float*)d_in[11];
    const float* b3a = (const float*)d_in[12];
    const float* w3b = (const float*)d_in[13];
    const float* b3b = (const float*)d_in[14];
    const float* w4a = (const float*)d_in[15];
    const float* b4a = (const float*)d_in[16];
    const float* w4b = (const float*)d_in[17];
    const float* b4b = (const float*)d_in[18];
    const float* wo  = (const float*)d_in[19];
    const float* bo  = (const float*)d_in[20];
    float* out = (float*)d_out;
    (void)in_sizes; (void)n_in; (void)out_size; (void)ws_size;

    char* ws = (char*)d_ws;
    size_t off = 0;
    auto alloc = [&](size_t bytes) {
        size_t o = off;
        off = (off + bytes + 255) & ~(size_t)255;
        return o;
    };
    const size_t SLOT_BF = (size_t)3200 * 256 * 2;   // 1.64 MB
    unsigned short* S_U  = (unsigned short*)(ws + alloc(SLOT_BF)); // U
    unsigned short* S_Hs = (unsigned short*)(ws + alloc(SLOT_BF)); // Hs
    unsigned short* S_Vs = (unsigned short*)(ws + alloc(SLOT_BF)); // Vs
    unsigned short* S_4  = (unsigned short*)(ws + alloc(SLOT_BF)); // hin -> Ssc -> C4
    unsigned short* Wp1a = (unsigned short*)(ws + alloc(224 * 256 * 2));
    unsigned short* Wp1b = (unsigned short*)(ws + alloc(256 * 256 * 2));
    unsigned short* Wp2r = (unsigned short*)(ws + alloc(256 * 256 * 2));
    unsigned short* Wp2s = (unsigned short*)(ws + alloc(256 * 256 * 2));
    unsigned short* Wp2b = (unsigned short*)(ws + alloc(256 * 256 * 2));
    unsigned short* Wp3a = (unsigned short*)(ws + alloc(256 * 256 * 2));
    unsigned short* Wp3b = (unsigned short*)(ws + alloc(256 * 256 * 2));
    unsigned short* Wp4r = (unsigned short*)(ws + alloc(256 * 256 * 2));
    unsigned short* Wp4s = (unsigned short*)(ws + alloc(256 * 256 * 2));
    unsigned short* Wpz  = (unsigned short*)(ws + alloc(256 * 256 * 2));
    unsigned short* Wfp  = (unsigned short*)(ws + alloc(8 * 16 * 32 * 2));
    float*          bfv  = (float*)(ws + alloc(4 * 4));
    float*          b4ap = (float*)(ws + alloc(256 * 4));
    float*          b2bs = (float*)(ws + alloc(256 * 4));
    // total ~8 MB (<= 11.2 proven safe)

    unsigned short* hin = S_4;   // [prep, nodeA]
    unsigned short* Ssc = S_4;   // [colsum, nodeC]
    unsigned short* C4  = S_4;   // [nodeC, phaseB] (block-local read-before-write)

    // ---- 5 dispatches ----
    hipLaunchKernelGGL(prep_kernel, dim3(5330), dim3(256), 0, stream,
                       x, w1a, w1b, w2a, w2b, w3a, w3b, w4a, b4a, w4b, b4b, wo, bo, b2b,
                       Wp1a, Wp1b, Wp2r, Wp2s, Wp2b, Wp3a, Wp3b, Wp4r, Wp4s, Wpz,
                       Wfp, bfv, b4ap, b2bs, hin);
    hipLaunchKernelGGL(node_fusedA_kernel, dim3(200), dim3(256), 0, stream,
                       hin, Wp1a, b1a, Wp1b, b1b, Wp2r, b2a, Wp2s, S_U, S_Hs);
    hipLaunchKernelGGL(colsum_kernel, dim3(3200), dim3(256), 0, stream, S_U, S_Hs, Ssc);
    hipLaunchKernelGGL(node_fusedC_kernel, dim3(200), dim3(256), 0, stream,
                       Ssc, Wp2b, b2bs, Wp3a, b3a, Wp3b, b3b, Wp4r, b4ap, Wp4s, C4, S_Vs);
    hipLaunchKernelGGL(edge_phaseB_kernel, dim3(3200, 2), dim3(512), 0, stream,
                       S_Hs, S_Vs, S_U, C4, Wpz, Wfp, bfv, out);
}

// Round 15
// 256.220 us; speedup vs baseline: 1.4551x; 1.0133x over previous
//
#include <hip/hip_runtime.h>
#include <hip/hip_bf16.h>
#include <stdint.h>

// ---------------------------------------------------------------------------
// NRI-style MLP encoder. B=32, T=50, N=100, D=4, E=9900, H=256. fp32 I/O.
// R7 formulation (send terms are node GEMMs; only edge GEMM is K=256 t2@Wpz).
// R15 changes (rest-of-pipeline ~143us vs phaseB 116us):
//  - nodeA/nodeC: 512 thr (8 waves x 32-col tiles), same 200 blocks -> 2x
//    resident waves; these kernels run <1 block/CU so barrier-chained stages
//    were latency-exposed at 4 waves.
//  - colsum: 4 cols/thread via ushort4 (wave reads full 512B row/j), grid 800.
//  - phaseB: z4 col-pair packed via one f2bf_pk + shr (R14 otherwise: 512thr,
//    acc[4][2], (512,6), unroll-1 spill guard — WRITE_SIZE must stay ~5MB).
// Pipeline (5 dispatches): prep, nodeA, colsum, nodeC, phaseB.
// ---------------------------------------------------------------------------

typedef __attribute__((ext_vector_type(8))) short short8;
typedef __attribute__((ext_vector_type(4))) float float4v;
typedef __attribute__((ext_vector_type(4))) unsigned short ushort4v;

__device__ inline float bf2f(unsigned short u) {
    union { unsigned int i; float f; } v; v.i = ((unsigned int)u) << 16; return v.f;
}

#if __has_builtin(__builtin_amdgcn_cvt_pk_bf16_f32)
typedef __attribute__((ext_vector_type(2))) __bf16 bf16x2;
__device__ inline unsigned int f2bf_pk(float a, float b) {   // [15:0]=a [31:16]=b
    union { bf16x2 v; unsigned int u; } c;
    c.v = __builtin_amdgcn_cvt_pk_bf16_f32(a, b);
    return c.u;
}
__device__ inline unsigned short f2bf(float f) {
    return (unsigned short)(f2bf_pk(f, f) & 0xFFFFu);
}
#else
__device__ inline unsigned short f2bf(float f) {
    union { float f; unsigned int i; } v; v.f = f;
    unsigned int i = v.i;
    return (unsigned short)((i + 0x7FFFu + ((i >> 16) & 1u)) >> 16);
}
__device__ inline unsigned int f2bf_pk(float a, float b) {
    return (unsigned int)f2bf(a) | ((unsigned int)f2bf(b) << 16);
}
#endif

// ---------------------------------------------------------------------------
// MEGA-PREP: bx<2272 weight packs | <2528 Wpz=pack(w2b@w4a_e) | <2530 misc
// (Wfp/bfv/b4ap/b2bs) | rest repack x. fp32 in, bf16 packed out.
// ---------------------------------------------------------------------------
__global__ __launch_bounds__(256) void prep_kernel(
        const float* __restrict__ x,
        const float* __restrict__ w1a, const float* __restrict__ w1b,
        const float* __restrict__ w2a, const float* __restrict__ w2b,
        const float* __restrict__ w3a, const float* __restrict__ w3b,
        const float* __restrict__ w4a, const float* __restrict__ b4a,
        const float* __restrict__ w4b, const float* __restrict__ b4b,
        const float* __restrict__ wo,  const float* __restrict__ bo,
        const float* __restrict__ b2b,
        unsigned short* __restrict__ Wp1a, unsigned short* __restrict__ Wp1b,
        unsigned short* __restrict__ Wp2r, unsigned short* __restrict__ Wp2s,
        unsigned short* __restrict__ Wp2b, unsigned short* __restrict__ Wp3a,
        unsigned short* __restrict__ Wp3b, unsigned short* __restrict__ Wp4r,
        unsigned short* __restrict__ Wp4s, unsigned short* __restrict__ Wpz,
        unsigned short* __restrict__ Wfp, float* __restrict__ bfv,
        float* __restrict__ b4ap, float* __restrict__ b2bs,
        unsigned short* __restrict__ hin) {
    int bx = blockIdx.x;
    int tid = threadIdx.x;
    if (bx < 2272) {
        const float* W; unsigned short* Wp; int Kin; int b0;
        if      (bx <  224) { W = w1a;             Wp = Wp1a; Kin = 200; b0 = 0;    }
        else if (bx <  480) { W = w1b;             Wp = Wp1b; Kin = 256; b0 = 224;  }
        else if (bx <  736) { W = w2a;             Wp = Wp2r; Kin = 256; b0 = 480;  }
        else if (bx <  992) { W = w2a + 256 * 256; Wp = Wp2s; Kin = 256; b0 = 736;  }
        else if (bx < 1248) { W = w2b;             Wp = Wp2b; Kin = 256; b0 = 992;  }
        else if (bx < 1504) { W = w3a;             Wp = Wp3a; Kin = 256; b0 = 1248; }
        else if (bx < 1760) { W = w3b;             Wp = Wp3b; Kin = 256; b0 = 1504; }
        else if (bx < 2016) { W = w4a;             Wp = Wp4r; Kin = 256; b0 = 1760; }
        else                { W = w4a + 256 * 256; Wp = Wp4s; Kin = 256; b0 = 2016; }
        int idx = (bx - b0) * 256 + tid;
        int k = idx >> 8, n = idx & 255;
        unsigned short v = (k < Kin) ? f2bf(W[k * 256 + n]) : (unsigned short)0;
        Wp[((size_t)(k >> 5) * 256 + n) * 32 + (k & 31)] = v;
    } else if (bx < 2528) {
        int k = bx - 2272, c = tid;
        float s = 0.f;
        for (int t = 0; t < 256; ++t)
            s += w2b[k * 256 + t] * w4a[(size_t)(512 + t) * 256 + c];
        Wpz[((size_t)(k >> 5) * 256 + c) * 32 + (k & 31)] = f2bf(s);
    } else if (bx < 2530) {
        int k = tid;
        if (bx == 2528) {
            float a[4] = {0.f, 0.f, 0.f, 0.f};
            for (int c = 0; c < 256; ++c) {
                float wv = w4b[k * 256 + c];
                #pragma unroll
                for (int o = 0; o < 4; ++o) a[o] += wv * wo[c * 4 + o];
            }
            #pragma unroll
            for (int n = 0; n < 16; ++n)
                Wfp[(size_t)(k >> 5) * 512 + n * 32 + (k & 31)] =
                    (n < 4) ? f2bf(a[n]) : (unsigned short)0;
            if (k < 4) {
                float s = bo[k];
                for (int c = 0; c < 256; ++c) s += b4b[c] * wo[c * 4 + k];
                bfv[k] = s;
            }
        } else {
            float s = b4a[k];
            for (int t = 0; t < 256; ++t)
                s += b2b[t] * w4a[(size_t)(512 + t) * 256 + k];
            b4ap[k] = s;
            b2bs[k] = 0.99f * b2b[k];
        }
    } else {
        int idx = (bx - 2530) * 256 + tid;
        if (idx < 3200 * 224) {
            int row = idx / 224;
            int c = idx - row * 224;
            int b = row / 100, n = row - b * 100;
            unsigned short v = 0;
            if (c < 200) {
                int t = c >> 2, d = c & 3;
                v = f2bf(x[(((size_t)(b * 50 + t)) * 100 + n) * 4 + d]);
            }
            hin[(size_t)row * 224 + c] = v;
        }
    }
}

// ---------------------------------------------------------------------------
// nodeA (fused, 512 thr = 8 waves x 32 cols): rows m0=bx*16.
// t1=relu(hin@W1a+b1a) [LDS] -> h=t1@W1b+b1b [LDS] -> U,Hs (dual, global).
// ---------------------------------------------------------------------------
__global__ __launch_bounds__(512) void node_fusedA_kernel(
        const unsigned short* __restrict__ hin,
        const unsigned short* __restrict__ Wp1a, const float* __restrict__ b1a,
        const unsigned short* __restrict__ Wp1b, const float* __restrict__ b1b,
        const unsigned short* __restrict__ Wp2r, const float* __restrict__ b2a,
        const unsigned short* __restrict__ Wp2s,
        unsigned short* __restrict__ U, unsigned short* __restrict__ Hs) {
    __shared__ __align__(16) unsigned short t1s[16 * 264];
    __shared__ __align__(16) unsigned short hs2[16 * 264];
    const int m0 = blockIdx.x * 16;
    const int tid  = threadIdx.x;
    const int wave = tid >> 6;          // 0..7
    const int lane = tid & 63;
    const int l15  = lane & 15;
    const int quad = lane >> 4;
    const int n0   = wave * 32;
    const int koff = quad * 8;

    // ---- S1: t1 = relu(hin@W1a + b1a), K=224 ----
    {
        float4v acc[2];
        acc[0] = (float4v)(0.0f); acc[1] = (float4v)(0.0f);
        for (int kb = 0; kb < 7; ++kb) {
            short8 af = *(const short8*)(hin + (size_t)(m0 + l15) * 224 + kb * 32 + koff);
            #pragma unroll
            for (int ni = 0; ni < 2; ++ni) {
                short8 bf = *(const short8*)(Wp1a + ((size_t)kb * 256 + n0 + ni * 16 + l15) * 32 + koff);
                acc[ni] = __builtin_amdgcn_mfma_f32_16x16x32_bf16(af, bf, acc[ni], 0, 0, 0);
            }
        }
        #pragma unroll
        for (int ni = 0; ni < 2; ++ni) {
            int col = n0 + ni * 16 + l15;
            float bv = b1a[col];
            #pragma unroll
            for (int r = 0; r < 4; ++r) {
                float v = acc[ni][r] + bv;
                v = v > 0.f ? v : 0.f;
                t1s[(quad * 4 + r) * 264 + col] = f2bf(v);
            }
        }
    }
    __syncthreads();

    // ---- S2: h = t1@W1b + b1b ----
    {
        float4v acc[2];
        acc[0] = (float4v)(0.0f); acc[1] = (float4v)(0.0f);
        for (int kb = 0; kb < 8; ++kb) {
            short8 af = *(const short8*)(&t1s[l15 * 264 + kb * 32 + koff]);
            #pragma unroll
            for (int ni = 0; ni < 2; ++ni) {
                short8 bf = *(const short8*)(Wp1b + ((size_t)kb * 256 + n0 + ni * 16 + l15) * 32 + koff);
                acc[ni] = __builtin_amdgcn_mfma_f32_16x16x32_bf16(af, bf, acc[ni], 0, 0, 0);
            }
        }
        #pragma unroll
        for (int ni = 0; ni < 2; ++ni) {
            int col = n0 + ni * 16 + l15;
            float bv = b1b[col];
            #pragma unroll
            for (int r = 0; r < 4; ++r)
                hs2[(quad * 4 + r) * 264 + col] = f2bf(acc[ni][r] + bv);
        }
    }
    __syncthreads();

    // ---- S3 (dual): U = h@W2r + b2a ; Hs = h@W2s ----
    {
        float4v aU[2], aH[2];
        aU[0] = (float4v)(0.0f); aU[1] = (float4v)(0.0f);
        aH[0] = (float4v)(0.0f); aH[1] = (float4v)(0.0f);
        for (int kb = 0; kb < 8; ++kb) {
            short8 af = *(const short8*)(&hs2[l15 * 264 + kb * 32 + koff]);
            #pragma unroll
            for (int ni = 0; ni < 2; ++ni) {
                short8 bu = *(const short8*)(Wp2r + ((size_t)kb * 256 + n0 + ni * 16 + l15) * 32 + koff);
                short8 bh = *(const short8*)(Wp2s + ((size_t)kb * 256 + n0 + ni * 16 + l15) * 32 + koff);
                aU[ni] = __builtin_amdgcn_mfma_f32_16x16x32_bf16(af, bu, aU[ni], 0, 0, 0);
                aH[ni] = __builtin_amdgcn_mfma_f32_16x16x32_bf16(af, bh, aH[ni], 0, 0, 0);
            }
        }
        #pragma unroll
        for (int ni = 0; ni < 2; ++ni) {
            int col = n0 + ni * 16 + l15;
            float bv = b2a[col];
            #pragma unroll
            for (int r = 0; r < 4; ++r) {
                size_t o = (size_t)(m0 + quad * 4 + r) * 256 + col;
                U[o]  = f2bf(aU[ni][r] + bv);
                Hs[o] = f2bf(aH[ni][r]);
            }
        }
    }
}

// ---------------------------------------------------------------------------
// nodeC (fused, 512 thr = 8 waves x 32 cols): rows m0=bx*16.
// vin [LDS] -> t3 [LDS] -> v2 [LDS] -> C4,Vs (dual, global).
// ---------------------------------------------------------------------------
__global__ __launch_bounds__(512) void node_fusedC_kernel(
        const unsigned short* __restrict__ Ssc,
        const unsigned short* __restrict__ Wp2b, const float* __restrict__ b2bs,
        const unsigned short* __restrict__ Wp3a, const float* __restrict__ b3a,
        const unsigned short* __restrict__ Wp3b, const float* __restrict__ b3b,
        const unsigned short* __restrict__ Wp4r, const float* __restrict__ b4ap,
        const unsigned short* __restrict__ Wp4s,
        unsigned short* __restrict__ C4, unsigned short* __restrict__ Vs) {
    __shared__ __align__(16) unsigned short buf0[16 * 264];
    __shared__ __align__(16) unsigned short buf1[16 * 264];
    const int m0 = blockIdx.x * 16;
    const int tid  = threadIdx.x;
    const int wave = tid >> 6;
    const int lane = tid & 63;
    const int l15  = lane & 15;
    const int quad = lane >> 4;
    const int n0   = wave * 32;
    const int koff = quad * 8;

    // ---- S1: vin = Ssc@W2b + b2bs -> buf0 ----
    {
        float4v acc[2];
        acc[0] = (float4v)(0.0f); acc[1] = (float4v)(0.0f);
        for (int kb = 0; kb < 8; ++kb) {
            short8 af = *(const short8*)(Ssc + (size_t)(m0 + l15) * 256 + kb * 32 + koff);
            #pragma unroll
            for (int ni = 0; ni < 2; ++ni) {
                short8 bf = *(const short8*)(Wp2b + ((size_t)kb * 256 + n0 + ni * 16 + l15) * 32 + koff);
                acc[ni] = __builtin_amdgcn_mfma_f32_16x16x32_bf16(af, bf, acc[ni], 0, 0, 0);
            }
        }
        #pragma unroll
        for (int ni = 0; ni < 2; ++ni) {
            int col = n0 + ni * 16 + l15;
            float bv = b2bs[col];
            #pragma unroll
            for (int r = 0; r < 4; ++r)
                buf0[(quad * 4 + r) * 264 + col] = f2bf(acc[ni][r] + bv);
        }
    }
    __syncthreads();

    // ---- S2: t3 = relu(vin@W3a + b3a) -> buf1 ----
    {
        float4v acc[2];
        acc[0] = (float4v)(0.0f); acc[1] = (float4v)(0.0f);
        for (int kb = 0; kb < 8; ++kb) {
            short8 af = *(const short8*)(&buf0[l15 * 264 + kb * 32 + koff]);
            #pragma unroll
            for (int ni = 0; ni < 2; ++ni) {
                short8 bf = *(const short8*)(Wp3a + ((size_t)kb * 256 + n0 + ni * 16 + l15) * 32 + koff);
                acc[ni] = __builtin_amdgcn_mfma_f32_16x16x32_bf16(af, bf, acc[ni], 0, 0, 0);
            }
        }
        #pragma unroll
        for (int ni = 0; ni < 2; ++ni) {
            int col = n0 + ni * 16 + l15;
            float bv = b3a[col];
            #pragma unroll
            for (int r = 0; r < 4; ++r) {
                float v = acc[ni][r] + bv;
                v = v > 0.f ? v : 0.f;
                buf1[(quad * 4 + r) * 264 + col] = f2bf(v);
            }
        }
    }
    __syncthreads();

    // ---- S3: v2 = t3@W3b + b3b -> buf0 ----
    {
        float4v acc[2];
        acc[0] = (float4v)(0.0f); acc[1] = (float4v)(0.0f);
        for (int kb = 0; kb < 8; ++kb) {
            short8 af = *(const short8*)(&buf1[l15 * 264 + kb * 32 + koff]);
            #pragma unroll
            for (int ni = 0; ni < 2; ++ni) {
                short8 bf = *(const short8*)(Wp3b + ((size_t)kb * 256 + n0 + ni * 16 + l15) * 32 + koff);
                acc[ni] = __builtin_amdgcn_mfma_f32_16x16x32_bf16(af, bf, acc[ni], 0, 0, 0);
            }
        }
        __syncthreads();   // buf0's S1 readers done (S2 barrier); safe rewrite
        #pragma unroll
        for (int ni = 0; ni < 2; ++ni) {
            int col = n0 + ni * 16 + l15;
            float bv = b3b[col];
            #pragma unroll
            for (int r = 0; r < 4; ++r)
                buf0[(quad * 4 + r) * 264 + col] = f2bf(acc[ni][r] + bv);
        }
    }
    __syncthreads();

    // ---- S4 (dual): C4 = v2@W4r + b4ap ; Vs = v2@W4s ----
    {
        float4v aC[2], aV[2];
        aC[0] = (float4v)(0.0f); aC[1] = (float4v)(0.0f);
        aV[0] = (float4v)(0.0f); aV[1] = (float4v)(0.0f);
        for (int kb = 0; kb < 8; ++kb) {
            short8 af = *(const short8*)(&buf0[l15 * 264 + kb * 32 + koff]);
            #pragma unroll
            for (int ni = 0; ni < 2; ++ni) {
                short8 bc = *(const short8*)(Wp4r + ((size_t)kb * 256 + n0 + ni * 16 + l15) * 32 + koff);
                short8 bv = *(const short8*)(Wp4s + ((size_t)kb * 256 + n0 + ni * 16 + l15) * 32 + koff);
                aC[ni] = __builtin_amdgcn_mfma_f32_16x16x32_bf16(af, bc, aC[ni], 0, 0, 0);
                aV[ni] = __builtin_amdgcn_mfma_f32_16x16x32_bf16(af, bv, aV[ni], 0, 0, 0);
            }
        }
        #pragma unroll
        for (int ni = 0; ni < 2; ++ni) {
            int col = n0 + ni * 16 + l15;
            float bv = b4ap[col];
            #pragma unroll
            for (int r = 0; r < 4; ++r) {
                size_t o = (size_t)(m0 + quad * 4 + r) * 256 + col;
                C4[o] = f2bf(aC[ni][r] + bv);
                Vs[o] = f2bf(aV[ni][r]);
            }
        }
    }
}

// ---------------------------------------------------------------------------
// colsum (vectorized): thread handles 4 cols; block = 4 groups. Grid 800.
// Ssc[g,c] = 0.01*( sum_j relu(U[g,c]+Hs[b,j,c]) - relu(U[g,c]+Hs[b,i,c]) )
// ---------------------------------------------------------------------------
__global__ __launch_bounds__(256) void colsum_kernel(
        const unsigned short* __restrict__ U, const unsigned short* __restrict__ Hs,
        unsigned short* __restrict__ Ssc) {
    const int g = blockIdx.x * 4 + (threadIdx.x >> 6);
    const int b = g / 100, i = g - b * 100;
    const int c = (threadIdx.x & 63) * 4;
    ushort4v uv = *(const ushort4v*)(U + (size_t)g * 256 + c);
    const float u0 = bf2f(uv[0]), u1 = bf2f(uv[1]), u2 = bf2f(uv[2]), u3 = bf2f(uv[3]);
    const unsigned short* base = Hs + (size_t)b * 100 * 256 + c;
    float s0 = 0.f, s1 = 0.f, s2 = 0.f, s3 = 0.f;
    #pragma unroll 4
    for (int j = 0; j < 100; ++j) {
        ushort4v hv = *(const ushort4v*)(base + (size_t)j * 256);
        float v0 = u0 + bf2f(hv[0]); s0 += (v0 > 0.f ? v0 : 0.f);
        float v1 = u1 + bf2f(hv[1]); s1 += (v1 > 0.f ? v1 : 0.f);
        float v2 = u2 + bf2f(hv[2]); s2 += (v2 > 0.f ? v2 : 0.f);
        float v3 = u3 + bf2f(hv[3]); s3 += (v3 > 0.f ? v3 : 0.f);
    }
    {
        ushort4v hv = *(const ushort4v*)(base + (size_t)i * 256);
        float v0 = u0 + bf2f(hv[0]); s0 -= (v0 > 0.f ? v0 : 0.f);
        float v1 = u1 + bf2f(hv[1]); s1 -= (v1 > 0.f ? v1 : 0.f);
        float v2 = u2 + bf2f(hv[2]); s2 -= (v2 > 0.f ? v2 : 0.f);
        float v3 = u3 + bf2f(hv[3]); s3 -= (v3 > 0.f ? v3 : 0.f);
    }
    unsigned int* dst = (unsigned int*)(Ssc + (size_t)g * 256 + c);
    dst[0] = f2bf_pk(s0 * 0.01f, s1 * 0.01f);
    dst[1] = f2bf_pk(s2 * 0.01f, s3 * 0.01f);
}

// ---------------------------------------------------------------------------
// Phase B (R14 + z4 pk-trim): grid (3200,2), block 512 (8 waves x 32 cols).
// stage0: t2 -> LDS ONCE (8 rows/wave, pk). K-loop: acc[4][2], unroll 1.
// z4 -> LDS (aliases t2s, pk col-pairs); projection waves 0-3 vs Wfp.
// LDS 33792 B. __launch_bounds__(512,6): 24 waves/CU. No spill (WRITE ~5MB).
// ---------------------------------------------------------------------------
__global__ __launch_bounds__(512, 6) void edge_phaseB_kernel(
        const unsigned short* __restrict__ Hs, const unsigned short* __restrict__ Vs,
        const unsigned short* __restrict__ U, const unsigned short* __restrict__ C4,
        const unsigned short* __restrict__ Wpz, const unsigned short* __restrict__ Wfp,
        const float* __restrict__ bfv,
        float* __restrict__ out) {
    __shared__ __align__(16) unsigned short t2s[64 * 264]; // 33792 B (z4 aliases later)
    const int g = blockIdx.x, hb = blockIdx.y;
    const int b = g / 100, nr = g - b * 100;
    const int nrows = hb ? 49 : 50;
    const int k0 = hb * 50;
    const int tid  = threadIdx.x;
    const int wave = tid >> 6;          // 0..7
    const int lane = tid & 63;
    const int l15  = lane & 15;
    const int quad = lane >> 4;
    const int n0   = wave * 32;         // 32-col slice per wave
    const int koff = quad * 8;

    // ---- stage 0: build t2 tile ONCE (8 rows/wave; pk-pack; pad rows 0) ----
    {
        const int c = lane * 4;
        ushort4v uv = *(const ushort4v*)(U + (size_t)g * 256 + c);
        float u0 = bf2f(uv[0]), u1 = bf2f(uv[1]), u2 = bf2f(uv[2]), u3 = bf2f(uv[3]);
        for (int r = wave; r < 64; r += 8) {
            unsigned int p01 = 0, p23 = 0;
            if (r < nrows) {
                int k = k0 + r;
                int j = k + (k >= nr ? 1 : 0);
                ushort4v hv = *(const ushort4v*)(Hs + (size_t)(b * 100 + j) * 256 + c);
                float t0 = u0 + bf2f(hv[0]); t0 = t0 > 0.f ? t0 : 0.f;
                float t1 = u1 + bf2f(hv[1]); t1 = t1 > 0.f ? t1 : 0.f;
                float t2 = u2 + bf2f(hv[2]); t2 = t2 > 0.f ? t2 : 0.f;
                float t3 = u3 + bf2f(hv[3]); t3 = t3 > 0.f ? t3 : 0.f;
                p01 = f2bf_pk(t0, t1);
                p23 = f2bf_pk(t2, t3);
            }
            unsigned int* dst = (unsigned int*)(&t2s[r * 264 + c]);
            dst[0] = p01;
            dst[1] = p23;
        }
    }
    __syncthreads();

    // ---- K-loop: z4 GEMM (K=256), A from LDS, B from L2; acc[4][2] ----
    float4v acc[4][2];
    #pragma unroll
    for (int mi = 0; mi < 4; ++mi) {
        acc[mi][0] = (float4v)(0.0f);
        acc[mi][1] = (float4v)(0.0f);
    }

    #pragma unroll 1              // spill guard (R10 lesson); live-set kept < 84-reg cap
    for (int kb = 0; kb < 8; ++kb) {
        short8 bf0 = *(const short8*)(Wpz + ((size_t)kb * 256 + n0 + l15) * 32 + koff);
        short8 bf1 = *(const short8*)(Wpz + ((size_t)kb * 256 + n0 + 16 + l15) * 32 + koff);
        #pragma unroll
        for (int mi = 0; mi < 4; ++mi) {
            short8 af = *(const short8*)(&t2s[(mi * 16 + l15) * 264 + kb * 32 + koff]);
            acc[mi][0] = __builtin_amdgcn_mfma_f32_16x16x32_bf16(af, bf0, acc[mi][0], 0, 0, 0);
            acc[mi][1] = __builtin_amdgcn_mfma_f32_16x16x32_bf16(af, bf1, acc[mi][1], 0, 0, 0);
        }
    }
    __syncthreads();            // all t2s A-reads done; z4 aliases t2s below

    // ---- z4 = relu(C4_i + Vs_j + acc) -> LDS (C-layout), pk col-pairs ----
    {
        float c4v0 = bf2f(C4[(size_t)g * 256 + n0 + l15]);
        float c4v1 = bf2f(C4[(size_t)g * 256 + n0 + 16 + l15]);
        #pragma unroll
        for (int mi = 0; mi < 4; ++mi) {
            #pragma unroll
            for (int r = 0; r < 4; ++r) {
                int row = mi * 16 + quad * 4 + r;      // local edge idx (C-layout)
                int k = k0 + row;
                int j = (row < nrows) ? (k + (k >= nr ? 1 : 0)) : 0;
                const unsigned short* vsr = Vs + (size_t)(b * 100 + j) * 256;
                float z0 = c4v0 + bf2f(vsr[n0 + l15]) + acc[mi][0][r];
                float z1 = c4v1 + bf2f(vsr[n0 + 16 + l15]) + acc[mi][1][r];
                z0 = z0 > 0.f ? z0 : 0.f;
                z1 = z1 > 0.f ? z1 : 0.f;
                unsigned int zp = f2bf_pk(z0, z1);
                t2s[row * 264 + n0 + l15]      = (unsigned short)zp;
                t2s[row * 264 + n0 + 16 + l15] = (unsigned short)(zp >> 16);
            }
        }
    }
    __syncthreads();

    // ---- projection: waves 0-3, rows wave*16..+15; 8 MFMA vs Wfp ----
    if (wave < 4) {
        float4v pacc = (float4v)(0.0f);
        #pragma unroll
        for (int kb = 0; kb < 8; ++kb) {
            short8 za = *(const short8*)(&t2s[(wave * 16 + l15) * 264 + kb * 32 + koff]);
            short8 wb = *(const short8*)(Wfp + (size_t)kb * 512 + l15 * 32 + koff);
            pacc = __builtin_amdgcn_mfma_f32_16x16x32_bf16(za, wb, pacc, 0, 0, 0);
        }
        if (l15 < 4) {
            float bv = bfv[l15];
            #pragma unroll
            for (int r = 0; r < 4; ++r) {
                int row = wave * 16 + quad * 4 + r;
                if (row < nrows)
                    out[((size_t)b * 9900 + nr * 99 + k0 + row) * 4 + l15] = pacc[r] + bv;
            }
        }
    }
}

extern "C" void kernel_launch(void* const* d_in, const int* in_sizes, int n_in,
                              void* d_out, int out_size, void* d_ws, size_t ws_size,
                              hipStream_t stream) {
    const float* x   = (const float*)d_in[0];
    const float* w1a = (const float*)d_in[3];
    const float* b1a = (const float*)d_in[4];
    const float* w1b = (const float*)d_in[5];
    const float* b1b = (const float*)d_in[6];
    const float* w2a = (const float*)d_in[7];
    const float* b2a = (const float*)d_in[8];
    const float* w2b = (const float*)d_in[9];
    const float* b2b = (const float*)d_in[10];
    const float* w3a = (const float*)d_in[11];
    const float* b3a = (const float*)d_in[12];
    const float* w3b = (const float*)d_in[13];
    const float* b3b = (const float*)d_in[14];
    const float* w4a = (const float*)d_in[15];
    const float* b4a = (const float*)d_in[16];
    const float* w4b = (const float*)d_in[17];
    const float* b4b = (const float*)d_in[18];
    const float* wo  = (const float*)d_in[19];
    const float* bo  = (const float*)d_in[20];
    float* out = (float*)d_out;
    (void)in_sizes; (void)n_in; (void)out_size; (void)ws_size;

    char* ws = (char*)d_ws;
    size_t off = 0;
    auto alloc = [&](size_t bytes) {
        size_t o = off;
        off = (off + bytes + 255) & ~(size_t)255;
        return o;
    };
    const size_t SLOT_BF = (size_t)3200 * 256 * 2;   // 1.64 MB
    unsigned short* S_U  = (unsigned short*)(ws + alloc(SLOT_BF)); // U
    unsigned short* S_Hs = (unsigned short*)(ws + alloc(SLOT_BF)); // Hs
    unsigned short* S_Vs = (unsigned short*)(ws + alloc(SLOT_BF)); // Vs
    unsigned short* S_4  = (unsigned short*)(ws + alloc(SLOT_BF)); // hin -> Ssc -> C4
    unsigned short* Wp1a = (unsigned short*)(ws + alloc(224 * 256 * 2));
    unsigned short* Wp1b = (unsigned short*)(ws + alloc(256 * 256 * 2));
    unsigned short* Wp2r = (unsigned short*)(ws + alloc(256 * 256 * 2));
    unsigned short* Wp2s = (unsigned short*)(ws + alloc(256 * 256 * 2));
    unsigned short* Wp2b = (unsigned short*)(ws + alloc(256 * 256 * 2));
    unsigned short* Wp3a = (unsigned short*)(ws + alloc(256 * 256 * 2));
    unsigned short* Wp3b = (unsigned short*)(ws + alloc(256 * 256 * 2));
    unsigned short* Wp4r = (unsigned short*)(ws + alloc(256 * 256 * 2));
    unsigned short* Wp4s = (unsigned short*)(ws + alloc(256 * 256 * 2));
    unsigned short* Wpz  = (unsigned short*)(ws + alloc(256 * 256 * 2));
    unsigned short* Wfp  = (unsigned short*)(ws + alloc(8 * 16 * 32 * 2));
    float*          bfv  = (float*)(ws + alloc(4 * 4));
    float*          b4ap = (float*)(ws + alloc(256 * 4));
    float*          b2bs = (float*)(ws + alloc(256 * 4));
    // total ~8 MB (<= 11.2 proven safe)

    unsigned short* hin = S_4;   // [prep, nodeA]
    unsigned short* Ssc = S_4;   // [colsum, nodeC]
    unsigned short* C4  = S_4;   // [nodeC, phaseB] (block-local read-before-write)

    // ---- 5 dispatches ----
    hipLaunchKernelGGL(prep_kernel, dim3(5330), dim3(256), 0, stream,
                       x, w1a, w1b, w2a, w2b, w3a, w3b, w4a, b4a, w4b, b4b, wo, bo, b2b,
                       Wp1a, Wp1b, Wp2r, Wp2s, Wp2b, Wp3a, Wp3b, Wp4r, Wp4s, Wpz,
                       Wfp, bfv, b4ap, b2bs, hin);
    hipLaunchKernelGGL(node_fusedA_kernel, dim3(200), dim3(512), 0, stream,
                       hin, Wp1a, b1a, Wp1b, b1b, Wp2r, b2a, Wp2s, S_U, S_Hs);
    hipLaunchKernelGGL(colsum_kernel, dim3(800), dim3(256), 0, stream, S_U, S_Hs, Ssc);
    hipLaunchKernelGGL(node_fusedC_kernel, dim3(200), dim3(512), 0, stream,
                       Ssc, Wp2b, b2bs, Wp3a, b3a, Wp3b, b3b, Wp4r, b4ap, Wp4s, C4, S_Vs);
    hipLaunchKernelGGL(edge_phaseB_kernel, dim3(3200, 2), dim3(512), 0, stream,
                       S_Hs, S_Vs, S_U, C4, Wpz, Wfp, bfv, out);
}

// Round 16
// 249.125 us; speedup vs baseline: 1.4965x; 1.0285x over previous
//
#include <hip/hip_runtime.h>
#include <hip/hip_bf16.h>
#include <stdint.h>

// ---------------------------------------------------------------------------
// NRI-style MLP encoder. B=32, T=50, N=100, D=4, E=9900, H=256. fp32 I/O.
// R7 formulation (send terms are node GEMMs; only edge GEMM is K=256 t2@Wpz).
// R16 changes:
//  - colsum fused into nodeC stage-0 (Ssc in LDS, same j-order fp32 sums ->
//    bit-identical). Pipeline now 4 dispatches: prep, nodeA, nodeC, phaseB.
//  - phaseB even/odd column pairing: Wpz packed so MFMA tile0=even cols,
//    tile1=odd cols (permuted in prep; Wpz only feeds phaseB). z4-formation
//    uses one dword Vs load + one dword C4 load + one f2bf_pk + one dword
//    LDS store per col-pair; z4 lands in NATURAL order so projection/Wfp
//    unchanged. jtab[64] LDS table replaces per-iter j recompute.
//  - phaseB otherwise R14/R15 config (512thr, acc[4][2], (512,6), unroll-1).
// ---------------------------------------------------------------------------

typedef __attribute__((ext_vector_type(8))) short short8;
typedef __attribute__((ext_vector_type(4))) float float4v;
typedef __attribute__((ext_vector_type(4))) unsigned short ushort4v;
typedef __attribute__((ext_vector_type(4))) unsigned int uint4v;

__device__ inline float bf2f(unsigned short u) {
    union { unsigned int i; float f; } v; v.i = ((unsigned int)u) << 16; return v.f;
}

#if __has_builtin(__builtin_amdgcn_cvt_pk_bf16_f32)
typedef __attribute__((ext_vector_type(2))) __bf16 bf16x2;
__device__ inline unsigned int f2bf_pk(float a, float b) {   // [15:0]=a [31:16]=b
    union { bf16x2 v; unsigned int u; } c;
    c.v = __builtin_amdgcn_cvt_pk_bf16_f32(a, b);
    return c.u;
}
__device__ inline unsigned short f2bf(float f) {
    return (unsigned short)(f2bf_pk(f, f) & 0xFFFFu);
}
#else
__device__ inline unsigned short f2bf(float f) {
    union { float f; unsigned int i; } v; v.f = f;
    unsigned int i = v.i;
    return (unsigned short)((i + 0x7FFFu + ((i >> 16) & 1u)) >> 16);
}
__device__ inline unsigned int f2bf_pk(float a, float b) {
    return (unsigned int)f2bf(a) | ((unsigned int)f2bf(b) << 16);
}
#endif

// ---------------------------------------------------------------------------
// MEGA-PREP: bx<2272 weight packs | <2528 Wpz=pack(w2b@w4a_e, EVEN/ODD perm)
// | <2530 misc (Wfp/bfv/b4ap/b2bs) | rest repack x.
// ---------------------------------------------------------------------------
__global__ __launch_bounds__(256) void prep_kernel(
        const float* __restrict__ x,
        const float* __restrict__ w1a, const float* __restrict__ w1b,
        const float* __restrict__ w2a, const float* __restrict__ w2b,
        const float* __restrict__ w3a, const float* __restrict__ w3b,
        const float* __restrict__ w4a, const float* __restrict__ b4a,
        const float* __restrict__ w4b, const float* __restrict__ b4b,
        const float* __restrict__ wo,  const float* __restrict__ bo,
        const float* __restrict__ b2b,
        unsigned short* __restrict__ Wp1a, unsigned short* __restrict__ Wp1b,
        unsigned short* __restrict__ Wp2r, unsigned short* __restrict__ Wp2s,
        unsigned short* __restrict__ Wp2b, unsigned short* __restrict__ Wp3a,
        unsigned short* __restrict__ Wp3b, unsigned short* __restrict__ Wp4r,
        unsigned short* __restrict__ Wp4s, unsigned short* __restrict__ Wpz,
        unsigned short* __restrict__ Wfp, float* __restrict__ bfv,
        float* __restrict__ b4ap, float* __restrict__ b2bs,
        unsigned short* __restrict__ hin) {
    int bx = blockIdx.x;
    int tid = threadIdx.x;
    if (bx < 2272) {
        const float* W; unsigned short* Wp; int Kin; int b0;
        if      (bx <  224) { W = w1a;             Wp = Wp1a; Kin = 200; b0 = 0;    }
        else if (bx <  480) { W = w1b;             Wp = Wp1b; Kin = 256; b0 = 224;  }
        else if (bx <  736) { W = w2a;             Wp = Wp2r; Kin = 256; b0 = 480;  }
        else if (bx <  992) { W = w2a + 256 * 256; Wp = Wp2s; Kin = 256; b0 = 736;  }
        else if (bx < 1248) { W = w2b;             Wp = Wp2b; Kin = 256; b0 = 992;  }
        else if (bx < 1504) { W = w3a;             Wp = Wp3a; Kin = 256; b0 = 1248; }
        else if (bx < 1760) { W = w3b;             Wp = Wp3b; Kin = 256; b0 = 1504; }
        else if (bx < 2016) { W = w4a;             Wp = Wp4r; Kin = 256; b0 = 1760; }
        else                { W = w4a + 256 * 256; Wp = Wp4s; Kin = 256; b0 = 2016; }
        int idx = (bx - b0) * 256 + tid;
        int k = idx >> 8, n = idx & 255;
        unsigned short v = (k < Kin) ? f2bf(W[k * 256 + n]) : (unsigned short)0;
        Wp[((size_t)(k >> 5) * 256 + n) * 32 + (k & 31)] = v;
    } else if (bx < 2528) {
        int k = bx - 2272, c = tid;           // c = PHYSICAL output col
        float s = 0.f;
        for (int t = 0; t < 256; ++t)
            s += w2b[k * 256 + t] * w4a[(size_t)(512 + t) * 256 + c];
        // even/odd pairing: packed pos n = w*32 + (c&1)*16 + ((c&31)>>1)
        int n = (c & ~31) + (c & 1) * 16 + ((c & 31) >> 1);
        Wpz[((size_t)(k >> 5) * 256 + n) * 32 + (k & 31)] = f2bf(s);
    } else if (bx < 2530) {
        int k = tid;
        if (bx == 2528) {
            float a[4] = {0.f, 0.f, 0.f, 0.f};
            for (int c = 0; c < 256; ++c) {
                float wv = w4b[k * 256 + c];
                #pragma unroll
                for (int o = 0; o < 4; ++o) a[o] += wv * wo[c * 4 + o];
            }
            #pragma unroll
            for (int n = 0; n < 16; ++n)
                Wfp[(size_t)(k >> 5) * 512 + n * 32 + (k & 31)] =
                    (n < 4) ? f2bf(a[n]) : (unsigned short)0;
            if (k < 4) {
                float s = bo[k];
                for (int c = 0; c < 256; ++c) s += b4b[c] * wo[c * 4 + k];
                bfv[k] = s;
            }
        } else {
            float s = b4a[k];
            for (int t = 0; t < 256; ++t)
                s += b2b[t] * w4a[(size_t)(512 + t) * 256 + k];
            b4ap[k] = s;
            b2bs[k] = 0.99f * b2b[k];
        }
    } else {
        int idx = (bx - 2530) * 256 + tid;
        if (idx < 3200 * 224) {
            int row = idx / 224;
            int c = idx - row * 224;
            int b = row / 100, n = row - b * 100;
            unsigned short v = 0;
            if (c < 200) {
                int t = c >> 2, d = c & 3;
                v = f2bf(x[(((size_t)(b * 50 + t)) * 100 + n) * 4 + d]);
            }
            hin[(size_t)row * 224 + c] = v;
        }
    }
}

// ---------------------------------------------------------------------------
// nodeA (fused, 512 thr = 8 waves x 32 cols): rows m0=bx*16.
// t1=relu(hin@W1a+b1a) [LDS] -> h=t1@W1b+b1b [LDS] -> U,Hs (dual, global).
// ---------------------------------------------------------------------------
__global__ __launch_bounds__(512) void node_fusedA_kernel(
        const unsigned short* __restrict__ hin,
        const unsigned short* __restrict__ Wp1a, const float* __restrict__ b1a,
        const unsigned short* __restrict__ Wp1b, const float* __restrict__ b1b,
        const unsigned short* __restrict__ Wp2r, const float* __restrict__ b2a,
        const unsigned short* __restrict__ Wp2s,
        unsigned short* __restrict__ U, unsigned short* __restrict__ Hs) {
    __shared__ __align__(16) unsigned short t1s[16 * 264];
    __shared__ __align__(16) unsigned short hs2[16 * 264];
    const int m0 = blockIdx.x * 16;
    const int tid  = threadIdx.x;
    const int wave = tid >> 6;          // 0..7
    const int lane = tid & 63;
    const int l15  = lane & 15;
    const int quad = lane >> 4;
    const int n0   = wave * 32;
    const int koff = quad * 8;

    // ---- S1: t1 = relu(hin@W1a + b1a), K=224 ----
    {
        float4v acc[2];
        acc[0] = (float4v)(0.0f); acc[1] = (float4v)(0.0f);
        for (int kb = 0; kb < 7; ++kb) {
            short8 af = *(const short8*)(hin + (size_t)(m0 + l15) * 224 + kb * 32 + koff);
            #pragma unroll
            for (int ni = 0; ni < 2; ++ni) {
                short8 bf = *(const short8*)(Wp1a + ((size_t)kb * 256 + n0 + ni * 16 + l15) * 32 + koff);
                acc[ni] = __builtin_amdgcn_mfma_f32_16x16x32_bf16(af, bf, acc[ni], 0, 0, 0);
            }
        }
        #pragma unroll
        for (int ni = 0; ni < 2; ++ni) {
            int col = n0 + ni * 16 + l15;
            float bv = b1a[col];
            #pragma unroll
            for (int r = 0; r < 4; ++r) {
                float v = acc[ni][r] + bv;
                v = v > 0.f ? v : 0.f;
                t1s[(quad * 4 + r) * 264 + col] = f2bf(v);
            }
        }
    }
    __syncthreads();

    // ---- S2: h = t1@W1b + b1b ----
    {
        float4v acc[2];
        acc[0] = (float4v)(0.0f); acc[1] = (float4v)(0.0f);
        for (int kb = 0; kb < 8; ++kb) {
            short8 af = *(const short8*)(&t1s[l15 * 264 + kb * 32 + koff]);
            #pragma unroll
            for (int ni = 0; ni < 2; ++ni) {
                short8 bf = *(const short8*)(Wp1b + ((size_t)kb * 256 + n0 + ni * 16 + l15) * 32 + koff);
                acc[ni] = __builtin_amdgcn_mfma_f32_16x16x32_bf16(af, bf, acc[ni], 0, 0, 0);
            }
        }
        #pragma unroll
        for (int ni = 0; ni < 2; ++ni) {
            int col = n0 + ni * 16 + l15;
            float bv = b1b[col];
            #pragma unroll
            for (int r = 0; r < 4; ++r)
                hs2[(quad * 4 + r) * 264 + col] = f2bf(acc[ni][r] + bv);
        }
    }
    __syncthreads();

    // ---- S3 (dual): U = h@W2r + b2a ; Hs = h@W2s ----
    {
        float4v aU[2], aH[2];
        aU[0] = (float4v)(0.0f); aU[1] = (float4v)(0.0f);
        aH[0] = (float4v)(0.0f); aH[1] = (float4v)(0.0f);
        for (int kb = 0; kb < 8; ++kb) {
            short8 af = *(const short8*)(&hs2[l15 * 264 + kb * 32 + koff]);
            #pragma unroll
            for (int ni = 0; ni < 2; ++ni) {
                short8 bu = *(const short8*)(Wp2r + ((size_t)kb * 256 + n0 + ni * 16 + l15) * 32 + koff);
                short8 bh = *(const short8*)(Wp2s + ((size_t)kb * 256 + n0 + ni * 16 + l15) * 32 + koff);
                aU[ni] = __builtin_amdgcn_mfma_f32_16x16x32_bf16(af, bu, aU[ni], 0, 0, 0);
                aH[ni] = __builtin_amdgcn_mfma_f32_16x16x32_bf16(af, bh, aH[ni], 0, 0, 0);
            }
        }
        #pragma unroll
        for (int ni = 0; ni < 2; ++ni) {
            int col = n0 + ni * 16 + l15;
            float bv = b2a[col];
            #pragma unroll
            for (int r = 0; r < 4; ++r) {
                size_t o = (size_t)(m0 + quad * 4 + r) * 256 + col;
                U[o]  = f2bf(aU[ni][r] + bv);
                Hs[o] = f2bf(aH[ni][r]);
            }
        }
    }
}

// ---------------------------------------------------------------------------
// nodeC (fused + colsum S0, 512 thr): rows m0=bx*16.
// S0: Ssc = 0.01*(sum_j relu(U_g+Hs_bj) - relu(U_g+Hs_bi)) -> buf1 [LDS]
//     (16 groups x 32 thr, 8 cols/thread; same j-order as old colsum).
// S1: vin = Ssc@W2b+b2bs -> buf0 ; S2: t3 -> buf1 ; S3: v2 -> buf0 ;
// S4 (dual): C4 = v2@W4r+b4ap, Vs = v2@W4s -> global.
// ---------------------------------------------------------------------------
__global__ __launch_bounds__(512) void node_fusedC_kernel(
        const unsigned short* __restrict__ U, const unsigned short* __restrict__ Hs,
        const unsigned short* __restrict__ Wp2b, const float* __restrict__ b2bs,
        const unsigned short* __restrict__ Wp3a, const float* __restrict__ b3a,
        const unsigned short* __restrict__ Wp3b, const float* __restrict__ b3b,
        const unsigned short* __restrict__ Wp4r, const float* __restrict__ b4ap,
        const unsigned short* __restrict__ Wp4s,
        unsigned short* __restrict__ C4, unsigned short* __restrict__ Vs) {
    __shared__ __align__(16) unsigned short buf0[16 * 264];
    __shared__ __align__(16) unsigned short buf1[16 * 264];
    const int m0 = blockIdx.x * 16;
    const int tid  = threadIdx.x;
    const int wave = tid >> 6;
    const int lane = tid & 63;
    const int l15  = lane & 15;
    const int quad = lane >> 4;
    const int n0   = wave * 32;
    const int koff = quad * 8;

    // ---- S0: colsum -> buf1 (Ssc rows local 0..15) ----
    {
        const int rl = tid >> 5;           // group 0..15
        const int ct = (tid & 31) * 8;     // 8 cols
        const int g = m0 + rl;
        const int b = g / 100, i = g - b * 100;
        float u[8], s[8];
        {
            ushort4v u0 = *(const ushort4v*)(U + (size_t)g * 256 + ct);
            ushort4v u1 = *(const ushort4v*)(U + (size_t)g * 256 + ct + 4);
            #pragma unroll
            for (int e = 0; e < 4; ++e) { u[e] = bf2f(u0[e]); u[4 + e] = bf2f(u1[e]); }
            #pragma unroll
            for (int e = 0; e < 8; ++e) s[e] = 0.f;
        }
        const unsigned short* base = Hs + (size_t)b * 100 * 256 + ct;
        #pragma unroll 4
        for (int j = 0; j < 100; ++j) {
            ushort4v h0 = *(const ushort4v*)(base + (size_t)j * 256);
            ushort4v h1 = *(const ushort4v*)(base + (size_t)j * 256 + 4);
            #pragma unroll
            for (int e = 0; e < 4; ++e) {
                float v0 = u[e] + bf2f(h0[e]);     s[e]     += (v0 > 0.f ? v0 : 0.f);
                float v1 = u[4 + e] + bf2f(h1[e]); s[4 + e] += (v1 > 0.f ? v1 : 0.f);
            }
        }
        {
            ushort4v h0 = *(const ushort4v*)(base + (size_t)i * 256);
            ushort4v h1 = *(const ushort4v*)(base + (size_t)i * 256 + 4);
            #pragma unroll
            for (int e = 0; e < 4; ++e) {
                float v0 = u[e] + bf2f(h0[e]);     s[e]     -= (v0 > 0.f ? v0 : 0.f);
                float v1 = u[4 + e] + bf2f(h1[e]); s[4 + e] -= (v1 > 0.f ? v1 : 0.f);
            }
        }
        uint4v d;
        d[0] = f2bf_pk(s[0] * 0.01f, s[1] * 0.01f);
        d[1] = f2bf_pk(s[2] * 0.01f, s[3] * 0.01f);
        d[2] = f2bf_pk(s[4] * 0.01f, s[5] * 0.01f);
        d[3] = f2bf_pk(s[6] * 0.01f, s[7] * 0.01f);
        *(uint4v*)(&buf1[rl * 264 + ct]) = d;
    }
    __syncthreads();

    // ---- S1: vin = Ssc@W2b + b2bs -> buf0 ----
    {
        float4v acc[2];
        acc[0] = (float4v)(0.0f); acc[1] = (float4v)(0.0f);
        for (int kb = 0; kb < 8; ++kb) {
            short8 af = *(const short8*)(&buf1[l15 * 264 + kb * 32 + koff]);
            #pragma unroll
            for (int ni = 0; ni < 2; ++ni) {
                short8 bf = *(const short8*)(Wp2b + ((size_t)kb * 256 + n0 + ni * 16 + l15) * 32 + koff);
                acc[ni] = __builtin_amdgcn_mfma_f32_16x16x32_bf16(af, bf, acc[ni], 0, 0, 0);
            }
        }
        #pragma unroll
        for (int ni = 0; ni < 2; ++ni) {
            int col = n0 + ni * 16 + l15;
            float bv = b2bs[col];
            #pragma unroll
            for (int r = 0; r < 4; ++r)
                buf0[(quad * 4 + r) * 264 + col] = f2bf(acc[ni][r] + bv);
        }
    }
    __syncthreads();

    // ---- S2: t3 = relu(vin@W3a + b3a) -> buf1 ----
    {
        float4v acc[2];
        acc[0] = (float4v)(0.0f); acc[1] = (float4v)(0.0f);
        for (int kb = 0; kb < 8; ++kb) {
            short8 af = *(const short8*)(&buf0[l15 * 264 + kb * 32 + koff]);
            #pragma unroll
            for (int ni = 0; ni < 2; ++ni) {
                short8 bf = *(const short8*)(Wp3a + ((size_t)kb * 256 + n0 + ni * 16 + l15) * 32 + koff);
                acc[ni] = __builtin_amdgcn_mfma_f32_16x16x32_bf16(af, bf, acc[ni], 0, 0, 0);
            }
        }
        __syncthreads();   // buf1's S1 readers done; safe rewrite
        #pragma unroll
        for (int ni = 0; ni < 2; ++ni) {
            int col = n0 + ni * 16 + l15;
            float bv = b3a[col];
            #pragma unroll
            for (int r = 0; r < 4; ++r) {
                float v = acc[ni][r] + bv;
                v = v > 0.f ? v : 0.f;
                buf1[(quad * 4 + r) * 264 + col] = f2bf(v);
            }
        }
    }
    __syncthreads();

    // ---- S3: v2 = t3@W3b + b3b -> buf0 ----
    {
        float4v acc[2];
        acc[0] = (float4v)(0.0f); acc[1] = (float4v)(0.0f);
        for (int kb = 0; kb < 8; ++kb) {
            short8 af = *(const short8*)(&buf1[l15 * 264 + kb * 32 + koff]);
            #pragma unroll
            for (int ni = 0; ni < 2; ++ni) {
                short8 bf = *(const short8*)(Wp3b + ((size_t)kb * 256 + n0 + ni * 16 + l15) * 32 + koff);
                acc[ni] = __builtin_amdgcn_mfma_f32_16x16x32_bf16(af, bf, acc[ni], 0, 0, 0);
            }
        }
        __syncthreads();   // buf0's S2 readers done; safe rewrite
        #pragma unroll
        for (int ni = 0; ni < 2; ++ni) {
            int col = n0 + ni * 16 + l15;
            float bv = b3b[col];
            #pragma unroll
            for (int r = 0; r < 4; ++r)
                buf0[(quad * 4 + r) * 264 + col] = f2bf(acc[ni][r] + bv);
        }
    }
    __syncthreads();

    // ---- S4 (dual): C4 = v2@W4r + b4ap ; Vs = v2@W4s ----
    {
        float4v aC[2], aV[2];
        aC[0] = (float4v)(0.0f); aC[1] = (float4v)(0.0f);
        aV[0] = (float4v)(0.0f); aV[1] = (float4v)(0.0f);
        for (int kb = 0; kb < 8; ++kb) {
            short8 af = *(const short8*)(&buf0[l15 * 264 + kb * 32 + koff]);
            #pragma unroll
            for (int ni = 0; ni < 2; ++ni) {
                short8 bc = *(const short8*)(Wp4r + ((size_t)kb * 256 + n0 + ni * 16 + l15) * 32 + koff);
                short8 bv = *(const short8*)(Wp4s + ((size_t)kb * 256 + n0 + ni * 16 + l15) * 32 + koff);
                aC[ni] = __builtin_amdgcn_mfma_f32_16x16x32_bf16(af, bc, aC[ni], 0, 0, 0);
                aV[ni] = __builtin_amdgcn_mfma_f32_16x16x32_bf16(af, bv, aV[ni], 0, 0, 0);
            }
        }
        #pragma unroll
        for (int ni = 0; ni < 2; ++ni) {
            int col = n0 + ni * 16 + l15;
            float bv = b4ap[col];
            #pragma unroll
            for (int r = 0; r < 4; ++r) {
                size_t o = (size_t)(m0 + quad * 4 + r) * 256 + col;
                C4[o] = f2bf(aC[ni][r] + bv);
                Vs[o] = f2bf(aV[ni][r]);
            }
        }
    }
}

// ---------------------------------------------------------------------------
// Phase B: grid (3200,2), block 512 (8 waves x 32 cols, EVEN/ODD pairing).
// stage0: t2 -> LDS ONCE + jtab[64]. K-loop: acc[4][2] (tile0=even cols,
// tile1=odd via permuted Wpz), unroll 1. z4: per col-pair one dword Vs/C4
// load + one pk + one dword LDS store (natural order). Projection waves 0-3
// vs Wfp (unchanged). LDS 33792+256 B. (512,6): 24 waves/CU. No spill.
// ---------------------------------------------------------------------------
__global__ __launch_bounds__(512, 6) void edge_phaseB_kernel(
        const unsigned short* __restrict__ Hs, const unsigned short* __restrict__ Vs,
        const unsigned short* __restrict__ U, const unsigned short* __restrict__ C4,
        const unsigned short* __restrict__ Wpz, const unsigned short* __restrict__ Wfp,
        const float* __restrict__ bfv,
        float* __restrict__ out) {
    __shared__ __align__(16) unsigned short t2s[64 * 264]; // 33792 B (z4 aliases later)
    __shared__ int jtab[64];
    const int g = blockIdx.x, hb = blockIdx.y;
    const int b = g / 100, nr = g - b * 100;
    const int nrows = hb ? 49 : 50;
    const int k0 = hb * 50;
    const int tid  = threadIdx.x;
    const int wave = tid >> 6;          // 0..7
    const int lane = tid & 63;
    const int l15  = lane & 15;
    const int quad = lane >> 4;
    const int n0   = wave * 32;         // 32-col slice per wave
    const int koff = quad * 8;

    // ---- stage 0: build t2 tile ONCE + jtab (8 rows/wave; pad rows 0) ----
    {
        const int c = lane * 4;
        ushort4v uv = *(const ushort4v*)(U + (size_t)g * 256 + c);
        float u0 = bf2f(uv[0]), u1 = bf2f(uv[1]), u2 = bf2f(uv[2]), u3 = bf2f(uv[3]);
        for (int r = wave; r < 64; r += 8) {
            int k = k0 + r;
            int j = (r < nrows) ? (k + (k >= nr ? 1 : 0)) : 0;
            if (lane == 0) jtab[r] = b * 100 + j;
            unsigned int p01 = 0, p23 = 0;
            if (r < nrows) {
                ushort4v hv = *(const ushort4v*)(Hs + (size_t)(b * 100 + j) * 256 + c);
                float t0 = u0 + bf2f(hv[0]); t0 = t0 > 0.f ? t0 : 0.f;
                float t1 = u1 + bf2f(hv[1]); t1 = t1 > 0.f ? t1 : 0.f;
                float t2 = u2 + bf2f(hv[2]); t2 = t2 > 0.f ? t2 : 0.f;
                float t3 = u3 + bf2f(hv[3]); t3 = t3 > 0.f ? t3 : 0.f;
                p01 = f2bf_pk(t0, t1);
                p23 = f2bf_pk(t2, t3);
            }
            unsigned int* dst = (unsigned int*)(&t2s[r * 264 + c]);
            dst[0] = p01;
            dst[1] = p23;
        }
    }
    __syncthreads();

    // ---- K-loop: z4 GEMM (K=256); acc[·][0]=even cols, [1]=odd (perm Wpz) ----
    float4v acc[4][2];
    #pragma unroll
    for (int mi = 0; mi < 4; ++mi) {
        acc[mi][0] = (float4v)(0.0f);
        acc[mi][1] = (float4v)(0.0f);
    }

    #pragma unroll 1              // spill guard (R10 lesson)
    for (int kb = 0; kb < 8; ++kb) {
        short8 bf0 = *(const short8*)(Wpz + ((size_t)kb * 256 + n0 + l15) * 32 + koff);
        short8 bf1 = *(const short8*)(Wpz + ((size_t)kb * 256 + n0 + 16 + l15) * 32 + koff);
        #pragma unroll
        for (int mi = 0; mi < 4; ++mi) {
            short8 af = *(const short8*)(&t2s[(mi * 16 + l15) * 264 + kb * 32 + koff]);
            acc[mi][0] = __builtin_amdgcn_mfma_f32_16x16x32_bf16(af, bf0, acc[mi][0], 0, 0, 0);
            acc[mi][1] = __builtin_amdgcn_mfma_f32_16x16x32_bf16(af, bf1, acc[mi][1], 0, 0, 0);
        }
    }
    __syncthreads();            // all t2s A-reads done; z4 aliases t2s below

    // ---- z4 = relu(C4_i + Vs_j + acc) -> LDS (natural order, dword pairs) ----
    {
        const int cp = n0 + 2 * l15;            // even col; odd = cp+1
        unsigned int c4p = *(const unsigned int*)(C4 + (size_t)g * 256 + cp);
        float c4v0 = bf2f((unsigned short)c4p);
        float c4v1 = bf2f((unsigned short)(c4p >> 16));
        #pragma unroll
        for (int mi = 0; mi < 4; ++mi) {
            #pragma unroll
            for (int r = 0; r < 4; ++r) {
                int row = mi * 16 + quad * 4 + r;      // local edge idx (C-layout)
                int jr = jtab[row];
                unsigned int vsp = *(const unsigned int*)(Vs + (size_t)jr * 256 + cp);
                float z0 = c4v0 + bf2f((unsigned short)vsp) + acc[mi][0][r];
                float z1 = c4v1 + bf2f((unsigned short)(vsp >> 16)) + acc[mi][1][r];
                z0 = z0 > 0.f ? z0 : 0.f;
                z1 = z1 > 0.f ? z1 : 0.f;
                *(unsigned int*)(&t2s[row * 264 + cp]) = f2bf_pk(z0, z1);
            }
        }
    }
    __syncthreads();

    // ---- projection: waves 0-3, rows wave*16..+15; 8 MFMA vs Wfp ----
    if (wave < 4) {
        float4v pacc = (float4v)(0.0f);
        #pragma unroll
        for (int kb = 0; kb < 8; ++kb) {
            short8 za = *(const short8*)(&t2s[(wave * 16 + l15) * 264 + kb * 32 + koff]);
            short8 wb = *(const short8*)(Wfp + (size_t)kb * 512 + l15 * 32 + koff);
            pacc = __builtin_amdgcn_mfma_f32_16x16x32_bf16(za, wb, pacc, 0, 0, 0);
        }
        if (l15 < 4) {
            float bv = bfv[l15];
            #pragma unroll
            for (int r = 0; r < 4; ++r) {
                int row = wave * 16 + quad * 4 + r;
                if (row < nrows)
                    out[((size_t)b * 9900 + nr * 99 + k0 + row) * 4 + l15] = pacc[r] + bv;
            }
        }
    }
}

extern "C" void kernel_launch(void* const* d_in, const int* in_sizes, int n_in,
                              void* d_out, int out_size, void* d_ws, size_t ws_size,
                              hipStream_t stream) {
    const float* x   = (const float*)d_in[0];
    const float* w1a = (const float*)d_in[3];
    const float* b1a = (const float*)d_in[4];
    const float* w1b = (const float*)d_in[5];
    const float* b1b = (const float*)d_in[6];
    const float* w2a = (const float*)d_in[7];
    const float* b2a = (const float*)d_in[8];
    const float* w2b = (const float*)d_in[9];
    const float* b2b = (const float*)d_in[10];
    const float* w3a = (const float*)d_in[11];
    const float* b3a = (const float*)d_in[12];
    const float* w3b = (const float*)d_in[13];
    const float* b3b = (const float*)d_in[14];
    const float* w4a = (const float*)d_in[15];
    const float* b4a = (const float*)d_in[16];
    const float* w4b = (const float*)d_in[17];
    const float* b4b = (const float*)d_in[18];
    const float* wo  = (const float*)d_in[19];
    const float* bo  = (const float*)d_in[20];
    float* out = (float*)d_out;
    (void)in_sizes; (void)n_in; (void)out_size; (void)ws_size;

    char* ws = (char*)d_ws;
    size_t off = 0;
    auto alloc = [&](size_t bytes) {
        size_t o = off;
        off = (off + bytes + 255) & ~(size_t)255;
        return o;
    };
    const size_t SLOT_BF = (size_t)3200 * 256 * 2;   // 1.64 MB
    unsigned short* S_U  = (unsigned short*)(ws + alloc(SLOT_BF)); // U
    unsigned short* S_Hs = (unsigned short*)(ws + alloc(SLOT_BF)); // Hs
    unsigned short* S_Vs = (unsigned short*)(ws + alloc(SLOT_BF)); // Vs
    unsigned short* S_4  = (unsigned short*)(ws + alloc(SLOT_BF)); // hin -> C4
    unsigned short* Wp1a = (unsigned short*)(ws + alloc(224 * 256 * 2));
    unsigned short* Wp1b = (unsigned short*)(ws + alloc(256 * 256 * 2));
    unsigned short* Wp2r = (unsigned short*)(ws + alloc(256 * 256 * 2));
    unsigned short* Wp2s = (unsigned short*)(ws + alloc(256 * 256 * 2));
    unsigned short* Wp2b = (unsigned short*)(ws + alloc(256 * 256 * 2));
    unsigned short* Wp3a = (unsigned short*)(ws + alloc(256 * 256 * 2));
    unsigned short* Wp3b = (unsigned short*)(ws + alloc(256 * 256 * 2));
    unsigned short* Wp4r = (unsigned short*)(ws + alloc(256 * 256 * 2));
    unsigned short* Wp4s = (unsigned short*)(ws + alloc(256 * 256 * 2));
    unsigned short* Wpz  = (unsigned short*)(ws + alloc(256 * 256 * 2));
    unsigned short* Wfp  = (unsigned short*)(ws + alloc(8 * 16 * 32 * 2));
    float*          bfv  = (float*)(ws + alloc(4 * 4));
    float*          b4ap = (float*)(ws + alloc(256 * 4));
    float*          b2bs = (float*)(ws + alloc(256 * 4));
    // total ~8 MB (<= 11.2 proven safe)

    unsigned short* hin = S_4;   // [prep, nodeA]
    unsigned short* C4  = S_4;   // [nodeC, phaseB]

    // ---- 4 dispatches ----
    hipLaunchKernelGGL(prep_kernel, dim3(5330), dim3(256), 0, stream,
                       x, w1a, w1b, w2a, w2b, w3a, w3b, w4a, b4a, w4b, b4b, wo, bo, b2b,
                       Wp1a, Wp1b, Wp2r, Wp2s, Wp2b, Wp3a, Wp3b, Wp4r, Wp4s, Wpz,
                       Wfp, bfv, b4ap, b2bs, hin);
    hipLaunchKernelGGL(node_fusedA_kernel, dim3(200), dim3(512), 0, stream,
                       hin, Wp1a, b1a, Wp1b, b1b, Wp2r, b2a, Wp2s, S_U, S_Hs);
    hipLaunchKernelGGL(node_fusedC_kernel, dim3(200), dim3(512), 0, stream,
                       S_U, S_Hs, Wp2b, b2bs, Wp3a, b3a, Wp3b, b3b, Wp4r, b4ap, Wp4s, C4, S_Vs);
    hipLaunchKernelGGL(edge_phaseB_kernel, dim3(3200, 2), dim3(512), 0, stream,
                       S_Hs, S_Vs, S_U, C4, Wpz, Wfp, bfv, out);
}

// Round 17
// 249.012 us; speedup vs baseline: 1.4972x; 1.0005x over previous
//
#include <hip/hip_runtime.h>
#include <hip/hip_bf16.h>
#include <stdint.h>

// ---------------------------------------------------------------------------
// NRI-style MLP encoder. B=32, T=50, N=100, D=4, E=9900, H=256. fp32 I/O.
// R7 formulation (send terms are node GEMMs; only edge GEMM is K=256 t2@Wpz).
// R17 changes (phaseB z4 gather was latency-exposed AFTER the GEMM):
//  - prefetch all 16 Vs col-pair dwords (addresses from jtab) + C4 dword
//    BEFORE the K-loop -> latency hidden under 64 MFMAs.
//  - C4 folded into accumulator init (acc = c4 broadcast, not 0) — removes
//    32 adds; fp32 reorder ~1e-7 << threshold.
//  - z4 loop: register-only (2 shl + 2 add + 2 max + 1 pk + 1 ds_write)/pair.
//  - spill guard: (512,6) cap ~85 regs; arch ~58 + acc 32 is borderline —
//    WRITE_SIZE must stay ~5 MB (R8 signature = 100s of MB) else revert.
// Pipeline (4 dispatches): prep, nodeA, nodeC(+colsum), phaseB.
// ---------------------------------------------------------------------------

typedef __attribute__((ext_vector_type(8))) short short8;
typedef __attribute__((ext_vector_type(4))) float float4v;
typedef __attribute__((ext_vector_type(4))) unsigned short ushort4v;
typedef __attribute__((ext_vector_type(4))) unsigned int uint4v;

__device__ inline float bf2f(unsigned short u) {
    union { unsigned int i; float f; } v; v.i = ((unsigned int)u) << 16; return v.f;
}

#if __has_builtin(__builtin_amdgcn_cvt_pk_bf16_f32)
typedef __attribute__((ext_vector_type(2))) __bf16 bf16x2;
__device__ inline unsigned int f2bf_pk(float a, float b) {   // [15:0]=a [31:16]=b
    union { bf16x2 v; unsigned int u; } c;
    c.v = __builtin_amdgcn_cvt_pk_bf16_f32(a, b);
    return c.u;
}
__device__ inline unsigned short f2bf(float f) {
    return (unsigned short)(f2bf_pk(f, f) & 0xFFFFu);
}
#else
__device__ inline unsigned short f2bf(float f) {
    union { float f; unsigned int i; } v; v.f = f;
    unsigned int i = v.i;
    return (unsigned short)((i + 0x7FFFu + ((i >> 16) & 1u)) >> 16);
}
__device__ inline unsigned int f2bf_pk(float a, float b) {
    return (unsigned int)f2bf(a) | ((unsigned int)f2bf(b) << 16);
}
#endif

// ---------------------------------------------------------------------------
// MEGA-PREP: bx<2272 weight packs | <2528 Wpz=pack(w2b@w4a_e, EVEN/ODD perm)
// | <2530 misc (Wfp/bfv/b4ap/b2bs) | rest repack x.
// ---------------------------------------------------------------------------
__global__ __launch_bounds__(256) void prep_kernel(
        const float* __restrict__ x,
        const float* __restrict__ w1a, const float* __restrict__ w1b,
        const float* __restrict__ w2a, const float* __restrict__ w2b,
        const float* __restrict__ w3a, const float* __restrict__ w3b,
        const float* __restrict__ w4a, const float* __restrict__ b4a,
        const float* __restrict__ w4b, const float* __restrict__ b4b,
        const float* __restrict__ wo,  const float* __restrict__ bo,
        const float* __restrict__ b2b,
        unsigned short* __restrict__ Wp1a, unsigned short* __restrict__ Wp1b,
        unsigned short* __restrict__ Wp2r, unsigned short* __restrict__ Wp2s,
        unsigned short* __restrict__ Wp2b, unsigned short* __restrict__ Wp3a,
        unsigned short* __restrict__ Wp3b, unsigned short* __restrict__ Wp4r,
        unsigned short* __restrict__ Wp4s, unsigned short* __restrict__ Wpz,
        unsigned short* __restrict__ Wfp, float* __restrict__ bfv,
        float* __restrict__ b4ap, float* __restrict__ b2bs,
        unsigned short* __restrict__ hin) {
    int bx = blockIdx.x;
    int tid = threadIdx.x;
    if (bx < 2272) {
        const float* W; unsigned short* Wp; int Kin; int b0;
        if      (bx <  224) { W = w1a;             Wp = Wp1a; Kin = 200; b0 = 0;    }
        else if (bx <  480) { W = w1b;             Wp = Wp1b; Kin = 256; b0 = 224;  }
        else if (bx <  736) { W = w2a;             Wp = Wp2r; Kin = 256; b0 = 480;  }
        else if (bx <  992) { W = w2a + 256 * 256; Wp = Wp2s; Kin = 256; b0 = 736;  }
        else if (bx < 1248) { W = w2b;             Wp = Wp2b; Kin = 256; b0 = 992;  }
        else if (bx < 1504) { W = w3a;             Wp = Wp3a; Kin = 256; b0 = 1248; }
        else if (bx < 1760) { W = w3b;             Wp = Wp3b; Kin = 256; b0 = 1504; }
        else if (bx < 2016) { W = w4a;             Wp = Wp4r; Kin = 256; b0 = 1760; }
        else                { W = w4a + 256 * 256; Wp = Wp4s; Kin = 256; b0 = 2016; }
        int idx = (bx - b0) * 256 + tid;
        int k = idx >> 8, n = idx & 255;
        unsigned short v = (k < Kin) ? f2bf(W[k * 256 + n]) : (unsigned short)0;
        Wp[((size_t)(k >> 5) * 256 + n) * 32 + (k & 31)] = v;
    } else if (bx < 2528) {
        int k = bx - 2272, c = tid;           // c = PHYSICAL output col
        float s = 0.f;
        for (int t = 0; t < 256; ++t)
            s += w2b[k * 256 + t] * w4a[(size_t)(512 + t) * 256 + c];
        // even/odd pairing: packed pos n = w*32 + (c&1)*16 + ((c&31)>>1)
        int n = (c & ~31) + (c & 1) * 16 + ((c & 31) >> 1);
        Wpz[((size_t)(k >> 5) * 256 + n) * 32 + (k & 31)] = f2bf(s);
    } else if (bx < 2530) {
        int k = tid;
        if (bx == 2528) {
            float a[4] = {0.f, 0.f, 0.f, 0.f};
            for (int c = 0; c < 256; ++c) {
                float wv = w4b[k * 256 + c];
                #pragma unroll
                for (int o = 0; o < 4; ++o) a[o] += wv * wo[c * 4 + o];
            }
            #pragma unroll
            for (int n = 0; n < 16; ++n)
                Wfp[(size_t)(k >> 5) * 512 + n * 32 + (k & 31)] =
                    (n < 4) ? f2bf(a[n]) : (unsigned short)0;
            if (k < 4) {
                float s = bo[k];
                for (int c = 0; c < 256; ++c) s += b4b[c] * wo[c * 4 + k];
                bfv[k] = s;
            }
        } else {
            float s = b4a[k];
            for (int t = 0; t < 256; ++t)
                s += b2b[t] * w4a[(size_t)(512 + t) * 256 + k];
            b4ap[k] = s;
            b2bs[k] = 0.99f * b2b[k];
        }
    } else {
        int idx = (bx - 2530) * 256 + tid;
        if (idx < 3200 * 224) {
            int row = idx / 224;
            int c = idx - row * 224;
            int b = row / 100, n = row - b * 100;
            unsigned short v = 0;
            if (c < 200) {
                int t = c >> 2, d = c & 3;
                v = f2bf(x[(((size_t)(b * 50 + t)) * 100 + n) * 4 + d]);
            }
            hin[(size_t)row * 224 + c] = v;
        }
    }
}

// ---------------------------------------------------------------------------
// nodeA (fused, 512 thr = 8 waves x 32 cols): rows m0=bx*16.
// t1=relu(hin@W1a+b1a) [LDS] -> h=t1@W1b+b1b [LDS] -> U,Hs (dual, global).
// ---------------------------------------------------------------------------
__global__ __launch_bounds__(512) void node_fusedA_kernel(
        const unsigned short* __restrict__ hin,
        const unsigned short* __restrict__ Wp1a, const float* __restrict__ b1a,
        const unsigned short* __restrict__ Wp1b, const float* __restrict__ b1b,
        const unsigned short* __restrict__ Wp2r, const float* __restrict__ b2a,
        const unsigned short* __restrict__ Wp2s,
        unsigned short* __restrict__ U, unsigned short* __restrict__ Hs) {
    __shared__ __align__(16) unsigned short t1s[16 * 264];
    __shared__ __align__(16) unsigned short hs2[16 * 264];
    const int m0 = blockIdx.x * 16;
    const int tid  = threadIdx.x;
    const int wave = tid >> 6;          // 0..7
    const int lane = tid & 63;
    const int l15  = lane & 15;
    const int quad = lane >> 4;
    const int n0   = wave * 32;
    const int koff = quad * 8;

    // ---- S1: t1 = relu(hin@W1a + b1a), K=224 ----
    {
        float4v acc[2];
        acc[0] = (float4v)(0.0f); acc[1] = (float4v)(0.0f);
        for (int kb = 0; kb < 7; ++kb) {
            short8 af = *(const short8*)(hin + (size_t)(m0 + l15) * 224 + kb * 32 + koff);
            #pragma unroll
            for (int ni = 0; ni < 2; ++ni) {
                short8 bf = *(const short8*)(Wp1a + ((size_t)kb * 256 + n0 + ni * 16 + l15) * 32 + koff);
                acc[ni] = __builtin_amdgcn_mfma_f32_16x16x32_bf16(af, bf, acc[ni], 0, 0, 0);
            }
        }
        #pragma unroll
        for (int ni = 0; ni < 2; ++ni) {
            int col = n0 + ni * 16 + l15;
            float bv = b1a[col];
            #pragma unroll
            for (int r = 0; r < 4; ++r) {
                float v = acc[ni][r] + bv;
                v = v > 0.f ? v : 0.f;
                t1s[(quad * 4 + r) * 264 + col] = f2bf(v);
            }
        }
    }
    __syncthreads();

    // ---- S2: h = t1@W1b + b1b ----
    {
        float4v acc[2];
        acc[0] = (float4v)(0.0f); acc[1] = (float4v)(0.0f);
        for (int kb = 0; kb < 8; ++kb) {
            short8 af = *(const short8*)(&t1s[l15 * 264 + kb * 32 + koff]);
            #pragma unroll
            for (int ni = 0; ni < 2; ++ni) {
                short8 bf = *(const short8*)(Wp1b + ((size_t)kb * 256 + n0 + ni * 16 + l15) * 32 + koff);
                acc[ni] = __builtin_amdgcn_mfma_f32_16x16x32_bf16(af, bf, acc[ni], 0, 0, 0);
            }
        }
        #pragma unroll
        for (int ni = 0; ni < 2; ++ni) {
            int col = n0 + ni * 16 + l15;
            float bv = b1b[col];
            #pragma unroll
            for (int r = 0; r < 4; ++r)
                hs2[(quad * 4 + r) * 264 + col] = f2bf(acc[ni][r] + bv);
        }
    }
    __syncthreads();

    // ---- S3 (dual): U = h@W2r + b2a ; Hs = h@W2s ----
    {
        float4v aU[2], aH[2];
        aU[0] = (float4v)(0.0f); aU[1] = (float4v)(0.0f);
        aH[0] = (float4v)(0.0f); aH[1] = (float4v)(0.0f);
        for (int kb = 0; kb < 8; ++kb) {
            short8 af = *(const short8*)(&hs2[l15 * 264 + kb * 32 + koff]);
            #pragma unroll
            for (int ni = 0; ni < 2; ++ni) {
                short8 bu = *(const short8*)(Wp2r + ((size_t)kb * 256 + n0 + ni * 16 + l15) * 32 + koff);
                short8 bh = *(const short8*)(Wp2s + ((size_t)kb * 256 + n0 + ni * 16 + l15) * 32 + koff);
                aU[ni] = __builtin_amdgcn_mfma_f32_16x16x32_bf16(af, bu, aU[ni], 0, 0, 0);
                aH[ni] = __builtin_amdgcn_mfma_f32_16x16x32_bf16(af, bh, aH[ni], 0, 0, 0);
            }
        }
        #pragma unroll
        for (int ni = 0; ni < 2; ++ni) {
            int col = n0 + ni * 16 + l15;
            float bv = b2a[col];
            #pragma unroll
            for (int r = 0; r < 4; ++r) {
                size_t o = (size_t)(m0 + quad * 4 + r) * 256 + col;
                U[o]  = f2bf(aU[ni][r] + bv);
                Hs[o] = f2bf(aH[ni][r]);
            }
        }
    }
}

// ---------------------------------------------------------------------------
// nodeC (fused + colsum S0, 512 thr): rows m0=bx*16.
// S0: Ssc -> buf1 [LDS]; S1: vin -> buf0; S2: t3 -> buf1; S3: v2 -> buf0;
// S4 (dual): C4, Vs -> global.
// ---------------------------------------------------------------------------
__global__ __launch_bounds__(512) void node_fusedC_kernel(
        const unsigned short* __restrict__ U, const unsigned short* __restrict__ Hs,
        const unsigned short* __restrict__ Wp2b, const float* __restrict__ b2bs,
        const unsigned short* __restrict__ Wp3a, const float* __restrict__ b3a,
        const unsigned short* __restrict__ Wp3b, const float* __restrict__ b3b,
        const unsigned short* __restrict__ Wp4r, const float* __restrict__ b4ap,
        const unsigned short* __restrict__ Wp4s,
        unsigned short* __restrict__ C4, unsigned short* __restrict__ Vs) {
    __shared__ __align__(16) unsigned short buf0[16 * 264];
    __shared__ __align__(16) unsigned short buf1[16 * 264];
    const int m0 = blockIdx.x * 16;
    const int tid  = threadIdx.x;
    const int wave = tid >> 6;
    const int lane = tid & 63;
    const int l15  = lane & 15;
    const int quad = lane >> 4;
    const int n0   = wave * 32;
    const int koff = quad * 8;

    // ---- S0: colsum -> buf1 (Ssc rows local 0..15) ----
    {
        const int rl = tid >> 5;           // group 0..15
        const int ct = (tid & 31) * 8;     // 8 cols
        const int g = m0 + rl;
        const int b = g / 100, i = g - b * 100;
        float u[8], s[8];
        {
            ushort4v u0 = *(const ushort4v*)(U + (size_t)g * 256 + ct);
            ushort4v u1 = *(const ushort4v*)(U + (size_t)g * 256 + ct + 4);
            #pragma unroll
            for (int e = 0; e < 4; ++e) { u[e] = bf2f(u0[e]); u[4 + e] = bf2f(u1[e]); }
            #pragma unroll
            for (int e = 0; e < 8; ++e) s[e] = 0.f;
        }
        const unsigned short* base = Hs + (size_t)b * 100 * 256 + ct;
        #pragma unroll 4
        for (int j = 0; j < 100; ++j) {
            ushort4v h0 = *(const ushort4v*)(base + (size_t)j * 256);
            ushort4v h1 = *(const ushort4v*)(base + (size_t)j * 256 + 4);
            #pragma unroll
            for (int e = 0; e < 4; ++e) {
                float v0 = u[e] + bf2f(h0[e]);     s[e]     += (v0 > 0.f ? v0 : 0.f);
                float v1 = u[4 + e] + bf2f(h1[e]); s[4 + e] += (v1 > 0.f ? v1 : 0.f);
            }
        }
        {
            ushort4v h0 = *(const ushort4v*)(base + (size_t)i * 256);
            ushort4v h1 = *(const ushort4v*)(base + (size_t)i * 256 + 4);
            #pragma unroll
            for (int e = 0; e < 4; ++e) {
                float v0 = u[e] + bf2f(h0[e]);     s[e]     -= (v0 > 0.f ? v0 : 0.f);
                float v1 = u[4 + e] + bf2f(h1[e]); s[4 + e] -= (v1 > 0.f ? v1 : 0.f);
            }
        }
        uint4v d;
        d[0] = f2bf_pk(s[0] * 0.01f, s[1] * 0.01f);
        d[1] = f2bf_pk(s[2] * 0.01f, s[3] * 0.01f);
        d[2] = f2bf_pk(s[4] * 0.01f, s[5] * 0.01f);
        d[3] = f2bf_pk(s[6] * 0.01f, s[7] * 0.01f);
        *(uint4v*)(&buf1[rl * 264 + ct]) = d;
    }
    __syncthreads();

    // ---- S1: vin = Ssc@W2b + b2bs -> buf0 ----
    {
        float4v acc[2];
        acc[0] = (float4v)(0.0f); acc[1] = (float4v)(0.0f);
        for (int kb = 0; kb < 8; ++kb) {
            short8 af = *(const short8*)(&buf1[l15 * 264 + kb * 32 + koff]);
            #pragma unroll
            for (int ni = 0; ni < 2; ++ni) {
                short8 bf = *(const short8*)(Wp2b + ((size_t)kb * 256 + n0 + ni * 16 + l15) * 32 + koff);
                acc[ni] = __builtin_amdgcn_mfma_f32_16x16x32_bf16(af, bf, acc[ni], 0, 0, 0);
            }
        }
        #pragma unroll
        for (int ni = 0; ni < 2; ++ni) {
            int col = n0 + ni * 16 + l15;
            float bv = b2bs[col];
            #pragma unroll
            for (int r = 0; r < 4; ++r)
                buf0[(quad * 4 + r) * 264 + col] = f2bf(acc[ni][r] + bv);
        }
    }
    __syncthreads();

    // ---- S2: t3 = relu(vin@W3a + b3a) -> buf1 ----
    {
        float4v acc[2];
        acc[0] = (float4v)(0.0f); acc[1] = (float4v)(0.0f);
        for (int kb = 0; kb < 8; ++kb) {
            short8 af = *(const short8*)(&buf0[l15 * 264 + kb * 32 + koff]);
            #pragma unroll
            for (int ni = 0; ni < 2; ++ni) {
                short8 bf = *(const short8*)(Wp3a + ((size_t)kb * 256 + n0 + ni * 16 + l15) * 32 + koff);
                acc[ni] = __builtin_amdgcn_mfma_f32_16x16x32_bf16(af, bf, acc[ni], 0, 0, 0);
            }
        }
        __syncthreads();   // buf1's S1 readers done; safe rewrite
        #pragma unroll
        for (int ni = 0; ni < 2; ++ni) {
            int col = n0 + ni * 16 + l15;
            float bv = b3a[col];
            #pragma unroll
            for (int r = 0; r < 4; ++r) {
                float v = acc[ni][r] + bv;
                v = v > 0.f ? v : 0.f;
                buf1[(quad * 4 + r) * 264 + col] = f2bf(v);
            }
        }
    }
    __syncthreads();

    // ---- S3: v2 = t3@W3b + b3b -> buf0 ----
    {
        float4v acc[2];
        acc[0] = (float4v)(0.0f); acc[1] = (float4v)(0.0f);
        for (int kb = 0; kb < 8; ++kb) {
            short8 af = *(const short8*)(&buf1[l15 * 264 + kb * 32 + koff]);
            #pragma unroll
            for (int ni = 0; ni < 2; ++ni) {
                short8 bf = *(const short8*)(Wp3b + ((size_t)kb * 256 + n0 + ni * 16 + l15) * 32 + koff);
                acc[ni] = __builtin_amdgcn_mfma_f32_16x16x32_bf16(af, bf, acc[ni], 0, 0, 0);
            }
        }
        __syncthreads();   // buf0's S2 readers done; safe rewrite
        #pragma unroll
        for (int ni = 0; ni < 2; ++ni) {
            int col = n0 + ni * 16 + l15;
            float bv = b3b[col];
            #pragma unroll
            for (int r = 0; r < 4; ++r)
                buf0[(quad * 4 + r) * 264 + col] = f2bf(acc[ni][r] + bv);
        }
    }
    __syncthreads();

    // ---- S4 (dual): C4 = v2@W4r + b4ap ; Vs = v2@W4s ----
    {
        float4v aC[2], aV[2];
        aC[0] = (float4v)(0.0f); aC[1] = (float4v)(0.0f);
        aV[0] = (float4v)(0.0f); aV[1] = (float4v)(0.0f);
        for (int kb = 0; kb < 8; ++kb) {
            short8 af = *(const short8*)(&buf0[l15 * 264 + kb * 32 + koff]);
            #pragma unroll
            for (int ni = 0; ni < 2; ++ni) {
                short8 bc = *(const short8*)(Wp4r + ((size_t)kb * 256 + n0 + ni * 16 + l15) * 32 + koff);
                short8 bv = *(const short8*)(Wp4s + ((size_t)kb * 256 + n0 + ni * 16 + l15) * 32 + koff);
                aC[ni] = __builtin_amdgcn_mfma_f32_16x16x32_bf16(af, bc, aC[ni], 0, 0, 0);
                aV[ni] = __builtin_amdgcn_mfma_f32_16x16x32_bf16(af, bv, aV[ni], 0, 0, 0);
            }
        }
        #pragma unroll
        for (int ni = 0; ni < 2; ++ni) {
            int col = n0 + ni * 16 + l15;
            float bv = b4ap[col];
            #pragma unroll
            for (int r = 0; r < 4; ++r) {
                size_t o = (size_t)(m0 + quad * 4 + r) * 256 + col;
                C4[o] = f2bf(aC[ni][r] + bv);
                Vs[o] = f2bf(aV[ni][r]);
            }
        }
    }
}

// ---------------------------------------------------------------------------
// Phase B: grid (3200,2), block 512 (8 waves x 32 cols, EVEN/ODD pairing).
// stage0: t2 -> LDS ONCE + jtab[64]. Then PREFETCH 16 Vs dwords + C4 dword
// (latency hidden under K-loop). acc INIT = C4 broadcast. K-loop: acc[4][2]
// vs permuted Wpz, unroll 1. z4: register-only per col-pair. Projection
// waves 0-3 vs Wfp. LDS 33792+256 B. (512,6). Spill guard: WRITE ~5MB.
// ---------------------------------------------------------------------------
__global__ __launch_bounds__(512, 6) void edge_phaseB_kernel(
        const unsigned short* __restrict__ Hs, const unsigned short* __restrict__ Vs,
        const unsigned short* __restrict__ U, const unsigned short* __restrict__ C4,
        const unsigned short* __restrict__ Wpz, const unsigned short* __restrict__ Wfp,
        const float* __restrict__ bfv,
        float* __restrict__ out) {
    __shared__ __align__(16) unsigned short t2s[64 * 264]; // 33792 B (z4 aliases later)
    __shared__ int jtab[64];
    const int g = blockIdx.x, hb = blockIdx.y;
    const int b = g / 100, nr = g - b * 100;
    const int nrows = hb ? 49 : 50;
    const int k0 = hb * 50;
    const int tid  = threadIdx.x;
    const int wave = tid >> 6;          // 0..7
    const int lane = tid & 63;
    const int l15  = lane & 15;
    const int quad = lane >> 4;
    const int n0   = wave * 32;         // 32-col slice per wave
    const int koff = quad * 8;

    // ---- stage 0: build t2 tile ONCE + jtab (8 rows/wave; pad rows 0) ----
    {
        const int c = lane * 4;
        ushort4v uv = *(const ushort4v*)(U + (size_t)g * 256 + c);
        float u0 = bf2f(uv[0]), u1 = bf2f(uv[1]), u2 = bf2f(uv[2]), u3 = bf2f(uv[3]);
        for (int r = wave; r < 64; r += 8) {
            int k = k0 + r;
            int j = (r < nrows) ? (k + (k >= nr ? 1 : 0)) : 0;
            if (lane == 0) jtab[r] = b * 100 + j;
            unsigned int p01 = 0, p23 = 0;
            if (r < nrows) {
                ushort4v hv = *(const ushort4v*)(Hs + (size_t)(b * 100 + j) * 256 + c);
                float t0 = u0 + bf2f(hv[0]); t0 = t0 > 0.f ? t0 : 0.f;
                float t1 = u1 + bf2f(hv[1]); t1 = t1 > 0.f ? t1 : 0.f;
                float t2 = u2 + bf2f(hv[2]); t2 = t2 > 0.f ? t2 : 0.f;
                float t3 = u3 + bf2f(hv[3]); t3 = t3 > 0.f ? t3 : 0.f;
                p01 = f2bf_pk(t0, t1);
                p23 = f2bf_pk(t2, t3);
            }
            unsigned int* dst = (unsigned int*)(&t2s[r * 264 + c]);
            dst[0] = p01;
            dst[1] = p23;
        }
    }
    __syncthreads();

    // ---- prefetch: Vs col-pair dwords for this thread's 16 rows + C4 ----
    const int cp = n0 + 2 * l15;            // even col; odd = cp+1
    unsigned int c4p = *(const unsigned int*)(C4 + (size_t)g * 256 + cp);
    unsigned int vsp[16];
    #pragma unroll
    for (int mi = 0; mi < 4; ++mi)
        #pragma unroll
        for (int r = 0; r < 4; ++r)
            vsp[mi * 4 + r] = *(const unsigned int*)(Vs + (size_t)jtab[mi * 16 + quad * 4 + r] * 256 + cp);

    // ---- K-loop: z4 GEMM (K=256); acc init = C4 broadcast ----
    float c4v0 = bf2f((unsigned short)c4p);
    float c4v1 = bf2f((unsigned short)(c4p >> 16));
    float4v acc[4][2];
    #pragma unroll
    for (int mi = 0; mi < 4; ++mi) {
        acc[mi][0] = (float4v)(c4v0);
        acc[mi][1] = (float4v)(c4v1);
    }

    #pragma unroll 1              // spill guard (R10 lesson)
    for (int kb = 0; kb < 8; ++kb) {
        short8 bf0 = *(const short8*)(Wpz + ((size_t)kb * 256 + n0 + l15) * 32 + koff);
        short8 bf1 = *(const short8*)(Wpz + ((size_t)kb * 256 + n0 + 16 + l15) * 32 + koff);
        #pragma unroll
        for (int mi = 0; mi < 4; ++mi) {
            short8 af = *(const short8*)(&t2s[(mi * 16 + l15) * 264 + kb * 32 + koff]);
            acc[mi][0] = __builtin_amdgcn_mfma_f32_16x16x32_bf16(af, bf0, acc[mi][0], 0, 0, 0);
            acc[mi][1] = __builtin_amdgcn_mfma_f32_16x16x32_bf16(af, bf1, acc[mi][1], 0, 0, 0);
        }
    }
    __syncthreads();            // all t2s A-reads done; z4 aliases t2s below

    // ---- z4 = relu(Vs_j + acc) -> LDS (natural order, register-only) ----
    #pragma unroll
    for (int mi = 0; mi < 4; ++mi) {
        #pragma unroll
        for (int r = 0; r < 4; ++r) {
            int row = mi * 16 + quad * 4 + r;      // local edge idx (C-layout)
            unsigned int vp = vsp[mi * 4 + r];
            float z0 = bf2f((unsigned short)vp) + acc[mi][0][r];
            float z1 = bf2f((unsigned short)(vp >> 16)) + acc[mi][1][r];
            z0 = z0 > 0.f ? z0 : 0.f;
            z1 = z1 > 0.f ? z1 : 0.f;
            *(unsigned int*)(&t2s[row * 264 + cp]) = f2bf_pk(z0, z1);
        }
    }
    __syncthreads();

    // ---- projection: waves 0-3, rows wave*16..+15; 8 MFMA vs Wfp ----
    if (wave < 4) {
        float4v pacc = (float4v)(0.0f);
        #pragma unroll
        for (int kb = 0; kb < 8; ++kb) {
            short8 za = *(const short8*)(&t2s[(wave * 16 + l15) * 264 + kb * 32 + koff]);
            short8 wb = *(const short8*)(Wfp + (size_t)kb * 512 + l15 * 32 + koff);
            pacc = __builtin_amdgcn_mfma_f32_16x16x32_bf16(za, wb, pacc, 0, 0, 0);
        }
        if (l15 < 4) {
            float bv = bfv[l15];
            #pragma unroll
            for (int r = 0; r < 4; ++r) {
                int row = wave * 16 + quad * 4 + r;
                if (row < nrows)
                    out[((size_t)b * 9900 + nr * 99 + k0 + row) * 4 + l15] = pacc[r] + bv;
            }
        }
    }
}

extern "C" void kernel_launch(void* const* d_in, const int* in_sizes, int n_in,
                              void* d_out, int out_size, void* d_ws, size_t ws_size,
                              hipStream_t stream) {
    const float* x   = (const float*)d_in[0];
    const float* w1a = (const float*)d_in[3];
    const float* b1a = (const float*)d_in[4];
    const float* w1b = (const float*)d_in[5];
    const float* b1b = (const float*)d_in[6];
    const float* w2a = (const float*)d_in[7];
    const float* b2a = (const float*)d_in[8];
    const float* w2b = (const float*)d_in[9];
    const float* b2b = (const float*)d_in[10];
    const float* w3a = (const float*)d_in[11];
    const float* b3a = (const float*)d_in[12];
    const float* w3b = (const float*)d_in[13];
    const float* b3b = (const float*)d_in[14];
    const float* w4a = (const float*)d_in[15];
    const float* b4a = (const float*)d_in[16];
    const float* w4b = (const float*)d_in[17];
    const float* b4b = (const float*)d_in[18];
    const float* wo  = (const float*)d_in[19];
    const float* bo  = (const float*)d_in[20];
    float* out = (float*)d_out;
    (void)in_sizes; (void)n_in; (void)out_size; (void)ws_size;

    char* ws = (char*)d_ws;
    size_t off = 0;
    auto alloc = [&](size_t bytes) {
        size_t o = off;
        off = (off + bytes + 255) & ~(size_t)255;
        return o;
    };
    const size_t SLOT_BF = (size_t)3200 * 256 * 2;   // 1.64 MB
    unsigned short* S_U  = (unsigned short*)(ws + alloc(SLOT_BF)); // U
    unsigned short* S_Hs = (unsigned short*)(ws + alloc(SLOT_BF)); // Hs
    unsigned short* S_Vs = (unsigned short*)(ws + alloc(SLOT_BF)); // Vs
    unsigned short* S_4  = (unsigned short*)(ws + alloc(SLOT_BF)); // hin -> C4
    unsigned short* Wp1a = (unsigned short*)(ws + alloc(224 * 256 * 2));
    unsigned short* Wp1b = (unsigned short*)(ws + alloc(256 * 256 * 2));
    unsigned short* Wp2r = (unsigned short*)(ws + alloc(256 * 256 * 2));
    unsigned short* Wp2s = (unsigned short*)(ws + alloc(256 * 256 * 2));
    unsigned short* Wp2b = (unsigned short*)(ws + alloc(256 * 256 * 2));
    unsigned short* Wp3a = (unsigned short*)(ws + alloc(256 * 256 * 2));
    unsigned short* Wp3b = (unsigned short*)(ws + alloc(256 * 256 * 2));
    unsigned short* Wp4r = (unsigned short*)(ws + alloc(256 * 256 * 2));
    unsigned short* Wp4s = (unsigned short*)(ws + alloc(256 * 256 * 2));
    unsigned short* Wpz  = (unsigned short*)(ws + alloc(256 * 256 * 2));
    unsigned short* Wfp  = (unsigned short*)(ws + alloc(8 * 16 * 32 * 2));
    float*          bfv  = (float*)(ws + alloc(4 * 4));
    float*          b4ap = (float*)(ws + alloc(256 * 4));
    float*          b2bs = (float*)(ws + alloc(256 * 4));
    // total ~8 MB (<= 11.2 proven safe)

    unsigned short* hin = S_4;   // [prep, nodeA]
    unsigned short* C4  = S_4;   // [nodeC, phaseB]

    // ---- 4 dispatches ----
    hipLaunchKernelGGL(prep_kernel, dim3(5330), dim3(256), 0, stream,
                       x, w1a, w1b, w2a, w2b, w3a, w3b, w4a, b4a, w4b, b4b, wo, bo, b2b,
                       Wp1a, Wp1b, Wp2r, Wp2s, Wp2b, Wp3a, Wp3b, Wp4r, Wp4s, Wpz,
                       Wfp, bfv, b4ap, b2bs, hin);
    hipLaunchKernelGGL(node_fusedA_kernel, dim3(200), dim3(512), 0, stream,
                       hin, Wp1a, b1a, Wp1b, b1b, Wp2r, b2a, Wp2s, S_U, S_Hs);
    hipLaunchKernelGGL(node_fusedC_kernel, dim3(200), dim3(512), 0, stream,
                       S_U, S_Hs, Wp2b, b2bs, Wp3a, b3a, Wp3b, b3b, Wp4r, b4ap, Wp4s, C4, S_Vs);
    hipLaunchKernelGGL(edge_phaseB_kernel, dim3(3200, 2), dim3(512), 0, stream,
                       S_Hs, S_Vs, S_U, C4, Wpz, Wfp, bfv, out);
}

// Round 18
// 248.963 us; speedup vs baseline: 1.4975x; 1.0002x over previous
//
#include <hip/hip_runtime.h>
#include <hip/hip_bf16.h>
#include <stdint.h>

// ---------------------------------------------------------------------------
// NRI-style MLP encoder. B=32, T=50, N=100, D=4, E=9900, H=256. fp32 I/O.
// R7 formulation (send terms are node GEMMs; only edge GEMM is K=256 t2@Wpz).
// R18 = R17 + K-loop unroll 2 (VALU-issue bound at 60%: unroll-1 recomputed
// all 12 operand addresses per kb; acc is now only 32 regs so 2-iter live
// window ~76-80 fits the (512,6) ~85-reg cap — R10's spill was with 64-AGPR
// acc + 32 hoisted reads). Spill guard: WRITE_SIZE must stay ~5 MB.
// nodeC colsum j-loop unroll 4->5 (100 % 5 == 0).
// Pipeline (4 dispatches): prep, nodeA, nodeC(+colsum), phaseB.
// ---------------------------------------------------------------------------

typedef __attribute__((ext_vector_type(8))) short short8;
typedef __attribute__((ext_vector_type(4))) float float4v;
typedef __attribute__((ext_vector_type(4))) unsigned short ushort4v;
typedef __attribute__((ext_vector_type(4))) unsigned int uint4v;

__device__ inline float bf2f(unsigned short u) {
    union { unsigned int i; float f; } v; v.i = ((unsigned int)u) << 16; return v.f;
}

#if __has_builtin(__builtin_amdgcn_cvt_pk_bf16_f32)
typedef __attribute__((ext_vector_type(2))) __bf16 bf16x2;
__device__ inline unsigned int f2bf_pk(float a, float b) {   // [15:0]=a [31:16]=b
    union { bf16x2 v; unsigned int u; } c;
    c.v = __builtin_amdgcn_cvt_pk_bf16_f32(a, b);
    return c.u;
}
__device__ inline unsigned short f2bf(float f) {
    return (unsigned short)(f2bf_pk(f, f) & 0xFFFFu);
}
#else
__device__ inline unsigned short f2bf(float f) {
    union { float f; unsigned int i; } v; v.f = f;
    unsigned int i = v.i;
    return (unsigned short)((i + 0x7FFFu + ((i >> 16) & 1u)) >> 16);
}
__device__ inline unsigned int f2bf_pk(float a, float b) {
    return (unsigned int)f2bf(a) | ((unsigned int)f2bf(b) << 16);
}
#endif

// ---------------------------------------------------------------------------
// MEGA-PREP: bx<2272 weight packs | <2528 Wpz=pack(w2b@w4a_e, EVEN/ODD perm)
// | <2530 misc (Wfp/bfv/b4ap/b2bs) | rest repack x.
// ---------------------------------------------------------------------------
__global__ __launch_bounds__(256) void prep_kernel(
        const float* __restrict__ x,
        const float* __restrict__ w1a, const float* __restrict__ w1b,
        const float* __restrict__ w2a, const float* __restrict__ w2b,
        const float* __restrict__ w3a, const float* __restrict__ w3b,
        const float* __restrict__ w4a, const float* __restrict__ b4a,
        const float* __restrict__ w4b, const float* __restrict__ b4b,
        const float* __restrict__ wo,  const float* __restrict__ bo,
        const float* __restrict__ b2b,
        unsigned short* __restrict__ Wp1a, unsigned short* __restrict__ Wp1b,
        unsigned short* __restrict__ Wp2r, unsigned short* __restrict__ Wp2s,
        unsigned short* __restrict__ Wp2b, unsigned short* __restrict__ Wp3a,
        unsigned short* __restrict__ Wp3b, unsigned short* __restrict__ Wp4r,
        unsigned short* __restrict__ Wp4s, unsigned short* __restrict__ Wpz,
        unsigned short* __restrict__ Wfp, float* __restrict__ bfv,
        float* __restrict__ b4ap, float* __restrict__ b2bs,
        unsigned short* __restrict__ hin) {
    int bx = blockIdx.x;
    int tid = threadIdx.x;
    if (bx < 2272) {
        const float* W; unsigned short* Wp; int Kin; int b0;
        if      (bx <  224) { W = w1a;             Wp = Wp1a; Kin = 200; b0 = 0;    }
        else if (bx <  480) { W = w1b;             Wp = Wp1b; Kin = 256; b0 = 224;  }
        else if (bx <  736) { W = w2a;             Wp = Wp2r; Kin = 256; b0 = 480;  }
        else if (bx <  992) { W = w2a + 256 * 256; Wp = Wp2s; Kin = 256; b0 = 736;  }
        else if (bx < 1248) { W = w2b;             Wp = Wp2b; Kin = 256; b0 = 992;  }
        else if (bx < 1504) { W = w3a;             Wp = Wp3a; Kin = 256; b0 = 1248; }
        else if (bx < 1760) { W = w3b;             Wp = Wp3b; Kin = 256; b0 = 1504; }
        else if (bx < 2016) { W = w4a;             Wp = Wp4r; Kin = 256; b0 = 1760; }
        else                { W = w4a + 256 * 256; Wp = Wp4s; Kin = 256; b0 = 2016; }
        int idx = (bx - b0) * 256 + tid;
        int k = idx >> 8, n = idx & 255;
        unsigned short v = (k < Kin) ? f2bf(W[k * 256 + n]) : (unsigned short)0;
        Wp[((size_t)(k >> 5) * 256 + n) * 32 + (k & 31)] = v;
    } else if (bx < 2528) {
        int k = bx - 2272, c = tid;           // c = PHYSICAL output col
        float s = 0.f;
        for (int t = 0; t < 256; ++t)
            s += w2b[k * 256 + t] * w4a[(size_t)(512 + t) * 256 + c];
        // even/odd pairing: packed pos n = w*32 + (c&1)*16 + ((c&31)>>1)
        int n = (c & ~31) + (c & 1) * 16 + ((c & 31) >> 1);
        Wpz[((size_t)(k >> 5) * 256 + n) * 32 + (k & 31)] = f2bf(s);
    } else if (bx < 2530) {
        int k = tid;
        if (bx == 2528) {
            float a[4] = {0.f, 0.f, 0.f, 0.f};
            for (int c = 0; c < 256; ++c) {
                float wv = w4b[k * 256 + c];
                #pragma unroll
                for (int o = 0; o < 4; ++o) a[o] += wv * wo[c * 4 + o];
            }
            #pragma unroll
            for (int n = 0; n < 16; ++n)
                Wfp[(size_t)(k >> 5) * 512 + n * 32 + (k & 31)] =
                    (n < 4) ? f2bf(a[n]) : (unsigned short)0;
            if (k < 4) {
                float s = bo[k];
                for (int c = 0; c < 256; ++c) s += b4b[c] * wo[c * 4 + k];
                bfv[k] = s;
            }
        } else {
            float s = b4a[k];
            for (int t = 0; t < 256; ++t)
                s += b2b[t] * w4a[(size_t)(512 + t) * 256 + k];
            b4ap[k] = s;
            b2bs[k] = 0.99f * b2b[k];
        }
    } else {
        int idx = (bx - 2530) * 256 + tid;
        if (idx < 3200 * 224) {
            int row = idx / 224;
            int c = idx - row * 224;
            int b = row / 100, n = row - b * 100;
            unsigned short v = 0;
            if (c < 200) {
                int t = c >> 2, d = c & 3;
                v = f2bf(x[(((size_t)(b * 50 + t)) * 100 + n) * 4 + d]);
            }
            hin[(size_t)row * 224 + c] = v;
        }
    }
}

// ---------------------------------------------------------------------------
// nodeA (fused, 512 thr = 8 waves x 32 cols): rows m0=bx*16.
// t1=relu(hin@W1a+b1a) [LDS] -> h=t1@W1b+b1b [LDS] -> U,Hs (dual, global).
// ---------------------------------------------------------------------------
__global__ __launch_bounds__(512) void node_fusedA_kernel(
        const unsigned short* __restrict__ hin,
        const unsigned short* __restrict__ Wp1a, const float* __restrict__ b1a,
        const unsigned short* __restrict__ Wp1b, const float* __restrict__ b1b,
        const unsigned short* __restrict__ Wp2r, const float* __restrict__ b2a,
        const unsigned short* __restrict__ Wp2s,
        unsigned short* __restrict__ U, unsigned short* __restrict__ Hs) {
    __shared__ __align__(16) unsigned short t1s[16 * 264];
    __shared__ __align__(16) unsigned short hs2[16 * 264];
    const int m0 = blockIdx.x * 16;
    const int tid  = threadIdx.x;
    const int wave = tid >> 6;          // 0..7
    const int lane = tid & 63;
    const int l15  = lane & 15;
    const int quad = lane >> 4;
    const int n0   = wave * 32;
    const int koff = quad * 8;

    // ---- S1: t1 = relu(hin@W1a + b1a), K=224 ----
    {
        float4v acc[2];
        acc[0] = (float4v)(0.0f); acc[1] = (float4v)(0.0f);
        for (int kb = 0; kb < 7; ++kb) {
            short8 af = *(const short8*)(hin + (size_t)(m0 + l15) * 224 + kb * 32 + koff);
            #pragma unroll
            for (int ni = 0; ni < 2; ++ni) {
                short8 bf = *(const short8*)(Wp1a + ((size_t)kb * 256 + n0 + ni * 16 + l15) * 32 + koff);
                acc[ni] = __builtin_amdgcn_mfma_f32_16x16x32_bf16(af, bf, acc[ni], 0, 0, 0);
            }
        }
        #pragma unroll
        for (int ni = 0; ni < 2; ++ni) {
            int col = n0 + ni * 16 + l15;
            float bv = b1a[col];
            #pragma unroll
            for (int r = 0; r < 4; ++r) {
                float v = acc[ni][r] + bv;
                v = v > 0.f ? v : 0.f;
                t1s[(quad * 4 + r) * 264 + col] = f2bf(v);
            }
        }
    }
    __syncthreads();

    // ---- S2: h = t1@W1b + b1b ----
    {
        float4v acc[2];
        acc[0] = (float4v)(0.0f); acc[1] = (float4v)(0.0f);
        for (int kb = 0; kb < 8; ++kb) {
            short8 af = *(const short8*)(&t1s[l15 * 264 + kb * 32 + koff]);
            #pragma unroll
            for (int ni = 0; ni < 2; ++ni) {
                short8 bf = *(const short8*)(Wp1b + ((size_t)kb * 256 + n0 + ni * 16 + l15) * 32 + koff);
                acc[ni] = __builtin_amdgcn_mfma_f32_16x16x32_bf16(af, bf, acc[ni], 0, 0, 0);
            }
        }
        #pragma unroll
        for (int ni = 0; ni < 2; ++ni) {
            int col = n0 + ni * 16 + l15;
            float bv = b1b[col];
            #pragma unroll
            for (int r = 0; r < 4; ++r)
                hs2[(quad * 4 + r) * 264 + col] = f2bf(acc[ni][r] + bv);
        }
    }
    __syncthreads();

    // ---- S3 (dual): U = h@W2r + b2a ; Hs = h@W2s ----
    {
        float4v aU[2], aH[2];
        aU[0] = (float4v)(0.0f); aU[1] = (float4v)(0.0f);
        aH[0] = (float4v)(0.0f); aH[1] = (float4v)(0.0f);
        for (int kb = 0; kb < 8; ++kb) {
            short8 af = *(const short8*)(&hs2[l15 * 264 + kb * 32 + koff]);
            #pragma unroll
            for (int ni = 0; ni < 2; ++ni) {
                short8 bu = *(const short8*)(Wp2r + ((size_t)kb * 256 + n0 + ni * 16 + l15) * 32 + koff);
                short8 bh = *(const short8*)(Wp2s + ((size_t)kb * 256 + n0 + ni * 16 + l15) * 32 + koff);
                aU[ni] = __builtin_amdgcn_mfma_f32_16x16x32_bf16(af, bu, aU[ni], 0, 0, 0);
                aH[ni] = __builtin_amdgcn_mfma_f32_16x16x32_bf16(af, bh, aH[ni], 0, 0, 0);
            }
        }
        #pragma unroll
        for (int ni = 0; ni < 2; ++ni) {
            int col = n0 + ni * 16 + l15;
            float bv = b2a[col];
            #pragma unroll
            for (int r = 0; r < 4; ++r) {
                size_t o = (size_t)(m0 + quad * 4 + r) * 256 + col;
                U[o]  = f2bf(aU[ni][r] + bv);
                Hs[o] = f2bf(aH[ni][r]);
            }
        }
    }
}

// ---------------------------------------------------------------------------
// nodeC (fused + colsum S0, 512 thr): rows m0=bx*16.
// S0: Ssc -> buf1 [LDS]; S1: vin -> buf0; S2: t3 -> buf1; S3: v2 -> buf0;
// S4 (dual): C4, Vs -> global.
// ---------------------------------------------------------------------------
__global__ __launch_bounds__(512) void node_fusedC_kernel(
        const unsigned short* __restrict__ U, const unsigned short* __restrict__ Hs,
        const unsigned short* __restrict__ Wp2b, const float* __restrict__ b2bs,
        const unsigned short* __restrict__ Wp3a, const float* __restrict__ b3a,
        const unsigned short* __restrict__ Wp3b, const float* __restrict__ b3b,
        const unsigned short* __restrict__ Wp4r, const float* __restrict__ b4ap,
        const unsigned short* __restrict__ Wp4s,
        unsigned short* __restrict__ C4, unsigned short* __restrict__ Vs) {
    __shared__ __align__(16) unsigned short buf0[16 * 264];
    __shared__ __align__(16) unsigned short buf1[16 * 264];
    const int m0 = blockIdx.x * 16;
    const int tid  = threadIdx.x;
    const int wave = tid >> 6;
    const int lane = tid & 63;
    const int l15  = lane & 15;
    const int quad = lane >> 4;
    const int n0   = wave * 32;
    const int koff = quad * 8;

    // ---- S0: colsum -> buf1 (Ssc rows local 0..15) ----
    {
        const int rl = tid >> 5;           // group 0..15
        const int ct = (tid & 31) * 8;     // 8 cols
        const int g = m0 + rl;
        const int b = g / 100, i = g - b * 100;
        float u[8], s[8];
        {
            ushort4v u0 = *(const ushort4v*)(U + (size_t)g * 256 + ct);
            ushort4v u1 = *(const ushort4v*)(U + (size_t)g * 256 + ct + 4);
            #pragma unroll
            for (int e = 0; e < 4; ++e) { u[e] = bf2f(u0[e]); u[4 + e] = bf2f(u1[e]); }
            #pragma unroll
            for (int e = 0; e < 8; ++e) s[e] = 0.f;
        }
        const unsigned short* base = Hs + (size_t)b * 100 * 256 + ct;
        #pragma unroll 5
        for (int j = 0; j < 100; ++j) {
            ushort4v h0 = *(const ushort4v*)(base + (size_t)j * 256);
            ushort4v h1 = *(const ushort4v*)(base + (size_t)j * 256 + 4);
            #pragma unroll
            for (int e = 0; e < 4; ++e) {
                float v0 = u[e] + bf2f(h0[e]);     s[e]     += (v0 > 0.f ? v0 : 0.f);
                float v1 = u[4 + e] + bf2f(h1[e]); s[4 + e] += (v1 > 0.f ? v1 : 0.f);
            }
        }
        {
            ushort4v h0 = *(const ushort4v*)(base + (size_t)i * 256);
            ushort4v h1 = *(const ushort4v*)(base + (size_t)i * 256 + 4);
            #pragma unroll
            for (int e = 0; e < 4; ++e) {
                float v0 = u[e] + bf2f(h0[e]);     s[e]     -= (v0 > 0.f ? v0 : 0.f);
                float v1 = u[4 + e] + bf2f(h1[e]); s[4 + e] -= (v1 > 0.f ? v1 : 0.f);
            }
        }
        uint4v d;
        d[0] = f2bf_pk(s[0] * 0.01f, s[1] * 0.01f);
        d[1] = f2bf_pk(s[2] * 0.01f, s[3] * 0.01f);
        d[2] = f2bf_pk(s[4] * 0.01f, s[5] * 0.01f);
        d[3] = f2bf_pk(s[6] * 0.01f, s[7] * 0.01f);
        *(uint4v*)(&buf1[rl * 264 + ct]) = d;
    }
    __syncthreads();

    // ---- S1: vin = Ssc@W2b + b2bs -> buf0 ----
    {
        float4v acc[2];
        acc[0] = (float4v)(0.0f); acc[1] = (float4v)(0.0f);
        for (int kb = 0; kb < 8; ++kb) {
            short8 af = *(const short8*)(&buf1[l15 * 264 + kb * 32 + koff]);
            #pragma unroll
            for (int ni = 0; ni < 2; ++ni) {
                short8 bf = *(const short8*)(Wp2b + ((size_t)kb * 256 + n0 + ni * 16 + l15) * 32 + koff);
                acc[ni] = __builtin_amdgcn_mfma_f32_16x16x32_bf16(af, bf, acc[ni], 0, 0, 0);
            }
        }
        #pragma unroll
        for (int ni = 0; ni < 2; ++ni) {
            int col = n0 + ni * 16 + l15;
            float bv = b2bs[col];
            #pragma unroll
            for (int r = 0; r < 4; ++r)
                buf0[(quad * 4 + r) * 264 + col] = f2bf(acc[ni][r] + bv);
        }
    }
    __syncthreads();

    // ---- S2: t3 = relu(vin@W3a + b3a) -> buf1 ----
    {
        float4v acc[2];
        acc[0] = (float4v)(0.0f); acc[1] = (float4v)(0.0f);
        for (int kb = 0; kb < 8; ++kb) {
            short8 af = *(const short8*)(&buf0[l15 * 264 + kb * 32 + koff]);
            #pragma unroll
            for (int ni = 0; ni < 2; ++ni) {
                short8 bf = *(const short8*)(Wp3a + ((size_t)kb * 256 + n0 + ni * 16 + l15) * 32 + koff);
                acc[ni] = __builtin_amdgcn_mfma_f32_16x16x32_bf16(af, bf, acc[ni], 0, 0, 0);
            }
        }
        __syncthreads();   // buf1's S1 readers done; safe rewrite
        #pragma unroll
        for (int ni = 0; ni < 2; ++ni) {
            int col = n0 + ni * 16 + l15;
            float bv = b3a[col];
            #pragma unroll
            for (int r = 0; r < 4; ++r) {
                float v = acc[ni][r] + bv;
                v = v > 0.f ? v : 0.f;
                buf1[(quad * 4 + r) * 264 + col] = f2bf(v);
            }
        }
    }
    __syncthreads();

    // ---- S3: v2 = t3@W3b + b3b -> buf0 ----
    {
        float4v acc[2];
        acc[0] = (float4v)(0.0f); acc[1] = (float4v)(0.0f);
        for (int kb = 0; kb < 8; ++kb) {
            short8 af = *(const short8*)(&buf1[l15 * 264 + kb * 32 + koff]);
            #pragma unroll
            for (int ni = 0; ni < 2; ++ni) {
                short8 bf = *(const short8*)(Wp3b + ((size_t)kb * 256 + n0 + ni * 16 + l15) * 32 + koff);
                acc[ni] = __builtin_amdgcn_mfma_f32_16x16x32_bf16(af, bf, acc[ni], 0, 0, 0);
            }
        }
        __syncthreads();   // buf0's S2 readers done; safe rewrite
        #pragma unroll
        for (int ni = 0; ni < 2; ++ni) {
            int col = n0 + ni * 16 + l15;
            float bv = b3b[col];
            #pragma unroll
            for (int r = 0; r < 4; ++r)
                buf0[(quad * 4 + r) * 264 + col] = f2bf(acc[ni][r] + bv);
        }
    }
    __syncthreads();

    // ---- S4 (dual): C4 = v2@W4r + b4ap ; Vs = v2@W4s ----
    {
        float4v aC[2], aV[2];
        aC[0] = (float4v)(0.0f); aC[1] = (float4v)(0.0f);
        aV[0] = (float4v)(0.0f); aV[1] = (float4v)(0.0f);
        for (int kb = 0; kb < 8; ++kb) {
            short8 af = *(const short8*)(&buf0[l15 * 264 + kb * 32 + koff]);
            #pragma unroll
            for (int ni = 0; ni < 2; ++ni) {
                short8 bc = *(const short8*)(Wp4r + ((size_t)kb * 256 + n0 + ni * 16 + l15) * 32 + koff);
                short8 bv = *(const short8*)(Wp4s + ((size_t)kb * 256 + n0 + ni * 16 + l15) * 32 + koff);
                aC[ni] = __builtin_amdgcn_mfma_f32_16x16x32_bf16(af, bc, aC[ni], 0, 0, 0);
                aV[ni] = __builtin_amdgcn_mfma_f32_16x16x32_bf16(af, bv, aV[ni], 0, 0, 0);
            }
        }
        #pragma unroll
        for (int ni = 0; ni < 2; ++ni) {
            int col = n0 + ni * 16 + l15;
            float bv = b4ap[col];
            #pragma unroll
            for (int r = 0; r < 4; ++r) {
                size_t o = (size_t)(m0 + quad * 4 + r) * 256 + col;
                C4[o] = f2bf(aC[ni][r] + bv);
                Vs[o] = f2bf(aV[ni][r]);
            }
        }
    }
}

// ---------------------------------------------------------------------------
// Phase B: grid (3200,2), block 512 (8 waves x 32 cols, EVEN/ODD pairing).
// stage0: t2 -> LDS ONCE + jtab[64]. PREFETCH 16 Vs dwords + C4 dword.
// acc INIT = C4 broadcast. K-loop: acc[4][2] vs permuted Wpz, UNROLL 2
// (fits ~85-reg cap now that acc=32; watch WRITE_SIZE). z4: register-only.
// Projection waves 0-3 vs Wfp. LDS 33792+256 B. (512,6).
// ---------------------------------------------------------------------------
__global__ __launch_bounds__(512, 6) void edge_phaseB_kernel(
        const unsigned short* __restrict__ Hs, const unsigned short* __restrict__ Vs,
        const unsigned short* __restrict__ U, const unsigned short* __restrict__ C4,
        const unsigned short* __restrict__ Wpz, const unsigned short* __restrict__ Wfp,
        const float* __restrict__ bfv,
        float* __restrict__ out) {
    __shared__ __align__(16) unsigned short t2s[64 * 264]; // 33792 B (z4 aliases later)
    __shared__ int jtab[64];
    const int g = blockIdx.x, hb = blockIdx.y;
    const int b = g / 100, nr = g - b * 100;
    const int nrows = hb ? 49 : 50;
    const int k0 = hb * 50;
    const int tid  = threadIdx.x;
    const int wave = tid >> 6;          // 0..7
    const int lane = tid & 63;
    const int l15  = lane & 15;
    const int quad = lane >> 4;
    const int n0   = wave * 32;         // 32-col slice per wave
    const int koff = quad * 8;

    // ---- stage 0: build t2 tile ONCE + jtab (8 rows/wave; pad rows 0) ----
    {
        const int c = lane * 4;
        ushort4v uv = *(const ushort4v*)(U + (size_t)g * 256 + c);
        float u0 = bf2f(uv[0]), u1 = bf2f(uv[1]), u2 = bf2f(uv[2]), u3 = bf2f(uv[3]);
        for (int r = wave; r < 64; r += 8) {
            int k = k0 + r;
            int j = (r < nrows) ? (k + (k >= nr ? 1 : 0)) : 0;
            if (lane == 0) jtab[r] = b * 100 + j;
            unsigned int p01 = 0, p23 = 0;
            if (r < nrows) {
                ushort4v hv = *(const ushort4v*)(Hs + (size_t)(b * 100 + j) * 256 + c);
                float t0 = u0 + bf2f(hv[0]); t0 = t0 > 0.f ? t0 : 0.f;
                float t1 = u1 + bf2f(hv[1]); t1 = t1 > 0.f ? t1 : 0.f;
                float t2 = u2 + bf2f(hv[2]); t2 = t2 > 0.f ? t2 : 0.f;
                float t3 = u3 + bf2f(hv[3]); t3 = t3 > 0.f ? t3 : 0.f;
                p01 = f2bf_pk(t0, t1);
                p23 = f2bf_pk(t2, t3);
            }
            unsigned int* dst = (unsigned int*)(&t2s[r * 264 + c]);
            dst[0] = p01;
            dst[1] = p23;
        }
    }
    __syncthreads();

    // ---- prefetch: Vs col-pair dwords for this thread's 16 rows + C4 ----
    const int cp = n0 + 2 * l15;            // even col; odd = cp+1
    unsigned int c4p = *(const unsigned int*)(C4 + (size_t)g * 256 + cp);
    unsigned int vsp[16];
    #pragma unroll
    for (int mi = 0; mi < 4; ++mi)
        #pragma unroll
        for (int r = 0; r < 4; ++r)
            vsp[mi * 4 + r] = *(const unsigned int*)(Vs + (size_t)jtab[mi * 16 + quad * 4 + r] * 256 + cp);

    // ---- K-loop: z4 GEMM (K=256); acc init = C4 broadcast ----
    float c4v0 = bf2f((unsigned short)c4p);
    float c4v1 = bf2f((unsigned short)(c4p >> 16));
    float4v acc[4][2];
    #pragma unroll
    for (int mi = 0; mi < 4; ++mi) {
        acc[mi][0] = (float4v)(c4v0);
        acc[mi][1] = (float4v)(c4v1);
    }

    #pragma unroll 2              // acc=32 regs now; 2-iter live window fits ~85 cap
    for (int kb = 0; kb < 8; ++kb) {
        short8 bf0 = *(const short8*)(Wpz + ((size_t)kb * 256 + n0 + l15) * 32 + koff);
        short8 bf1 = *(const short8*)(Wpz + ((size_t)kb * 256 + n0 + 16 + l15) * 32 + koff);
        #pragma unroll
        for (int mi = 0; mi < 4; ++mi) {
            short8 af = *(const short8*)(&t2s[(mi * 16 + l15) * 264 + kb * 32 + koff]);
            acc[mi][0] = __builtin_amdgcn_mfma_f32_16x16x32_bf16(af, bf0, acc[mi][0], 0, 0, 0);
            acc[mi][1] = __builtin_amdgcn_mfma_f32_16x16x32_bf16(af, bf1, acc[mi][1], 0, 0, 0);
        }
    }
    __syncthreads();            // all t2s A-reads done; z4 aliases t2s below

    // ---- z4 = relu(Vs_j + acc) -> LDS (natural order, register-only) ----
    #pragma unroll
    for (int mi = 0; mi < 4; ++mi) {
        #pragma unroll
        for (int r = 0; r < 4; ++r) {
            int row = mi * 16 + quad * 4 + r;      // local edge idx (C-layout)
            unsigned int vp = vsp[mi * 4 + r];
            float z0 = bf2f((unsigned short)vp) + acc[mi][0][r];
            float z1 = bf2f((unsigned short)(vp >> 16)) + acc[mi][1][r];
            z0 = z0 > 0.f ? z0 : 0.f;
            z1 = z1 > 0.f ? z1 : 0.f;
            *(unsigned int*)(&t2s[row * 264 + cp]) = f2bf_pk(z0, z1);
        }
    }
    __syncthreads();

    // ---- projection: waves 0-3, rows wave*16..+15; 8 MFMA vs Wfp ----
    if (wave < 4) {
        float4v pacc = (float4v)(0.0f);
        #pragma unroll
        for (int kb = 0; kb < 8; ++kb) {
            short8 za = *(const short8*)(&t2s[(wave * 16 + l15) * 264 + kb * 32 + koff]);
            short8 wb = *(const short8*)(Wfp + (size_t)kb * 512 + l15 * 32 + koff);
            pacc = __builtin_amdgcn_mfma_f32_16x16x32_bf16(za, wb, pacc, 0, 0, 0);
        }
        if (l15 < 4) {
            float bv = bfv[l15];
            #pragma unroll
            for (int r = 0; r < 4; ++r) {
                int row = wave * 16 + quad * 4 + r;
                if (row < nrows)
                    out[((size_t)b * 9900 + nr * 99 + k0 + row) * 4 + l15] = pacc[r] + bv;
            }
        }
    }
}

extern "C" void kernel_launch(void* const* d_in, const int* in_sizes, int n_in,
                              void* d_out, int out_size, void* d_ws, size_t ws_size,
                              hipStream_t stream) {
    const float* x   = (const float*)d_in[0];
    const float* w1a = (const float*)d_in[3];
    const float* b1a = (const float*)d_in[4];
    const float* w1b = (const float*)d_in[5];
    const float* b1b = (const float*)d_in[6];
    const float* w2a = (const float*)d_in[7];
    const float* b2a = (const float*)d_in[8];
    const float* w2b = (const float*)d_in[9];
    const float* b2b = (const float*)d_in[10];
    const float* w3a = (const float*)d_in[11];
    const float* b3a = (const float*)d_in[12];
    const float* w3b = (const float*)d_in[13];
    const float* b3b = (const float*)d_in[14];
    const float* w4a = (const float*)d_in[15];
    const float* b4a = (const float*)d_in[16];
    const float* w4b = (const float*)d_in[17];
    const float* b4b = (const float*)d_in[18];
    const float* wo  = (const float*)d_in[19];
    const float* bo  = (const float*)d_in[20];
    float* out = (float*)d_out;
    (void)in_sizes; (void)n_in; (void)out_size; (void)ws_size;

    char* ws = (char*)d_ws;
    size_t off = 0;
    auto alloc = [&](size_t bytes) {
        size_t o = off;
        off = (off + bytes + 255) & ~(size_t)255;
        return o;
    };
    const size_t SLOT_BF = (size_t)3200 * 256 * 2;   // 1.64 MB
    unsigned short* S_U  = (unsigned short*)(ws + alloc(SLOT_BF)); // U
    unsigned short* S_Hs = (unsigned short*)(ws + alloc(SLOT_BF)); // Hs
    unsigned short* S_Vs = (unsigned short*)(ws + alloc(SLOT_BF)); // Vs
    unsigned short* S_4  = (unsigned short*)(ws + alloc(SLOT_BF)); // hin -> C4
    unsigned short* Wp1a = (unsigned short*)(ws + alloc(224 * 256 * 2));
    unsigned short* Wp1b = (unsigned short*)(ws + alloc(256 * 256 * 2));
    unsigned short* Wp2r = (unsigned short*)(ws + alloc(256 * 256 * 2));
    unsigned short* Wp2s = (unsigned short*)(ws + alloc(256 * 256 * 2));
    unsigned short* Wp2b = (unsigned short*)(ws + alloc(256 * 256 * 2));
    unsigned short* Wp3a = (unsigned short*)(ws + alloc(256 * 256 * 2));
    unsigned short* Wp3b = (unsigned short*)(ws + alloc(256 * 256 * 2));
    unsigned short* Wp4r = (unsigned short*)(ws + alloc(256 * 256 * 2));
    unsigned short* Wp4s = (unsigned short*)(ws + alloc(256 * 256 * 2));
    unsigned short* Wpz  = (unsigned short*)(ws + alloc(256 * 256 * 2));
    unsigned short* Wfp  = (unsigned short*)(ws + alloc(8 * 16 * 32 * 2));
    float*          bfv  = (float*)(ws + alloc(4 * 4));
    float*          b4ap = (float*)(ws + alloc(256 * 4));
    float*          b2bs = (float*)(ws + alloc(256 * 4));
    // total ~8 MB (<= 11.2 proven safe)

    unsigned short* hin = S_4;   // [prep, nodeA]
    unsigned short* C4  = S_4;   // [nodeC, phaseB]

    // ---- 4 dispatches ----
    hipLaunchKernelGGL(prep_kernel, dim3(5330), dim3(256), 0, stream,
                       x, w1a, w1b, w2a, w2b, w3a, w3b, w4a, b4a, w4b, b4b, wo, bo, b2b,
                       Wp1a, Wp1b, Wp2r, Wp2s, Wp2b, Wp3a, Wp3b, Wp4r, Wp4s, Wpz,
                       Wfp, bfv, b4ap, b2bs, hin);
    hipLaunchKernelGGL(node_fusedA_kernel, dim3(200), dim3(512), 0, stream,
                       hin, Wp1a, b1a, Wp1b, b1b, Wp2r, b2a, Wp2s, S_U, S_Hs);
    hipLaunchKernelGGL(node_fusedC_kernel, dim3(200), dim3(512), 0, stream,
                       S_U, S_Hs, Wp2b, b2bs, Wp3a, b3a, Wp3b, b3b, Wp4r, b4ap, Wp4s, C4, S_Vs);
    hipLaunchKernelGGL(edge_phaseB_kernel, dim3(3200, 2), dim3(512), 0, stream,
                       S_Hs, S_Vs, S_U, C4, Wpz, Wfp, bfv, out);
}